// Round 2
// baseline (6199.696 us; speedup 1.0000x reference)
//
#include <hip/hip_runtime.h>
#include <hip/hip_bf16.h>
#include <math.h>

#define N_NODES 16384
#define NB      32
#define S_PG    512
#define NE      262144
#define D       256
#define D2      512
#define D3      768
#define NL      4
#define NH      4
#define DHD     64
#define OUTD    768

// ---------------- Atom encoder: h[n,d] = sum_f atom_tab[f, x[n,f], d] ----------------
__global__ __launch_bounds__(256) void k_atom_enc(const int* __restrict__ x,
                                                  const float* __restrict__ tab,
                                                  float* __restrict__ h) {
    int node = blockIdx.x * 4 + (threadIdx.x >> 6);
    int lane = threadIdx.x & 63;
    int dd = lane << 2;
    float4 acc = {0.f, 0.f, 0.f, 0.f};
#pragma unroll
    for (int f = 0; f < 9; ++f) {
        int v = x[node * 9 + f];
        const float4 t = *(const float4*)&tab[((size_t)(f * 119 + v)) * D + dd];
        acc.x += t.x; acc.y += t.y; acc.z += t.z; acc.w += t.w;
    }
    *(float4*)&h[(size_t)node * D + dd] = acc;
}

// ---------------- bw[l,fv,dout] = dot(bond_tab[fv,:], elin_w[l,:,dout]) ----------------
__global__ __launch_bounds__(256) void k_bondw(const float* __restrict__ bond_tab,
                                               const float* __restrict__ elin_w,
                                               float* __restrict__ bw) {
    int blk = blockIdx.x;         // L*66
    int l = blk / 66, fv = blk % 66;
    int dout = threadIdx.x;
    const float* tabrow = bond_tab + (size_t)fv * D;
    const float* w = elin_w + (size_t)l * D * D;
    float acc = 0.f;
    for (int d = 0; d < D; ++d) acc = fmaf(tabrow[d], w[d * D + dout], acc);
    bw[((size_t)l * 66 + fv) * D + dout] = acc;
}

// ---------------- agg = (1+eps[l]) * h ----------------
__global__ __launch_bounds__(256) void k_scale_init(const float* __restrict__ h,
                                                    const float* __restrict__ eps, int l,
                                                    float* __restrict__ agg) {
    size_t i = (size_t)blockIdx.x * blockDim.x + threadIdx.x;
    float s = 1.f + eps[l];
    float4 v = ((const float4*)h)[i];
    v.x *= s; v.y *= s; v.z *= s; v.w *= s;
    ((float4*)agg)[i] = v;
}

// ---------------- edge: agg[dst] += relu(h[src] + bw0[a0]+bw1[a1]+bw2[a2] + elin_b) ----------------
__global__ __launch_bounds__(256) void k_edge(const float* __restrict__ h,
                                              const float* __restrict__ bw,
                                              const float* __restrict__ elin_b,
                                              const int* __restrict__ ea,
                                              const int* __restrict__ src,
                                              const int* __restrict__ dst,
                                              float* __restrict__ agg) {
    int e = blockIdx.x * 4 + (threadIdx.x >> 6);
    int lane = threadIdx.x & 63;
    int dd = lane << 2;
    int s = src[e], dt = dst[e];
    int a0 = ea[e * 3], a1 = ea[e * 3 + 1], a2 = ea[e * 3 + 2];
    float4 v = *(const float4*)&h[(size_t)s * D + dd];
    const float4 b0 = *(const float4*)&bw[(size_t)a0 * D + dd];
    const float4 b1 = *(const float4*)&bw[(size_t)(22 + a1) * D + dd];
    const float4 b2 = *(const float4*)&bw[(size_t)(44 + a2) * D + dd];
    const float4 eb = *(const float4*)&elin_b[dd];
    v.x = fmaxf(v.x + b0.x + b1.x + b2.x + eb.x, 0.f);
    v.y = fmaxf(v.y + b0.y + b1.y + b2.y + eb.y, 0.f);
    v.z = fmaxf(v.z + b0.z + b1.z + b2.z + eb.z, 0.f);
    v.w = fmaxf(v.w + b0.w + b1.w + b2.w + eb.w, 0.f);
    float* p = &agg[(size_t)dt * D + dd];
    atomicAdd(p + 0, v.x); atomicAdd(p + 1, v.y);
    atomicAdd(p + 2, v.z); atomicAdd(p + 3, v.w);
}

// ---------------- generic fp32 GEMM: C = op(A@B + bias [+ res]) ----------------
// A [M,K] row-major, B [K,N] row-major, 128x128 tile, 8x8 per thread
template<int RELU, int HASRES>
__global__ __launch_bounds__(256) void k_gemm(const float* __restrict__ A,
                                              const float* __restrict__ B,
                                              const float* __restrict__ bias,
                                              const float* __restrict__ res,
                                              float* __restrict__ C,
                                              int M, int N, int K) {
    __shared__ float As[16][128];
    __shared__ float Bs[16][128];
    const int tid = threadIdx.x;
    const int row0 = blockIdx.y * 128, col0 = blockIdx.x * 128;
    float acc[8][8] = {};
    const int ar = tid >> 2;            // 0..63
    const int ak = (tid & 3) << 2;      // 0,4,8,12
    const int bk = tid >> 5;            // 0..7
    const int bc = (tid & 31) << 2;     // 0..124
    const int ty = tid >> 4, tx = tid & 15;
    for (int k0 = 0; k0 < K; k0 += 16) {
        float4 a0 = *(const float4*)&A[(size_t)(row0 + ar) * K + k0 + ak];
        float4 a1 = *(const float4*)&A[(size_t)(row0 + ar + 64) * K + k0 + ak];
        float4 b0 = *(const float4*)&B[(size_t)(k0 + bk) * N + col0 + bc];
        float4 b1 = *(const float4*)&B[(size_t)(k0 + bk + 8) * N + col0 + bc];
        As[ak + 0][ar] = a0.x; As[ak + 1][ar] = a0.y; As[ak + 2][ar] = a0.z; As[ak + 3][ar] = a0.w;
        As[ak + 0][ar + 64] = a1.x; As[ak + 1][ar + 64] = a1.y; As[ak + 2][ar + 64] = a1.z; As[ak + 3][ar + 64] = a1.w;
        *(float4*)&Bs[bk][bc] = b0;
        *(float4*)&Bs[bk + 8][bc] = b1;
        __syncthreads();
#pragma unroll
        for (int kk = 0; kk < 16; ++kk) {
            float a[8], b[8];
            *(float4*)&a[0] = *(const float4*)&As[kk][ty * 8];
            *(float4*)&a[4] = *(const float4*)&As[kk][ty * 8 + 4];
            *(float4*)&b[0] = *(const float4*)&Bs[kk][tx * 8];
            *(float4*)&b[4] = *(const float4*)&Bs[kk][tx * 8 + 4];
#pragma unroll
            for (int i = 0; i < 8; ++i)
#pragma unroll
                for (int j = 0; j < 8; ++j) acc[i][j] = fmaf(a[i], b[j], acc[i][j]);
        }
        __syncthreads();
    }
#pragma unroll
    for (int i = 0; i < 8; ++i) {
        int r = row0 + ty * 8 + i;
#pragma unroll
        for (int j4 = 0; j4 < 8; j4 += 4) {
            int c = col0 + tx * 8 + j4;
            float4 v;
            v.x = acc[i][j4 + 0]; v.y = acc[i][j4 + 1];
            v.z = acc[i][j4 + 2]; v.w = acc[i][j4 + 3];
            const float4 bb = *(const float4*)&bias[c];
            v.x += bb.x; v.y += bb.y; v.z += bb.z; v.w += bb.w;
            if (HASRES) {
                const float4 rr = *(const float4*)&res[(size_t)r * N + c];
                v.x += rr.x; v.y += rr.y; v.z += rr.z; v.w += rr.w;
            }
            if (RELU) {
                v.x = fmaxf(v.x, 0.f); v.y = fmaxf(v.y, 0.f);
                v.z = fmaxf(v.z, 0.f); v.w = fmaxf(v.w, 0.f);
            }
            *(float4*)&C[(size_t)r * N + c] = v;
        }
    }
}

// ---------------- BatchNorm: two-stage stats + apply ----------------
__global__ __launch_bounds__(256) void k_bn_stat1(const float* __restrict__ x,
                                                  float* __restrict__ part) {
    int c = threadIdx.x;
    int blk = blockIdx.x;                    // 128 blocks x 128 rows
    const float* p = x + (size_t)blk * 128 * D + c;
    float s = 0.f, s2 = 0.f;
    for (int r = 0; r < 128; ++r) { float v = p[(size_t)r * D]; s += v; s2 += v * v; }
    part[blk * 2 * D + c] = s;
    part[blk * 2 * D + D + c] = s2;
}

__global__ __launch_bounds__(256) void k_bn_stat2(const float* __restrict__ part,
                                                  float* __restrict__ ms) {
    int c = threadIdx.x;
    float s = 0.f, s2 = 0.f;
    for (int p = 0; p < 128; ++p) { s += part[p * 2 * D + c]; s2 += part[p * 2 * D + D + c]; }
    float mean = s / (float)N_NODES;
    float var = s2 / (float)N_NODES - mean * mean;
    ms[c] = mean;
    ms[D + c] = rsqrtf(var + 1e-5f);
}

// ADD=0: y = bn(x).  ADD=1: y += bn(x)  (y may alias x only when ADD=0)
template<int ADD>
__global__ __launch_bounds__(256) void k_bn_apply(const float* __restrict__ x,
                                                  const float* __restrict__ ms,
                                                  const float* __restrict__ g,
                                                  const float* __restrict__ b,
                                                  float* __restrict__ y) {
    size_t i4 = (size_t)blockIdx.x * blockDim.x + threadIdx.x;
    int c = (int)((i4 & 63) << 2);
    float4 v = ((const float4*)x)[i4];
    v.x = (v.x - ms[c + 0]) * ms[D + c + 0] * g[c + 0] + b[c + 0];
    v.y = (v.y - ms[c + 1]) * ms[D + c + 1] * g[c + 1] + b[c + 1];
    v.z = (v.z - ms[c + 2]) * ms[D + c + 2] * g[c + 2] + b[c + 2];
    v.w = (v.w - ms[c + 3]) * ms[D + c + 3] * g[c + 3] + b[c + 3];
    if (ADD) {
        float4 o = ((const float4*)y)[i4];
        v.x += o.x; v.y += o.y; v.z += o.z; v.w += o.w;
    }
    ((float4*)y)[i4] = v;
}

// ---------------- flash attention: per block = one (b,h), 64 q-rows, full S loop ----------------
__global__ __launch_bounds__(256) void k_flash(const float* __restrict__ qkv,
                                               float* __restrict__ ao) {
    __shared__ float Qs[64][65];
    __shared__ float KPs[64][65];   // K tile, then reused for P tile
    __shared__ float Vs[64][65];
    int bh = blockIdx.x;
    int b = bh >> 2, hh = bh & 3;
    int i0 = blockIdx.y << 6;
    int tid = threadIdx.x;
    int ty = tid >> 4, tx = tid & 15;
    int rr = tid >> 4, c4 = (tid & 15) << 2;
    const size_t base = (size_t)(b * S_PG) * D3 + (size_t)hh * DHD;

#pragma unroll
    for (int p = 0; p < 4; ++p) {
        int r = rr + p * 16;
        float4 q = *(const float4*)&qkv[base + (size_t)(i0 + r) * D3 + c4];
        Qs[r][c4] = q.x; Qs[r][c4 + 1] = q.y; Qs[r][c4 + 2] = q.z; Qs[r][c4 + 3] = q.w;
    }

    float m[4] = {-INFINITY, -INFINITY, -INFINITY, -INFINITY};
    float l[4] = {0.f, 0.f, 0.f, 0.f};
    float o[4][4] = {};

    for (int j0 = 0; j0 < S_PG; j0 += 64) {
#pragma unroll
        for (int p = 0; p < 4; ++p) {
            int r = rr + p * 16;
            float4 kk = *(const float4*)&qkv[base + D + (size_t)(j0 + r) * D3 + c4];
            KPs[r][c4] = kk.x; KPs[r][c4 + 1] = kk.y; KPs[r][c4 + 2] = kk.z; KPs[r][c4 + 3] = kk.w;
            float4 vv = *(const float4*)&qkv[base + D2 + (size_t)(j0 + r) * D3 + c4];
            Vs[r][c4] = vv.x; Vs[r][c4 + 1] = vv.y; Vs[r][c4 + 2] = vv.z; Vs[r][c4 + 3] = vv.w;
        }
        __syncthreads();
        // scores s[i][j] for q-rows ty*4+i, k-rows tx*4+j
        float s[4][4] = {};
        for (int k = 0; k < 64; ++k) {
            float a[4], bb[4];
#pragma unroll
            for (int i = 0; i < 4; ++i) a[i] = Qs[ty * 4 + i][k];
#pragma unroll
            for (int j = 0; j < 4; ++j) bb[j] = KPs[tx * 4 + j][k];
#pragma unroll
            for (int i = 0; i < 4; ++i)
#pragma unroll
                for (int j = 0; j < 4; ++j) s[i][j] = fmaf(a[i], bb[j], s[i][j]);
        }
        float pv[4][4], alpha[4];
#pragma unroll
        for (int i = 0; i < 4; ++i) {
            float pm = -INFINITY;
#pragma unroll
            for (int j = 0; j < 4; ++j) { s[i][j] *= 0.125f; pm = fmaxf(pm, s[i][j]); }
            // reduce max over the 16-thread tx group (lanes ty*16 .. ty*16+15)
#pragma unroll
            for (int off = 1; off < 16; off <<= 1) pm = fmaxf(pm, __shfl_xor(pm, off));
            float mn = fmaxf(m[i], pm);
            alpha[i] = __expf(m[i] - mn);           // exp(-inf - finite) = 0 on first tile
            float rs = 0.f;
#pragma unroll
            for (int j = 0; j < 4; ++j) { pv[i][j] = __expf(s[i][j] - mn); rs += pv[i][j]; }
#pragma unroll
            for (int off = 1; off < 16; off <<= 1) rs += __shfl_xor(rs, off);
            l[i] = l[i] * alpha[i] + rs;
            m[i] = mn;
        }
        __syncthreads();   // everyone done reading K before overwriting with P
#pragma unroll
        for (int i = 0; i < 4; ++i)
#pragma unroll
            for (int j = 0; j < 4; ++j) KPs[ty * 4 + i][tx * 4 + j] = pv[i][j];
#pragma unroll
        for (int i = 0; i < 4; ++i)
#pragma unroll
            for (int d = 0; d < 4; ++d) o[i][d] *= alpha[i];
        __syncthreads();   // P ready
        for (int j = 0; j < 64; ++j) {
            float a[4], bb[4];
#pragma unroll
            for (int i = 0; i < 4; ++i) a[i] = KPs[ty * 4 + i][j];
#pragma unroll
            for (int d = 0; d < 4; ++d) bb[d] = Vs[j][tx * 4 + d];
#pragma unroll
            for (int i = 0; i < 4; ++i)
#pragma unroll
                for (int d = 0; d < 4; ++d) o[i][d] = fmaf(a[i], bb[d], o[i][d]);
        }
        __syncthreads();   // done with P,V before next tile load
    }
#pragma unroll
    for (int i = 0; i < 4; ++i) {
        float inv = 1.f / l[i];
        int node = b * S_PG + i0 + ty * 4 + i;
        float4 v;
        v.x = o[i][0] * inv; v.y = o[i][1] * inv; v.z = o[i][2] * inv; v.w = o[i][3] * inv;
        *(float4*)&ao[(size_t)node * D + hh * DHD + tx * 4] = v;
    }
}

// ---------------- mean pool per graph ----------------
__global__ __launch_bounds__(256) void k_pool(const float* __restrict__ h, float* __restrict__ g) {
    int b = blockIdx.x, c = threadIdx.x;
    const float* p = h + (size_t)b * S_PG * D + c;
    float s = 0.f;
    for (int r = 0; r < S_PG; ++r) s += p[(size_t)r * D];
    g[b * D + c] = s * (1.f / (float)S_PG);
}

// ---------------- final head: z = relu(g@pw1+pb1)@pw2+pb2; z /= ||z|| ----------------
__global__ __launch_bounds__(256) void k_final(const float* __restrict__ g,
                                               const float* __restrict__ pw1,
                                               const float* __restrict__ pb1,
                                               const float* __restrict__ pw2,
                                               const float* __restrict__ pb2,
                                               float* __restrict__ out) {
    __shared__ float gs[D];
    __shared__ float ts[D];
    __shared__ float red[4];
    int b = blockIdx.x, tid = threadIdx.x;
    gs[tid] = g[b * D + tid];
    __syncthreads();
    float acc = pb1[tid];
    for (int d = 0; d < D; ++d) acc = fmaf(gs[d], pw1[d * D + tid], acc);
    ts[tid] = fmaxf(acc, 0.f);
    __syncthreads();
    float z[3];
#pragma unroll
    for (int rep = 0; rep < 3; ++rep) {
        int j = tid + rep * 256;
        float a = pb2[j];
        for (int d = 0; d < D; ++d) a = fmaf(ts[d], pw2[(size_t)d * OUTD + j], a);
        z[rep] = a;
    }
    float ss = z[0] * z[0] + z[1] * z[1] + z[2] * z[2];
#pragma unroll
    for (int o = 32; o >= 1; o >>= 1) ss += __shfl_xor(ss, o);
    if ((tid & 63) == 0) red[tid >> 6] = ss;
    __syncthreads();
    float rn = rsqrtf(red[0] + red[1] + red[2] + red[3]);
#pragma unroll
    for (int rep = 0; rep < 3; ++rep) out[b * OUTD + tid + rep * 256] = z[rep] * rn;
}

extern "C" void kernel_launch(void* const* d_in, const int* in_sizes, int n_in,
                              void* d_out, int out_size, void* d_ws, size_t ws_size,
                              hipStream_t stream) {
    const int* x        = (const int*)d_in[0];
    const int* ea       = (const int*)d_in[1];
    const int* eidx     = (const int*)d_in[2];
    const float* atom_tab = (const float*)d_in[4];
    const float* bond_tab = (const float*)d_in[5];
    const float* elin_w = (const float*)d_in[6];
    const float* elin_b = (const float*)d_in[7];
    const float* eps    = (const float*)d_in[8];
    const float* gw1    = (const float*)d_in[9];
    const float* gb1    = (const float*)d_in[10];
    const float* gw2    = (const float*)d_in[11];
    const float* gb2    = (const float*)d_in[12];
    const float* aw_in  = (const float*)d_in[13];
    const float* ab_in  = (const float*)d_in[14];
    const float* aw_out = (const float*)d_in[15];
    const float* ab_out = (const float*)d_in[16];
    const float* n1g    = (const float*)d_in[17];
    const float* n1b    = (const float*)d_in[18];
    const float* n2g    = (const float*)d_in[19];
    const float* n2b    = (const float*)d_in[20];
    const float* n3g    = (const float*)d_in[21];
    const float* n3b    = (const float*)d_in[22];
    const float* mw1    = (const float*)d_in[23];
    const float* mb1    = (const float*)d_in[24];
    const float* mw2    = (const float*)d_in[25];
    const float* mb2    = (const float*)d_in[26];
    const float* pw1    = (const float*)d_in[27];
    const float* pb1    = (const float*)d_in[28];
    const float* pw2    = (const float*)d_in[29];
    const float* pb2    = (const float*)d_in[30];

    // ---- compact workspace layout (~97 MiB) ----
    char* ws = (char*)d_ws;
    size_t off = 0;
    auto alloc = [&](size_t bytes) {
        void* p = ws + off;
        off += (bytes + 255) & ~(size_t)255;
        return p;
    };
    float* h    = (float*)alloc((size_t)N_NODES * D * 4);    // 16 MiB, layer state
    float* bufA = (float*)alloc((size_t)N_NODES * D * 4);    // 16 MiB: agg, then ao
    float* bufB = (float*)alloc((size_t)N_NODES * D * 4);    // 16 MiB: pre-bn1 -> hc -> out
    float* uni  = (float*)alloc((size_t)N_NODES * D3 * 4);   // 48 MiB: hidden512 / qkv / pre-bn2
    float* bw   = (float*)alloc((size_t)NL * 66 * D * 4);
    float* part = (float*)alloc((size_t)128 * 2 * D * 4);
    float* ms   = (float*)alloc((size_t)2 * D * 4);
    float* g    = (float*)alloc((size_t)NB * D * 4);
    (void)ws_size; (void)in_sizes; (void)n_in; (void)out_size;

    const int* srcp = eidx;
    const int* dstp = eidx + NE;
    const int EW = N_NODES * D / 1024;  // grid for 1-float4-per-thread elementwise

    k_atom_enc<<<N_NODES / 4, 256, 0, stream>>>(x, atom_tab, h);
    k_bondw<<<NL * 66, 256, 0, stream>>>(bond_tab, elin_w, bw);

    for (int l = 0; l < NL; ++l) {
        // --- GINE local branch ---
        k_scale_init<<<EW, 256, 0, stream>>>(h, eps, l, bufA);
        k_edge<<<NE / 4, 256, 0, stream>>>(h, bw + (size_t)l * 66 * D, elin_b + l * D,
                                           ea, srcp, dstp, bufA);
        k_gemm<1, 0><<<dim3(D2 / 128, N_NODES / 128), 256, 0, stream>>>(
            bufA, gw1 + (size_t)l * D * D2, gb1 + l * D2, nullptr, uni, N_NODES, D2, D);
        k_gemm<0, 1><<<dim3(D / 128, N_NODES / 128), 256, 0, stream>>>(
            uni, gw2 + (size_t)l * D2 * D, gb2 + l * D, h, bufB, N_NODES, D, D2);
        k_bn_stat1<<<128, 256, 0, stream>>>(bufB, part);
        k_bn_stat2<<<1, 256, 0, stream>>>(part, ms);
        k_bn_apply<0><<<EW, 256, 0, stream>>>(bufB, ms, n1g + l * D, n1b + l * D, bufB); // hc in-place
        // --- global attention (flash) ---
        k_gemm<0, 0><<<dim3(D3 / 128, N_NODES / 128), 256, 0, stream>>>(
            h, aw_in + (size_t)l * D * D3, ab_in + l * D3, nullptr, uni, N_NODES, D3, D);
        k_flash<<<dim3(NB * NH, S_PG / 64), 256, 0, stream>>>(uni, bufA);
        k_gemm<0, 1><<<dim3(D / 128, N_NODES / 128), 256, 0, stream>>>(
            bufA, aw_out + (size_t)l * D * D, ab_out + l * D, h, uni, N_NODES, D, D);  // pre-bn2
        k_bn_stat1<<<128, 256, 0, stream>>>(uni, part);
        k_bn_stat2<<<1, 256, 0, stream>>>(part, ms);
        k_bn_apply<1><<<EW, 256, 0, stream>>>(uni, ms, n2g + l * D, n2b + l * D, bufB); // bufB=hc+ha
        // --- combine + MLP ---
        k_gemm<1, 0><<<dim3(D2 / 128, N_NODES / 128), 256, 0, stream>>>(
            bufB, mw1 + (size_t)l * D * D2, mb1 + l * D2, nullptr, uni, N_NODES, D2, D);
        k_gemm<0, 1><<<dim3(D / 128, N_NODES / 128), 256, 0, stream>>>(
            uni, mw2 + (size_t)l * D2 * D, mb2 + l * D, bufB, h, N_NODES, D, D2);
        k_bn_stat1<<<128, 256, 0, stream>>>(h, part);
        k_bn_stat2<<<1, 256, 0, stream>>>(part, ms);
        k_bn_apply<0><<<EW, 256, 0, stream>>>(h, ms, n3g + l * D, n3b + l * D, h);      // in-place
    }
    k_pool<<<NB, 256, 0, stream>>>(h, g);
    k_final<<<NB, 256, 0, stream>>>(g, pw1, pb1, pw2, pb2, (float*)d_out);
}

// Round 3
// 4009.812 us; speedup vs baseline: 1.5461x; 1.5461x over previous
//
#include <hip/hip_runtime.h>
#include <hip/hip_bf16.h>
#include <math.h>

#define N_NODES 16384
#define NB      32
#define S_PG    512
#define NE      262144
#define EPG     8192      // edges per graph
#define D       256
#define D2      512
#define D3      768
#define NL      4
#define NH      4
#define DHD     64
#define OUTD    768

// ---------------- Atom encoder: h[n,d] = sum_f atom_tab[f, x[n,f], d] ----------------
__global__ __launch_bounds__(256) void k_atom_enc(const int* __restrict__ x,
                                                  const float* __restrict__ tab,
                                                  float* __restrict__ h) {
    int node = blockIdx.x * 4 + (threadIdx.x >> 6);
    int lane = threadIdx.x & 63;
    int dd = lane << 2;
    float4 acc = {0.f, 0.f, 0.f, 0.f};
#pragma unroll
    for (int f = 0; f < 9; ++f) {
        int v = x[node * 9 + f];
        const float4 t = *(const float4*)&tab[((size_t)(f * 119 + v)) * D + dd];
        acc.x += t.x; acc.y += t.y; acc.z += t.z; acc.w += t.w;
    }
    *(float4*)&h[(size_t)node * D + dd] = acc;
}

// ---------------- bw[l,fv,dout] = dot(bond_tab[fv,:], elin_w[l,:,dout]) ----------------
__global__ __launch_bounds__(256) void k_bondw(const float* __restrict__ bond_tab,
                                               const float* __restrict__ elin_w,
                                               float* __restrict__ bw) {
    int blk = blockIdx.x;         // L*66
    int l = blk / 66, fv = blk % 66;
    int dout = threadIdx.x;
    const float* tabrow = bond_tab + (size_t)fv * D;
    const float* w = elin_w + (size_t)l * D * D;
    float acc = 0.f;
    for (int d = 0; d < D; ++d) acc = fmaf(tabrow[d], w[d * D + dout], acc);
    bw[((size_t)l * 66 + fv) * D + dout] = acc;
}

// ---------------- GINE aggregation, LDS-resident per (graph, 16-dim slice) ----------------
// agg[n,:] = (1+eps[l]) * h[n,:] + sum_{e: dst(e)=n} relu(h[src(e),:] + bias_e)
__global__ __launch_bounds__(256) void k_edge_lds(const float* __restrict__ h,
                                                  const float* __restrict__ bw,
                                                  const float* __restrict__ elin_b,
                                                  const float* __restrict__ eps, int l,
                                                  const int* __restrict__ ea,
                                                  const int* __restrict__ src,
                                                  const int* __restrict__ dst,
                                                  float* __restrict__ agg) {
    __shared__ float acc[S_PG * 17];            // 512 nodes x 16 dims, stride 17 (bank spread)
    const int g  = blockIdx.x >> 4;             // graph
    const int sl = blockIdx.x & 15;             // 16-dim slice
    const int d0 = sl << 4;
    const int tid = threadIdx.x;

    for (int i = tid; i < S_PG * 17; i += 256) acc[i] = 0.f;
    __syncthreads();

    const int e0 = g * EPG;
    const int node0 = g * S_PG;
    const int sub = (tid & 3) << 2;             // 0,4,8,12 within slice
    const int dd = d0 + sub;
    const float4 eb = *(const float4*)&elin_b[dd];

    for (int it = 0; it < EPG / 64; ++it) {
        int e = e0 + it * 64 + (tid >> 2);
        int s = src[e], dt = dst[e];
        int a0 = ea[e * 3], a1 = ea[e * 3 + 1], a2 = ea[e * 3 + 2];
        float4 v  = *(const float4*)&h[(size_t)s * D + dd];
        float4 b0 = *(const float4*)&bw[(size_t)a0 * D + dd];
        float4 b1 = *(const float4*)&bw[(size_t)(22 + a1) * D + dd];
        float4 b2 = *(const float4*)&bw[(size_t)(44 + a2) * D + dd];
        float m0 = fmaxf(v.x + b0.x + b1.x + b2.x + eb.x, 0.f);
        float m1 = fmaxf(v.y + b0.y + b1.y + b2.y + eb.y, 0.f);
        float m2 = fmaxf(v.z + b0.z + b1.z + b2.z + eb.z, 0.f);
        float m3 = fmaxf(v.w + b0.w + b1.w + b2.w + eb.w, 0.f);
        float* p = &acc[(dt - node0) * 17 + sub];
        atomicAdd(p + 0, m0); atomicAdd(p + 1, m1);
        atomicAdd(p + 2, m2); atomicAdd(p + 3, m3);
    }
    __syncthreads();

    const float s1p = 1.f + eps[l];
    for (int n = tid; n < S_PG; n += 256) {
        const float* arow = &acc[n * 17];
        float* orow = &agg[(size_t)(node0 + n) * D + d0];
        const float* hrow = &h[(size_t)(node0 + n) * D + d0];
#pragma unroll
        for (int q = 0; q < 4; ++q) {
            float4 hv = *(const float4*)&hrow[q * 4];
            float4 ov;
            ov.x = s1p * hv.x + arow[q * 4 + 0];
            ov.y = s1p * hv.y + arow[q * 4 + 1];
            ov.z = s1p * hv.z + arow[q * 4 + 2];
            ov.w = s1p * hv.w + arow[q * 4 + 3];
            *(float4*)&orow[q * 4] = ov;
        }
    }
}

// ---------------- generic fp32 GEMM: C = op(A@B + bias [+ res]) ----------------
// A [M,K] row-major, B [K,N] row-major, 128x128 tile, 8x8 per thread
template<int RELU, int HASRES>
__global__ __launch_bounds__(256) void k_gemm(const float* __restrict__ A,
                                              const float* __restrict__ B,
                                              const float* __restrict__ bias,
                                              const float* __restrict__ res,
                                              float* __restrict__ C,
                                              int M, int N, int K) {
    __shared__ float As[16][128];
    __shared__ float Bs[16][128];
    const int tid = threadIdx.x;
    const int row0 = blockIdx.y * 128, col0 = blockIdx.x * 128;
    float acc[8][8] = {};
    const int ar = tid >> 2;            // 0..63
    const int ak = (tid & 3) << 2;      // 0,4,8,12
    const int bk = tid >> 5;            // 0..7
    const int bc = (tid & 31) << 2;     // 0..124
    const int ty = tid >> 4, tx = tid & 15;
    for (int k0 = 0; k0 < K; k0 += 16) {
        float4 a0 = *(const float4*)&A[(size_t)(row0 + ar) * K + k0 + ak];
        float4 a1 = *(const float4*)&A[(size_t)(row0 + ar + 64) * K + k0 + ak];
        float4 b0 = *(const float4*)&B[(size_t)(k0 + bk) * N + col0 + bc];
        float4 b1 = *(const float4*)&B[(size_t)(k0 + bk + 8) * N + col0 + bc];
        As[ak + 0][ar] = a0.x; As[ak + 1][ar] = a0.y; As[ak + 2][ar] = a0.z; As[ak + 3][ar] = a0.w;
        As[ak + 0][ar + 64] = a1.x; As[ak + 1][ar + 64] = a1.y; As[ak + 2][ar + 64] = a1.z; As[ak + 3][ar + 64] = a1.w;
        *(float4*)&Bs[bk][bc] = b0;
        *(float4*)&Bs[bk + 8][bc] = b1;
        __syncthreads();
#pragma unroll
        for (int kk = 0; kk < 16; ++kk) {
            float a[8], b[8];
            *(float4*)&a[0] = *(const float4*)&As[kk][ty * 8];
            *(float4*)&a[4] = *(const float4*)&As[kk][ty * 8 + 4];
            *(float4*)&b[0] = *(const float4*)&Bs[kk][tx * 8];
            *(float4*)&b[4] = *(const float4*)&Bs[kk][tx * 8 + 4];
#pragma unroll
            for (int i = 0; i < 8; ++i)
#pragma unroll
                for (int j = 0; j < 8; ++j) acc[i][j] = fmaf(a[i], b[j], acc[i][j]);
        }
        __syncthreads();
    }
#pragma unroll
    for (int i = 0; i < 8; ++i) {
        int r = row0 + ty * 8 + i;
#pragma unroll
        for (int j4 = 0; j4 < 8; j4 += 4) {
            int c = col0 + tx * 8 + j4;
            float4 v;
            v.x = acc[i][j4 + 0]; v.y = acc[i][j4 + 1];
            v.z = acc[i][j4 + 2]; v.w = acc[i][j4 + 3];
            const float4 bb = *(const float4*)&bias[c];
            v.x += bb.x; v.y += bb.y; v.z += bb.z; v.w += bb.w;
            if (HASRES) {
                const float4 rr = *(const float4*)&res[(size_t)r * N + c];
                v.x += rr.x; v.y += rr.y; v.z += rr.z; v.w += rr.w;
            }
            if (RELU) {
                v.x = fmaxf(v.x, 0.f); v.y = fmaxf(v.y, 0.f);
                v.z = fmaxf(v.z, 0.f); v.w = fmaxf(v.w, 0.f);
            }
            *(float4*)&C[(size_t)r * N + c] = v;
        }
    }
}

// ---------------- BatchNorm: two-stage stats + apply ----------------
__global__ __launch_bounds__(256) void k_bn_stat1(const float* __restrict__ x,
                                                  float* __restrict__ part) {
    int c = threadIdx.x;
    int blk = blockIdx.x;                    // 128 blocks x 128 rows
    const float* p = x + (size_t)blk * 128 * D + c;
    float s = 0.f, s2 = 0.f;
    for (int r = 0; r < 128; ++r) { float v = p[(size_t)r * D]; s += v; s2 += v * v; }
    part[blk * 2 * D + c] = s;
    part[blk * 2 * D + D + c] = s2;
}

__global__ __launch_bounds__(256) void k_bn_stat2(const float* __restrict__ part,
                                                  float* __restrict__ ms) {
    int c = threadIdx.x;
    float s = 0.f, s2 = 0.f;
    for (int p = 0; p < 128; ++p) { s += part[p * 2 * D + c]; s2 += part[p * 2 * D + D + c]; }
    float mean = s / (float)N_NODES;
    float var = s2 / (float)N_NODES - mean * mean;
    ms[c] = mean;
    ms[D + c] = rsqrtf(var + 1e-5f);
}

// ADD=0: y = bn(x).  ADD=1: y += bn(x)  (y may alias x only when ADD=0)
template<int ADD>
__global__ __launch_bounds__(256) void k_bn_apply(const float* __restrict__ x,
                                                  const float* __restrict__ ms,
                                                  const float* __restrict__ g,
                                                  const float* __restrict__ b,
                                                  float* __restrict__ y) {
    size_t i4 = (size_t)blockIdx.x * blockDim.x + threadIdx.x;
    int c = (int)((i4 & 63) << 2);
    float4 v = ((const float4*)x)[i4];
    v.x = (v.x - ms[c + 0]) * ms[D + c + 0] * g[c + 0] + b[c + 0];
    v.y = (v.y - ms[c + 1]) * ms[D + c + 1] * g[c + 1] + b[c + 1];
    v.z = (v.z - ms[c + 2]) * ms[D + c + 2] * g[c + 2] + b[c + 2];
    v.w = (v.w - ms[c + 3]) * ms[D + c + 3] * g[c + 3] + b[c + 3];
    if (ADD) {
        float4 o = ((const float4*)y)[i4];
        v.x += o.x; v.y += o.y; v.z += o.z; v.w += o.w;
    }
    ((float4*)y)[i4] = v;
}

// ---------------- flash attention: per block = one (b,h), 64 q-rows, full S loop ----------------
__global__ __launch_bounds__(256) void k_flash(const float* __restrict__ qkv,
                                               float* __restrict__ ao) {
    __shared__ float Qs[64][65];
    __shared__ float KPs[64][65];   // K tile, then reused for P tile
    __shared__ float Vs[64][65];
    int bh = blockIdx.x;
    int b = bh >> 2, hh = bh & 3;
    int i0 = blockIdx.y << 6;
    int tid = threadIdx.x;
    int ty = tid >> 4, tx = tid & 15;
    int rr = tid >> 4, c4 = (tid & 15) << 2;
    const size_t base = (size_t)(b * S_PG) * D3 + (size_t)hh * DHD;

#pragma unroll
    for (int p = 0; p < 4; ++p) {
        int r = rr + p * 16;
        float4 q = *(const float4*)&qkv[base + (size_t)(i0 + r) * D3 + c4];
        Qs[r][c4] = q.x; Qs[r][c4 + 1] = q.y; Qs[r][c4 + 2] = q.z; Qs[r][c4 + 3] = q.w;
    }

    float m[4] = {-INFINITY, -INFINITY, -INFINITY, -INFINITY};
    float l[4] = {0.f, 0.f, 0.f, 0.f};
    float o[4][4] = {};

    for (int j0 = 0; j0 < S_PG; j0 += 64) {
#pragma unroll
        for (int p = 0; p < 4; ++p) {
            int r = rr + p * 16;
            float4 kk = *(const float4*)&qkv[base + D + (size_t)(j0 + r) * D3 + c4];
            KPs[r][c4] = kk.x; KPs[r][c4 + 1] = kk.y; KPs[r][c4 + 2] = kk.z; KPs[r][c4 + 3] = kk.w;
            float4 vv = *(const float4*)&qkv[base + D2 + (size_t)(j0 + r) * D3 + c4];
            Vs[r][c4] = vv.x; Vs[r][c4 + 1] = vv.y; Vs[r][c4 + 2] = vv.z; Vs[r][c4 + 3] = vv.w;
        }
        __syncthreads();
        // scores s[i][j] for q-rows ty*4+i, k-rows tx*4+j
        float s[4][4] = {};
        for (int k = 0; k < 64; ++k) {
            float a[4], bb[4];
#pragma unroll
            for (int i = 0; i < 4; ++i) a[i] = Qs[ty * 4 + i][k];
#pragma unroll
            for (int j = 0; j < 4; ++j) bb[j] = KPs[tx * 4 + j][k];
#pragma unroll
            for (int i = 0; i < 4; ++i)
#pragma unroll
                for (int j = 0; j < 4; ++j) s[i][j] = fmaf(a[i], bb[j], s[i][j]);
        }
        float pv[4][4], alpha[4];
#pragma unroll
        for (int i = 0; i < 4; ++i) {
            float pm = -INFINITY;
#pragma unroll
            for (int j = 0; j < 4; ++j) { s[i][j] *= 0.125f; pm = fmaxf(pm, s[i][j]); }
#pragma unroll
            for (int off = 1; off < 16; off <<= 1) pm = fmaxf(pm, __shfl_xor(pm, off));
            float mn = fmaxf(m[i], pm);
            alpha[i] = __expf(m[i] - mn);           // exp(-inf - finite) = 0 on first tile
            float rs = 0.f;
#pragma unroll
            for (int j = 0; j < 4; ++j) { pv[i][j] = __expf(s[i][j] - mn); rs += pv[i][j]; }
#pragma unroll
            for (int off = 1; off < 16; off <<= 1) rs += __shfl_xor(rs, off);
            l[i] = l[i] * alpha[i] + rs;
            m[i] = mn;
        }
        __syncthreads();   // everyone done reading K before overwriting with P
#pragma unroll
        for (int i = 0; i < 4; ++i)
#pragma unroll
            for (int j = 0; j < 4; ++j) KPs[ty * 4 + i][tx * 4 + j] = pv[i][j];
#pragma unroll
        for (int i = 0; i < 4; ++i)
#pragma unroll
            for (int d = 0; d < 4; ++d) o[i][d] *= alpha[i];
        __syncthreads();   // P ready
        for (int j = 0; j < 64; ++j) {
            float a[4], bb[4];
#pragma unroll
            for (int i = 0; i < 4; ++i) a[i] = KPs[ty * 4 + i][j];
#pragma unroll
            for (int d = 0; d < 4; ++d) bb[d] = Vs[j][tx * 4 + d];
#pragma unroll
            for (int i = 0; i < 4; ++i)
#pragma unroll
                for (int d = 0; d < 4; ++d) o[i][d] = fmaf(a[i], bb[d], o[i][d]);
        }
        __syncthreads();   // done with P,V before next tile load
    }
#pragma unroll
    for (int i = 0; i < 4; ++i) {
        float inv = 1.f / l[i];
        int node = b * S_PG + i0 + ty * 4 + i;
        float4 v;
        v.x = o[i][0] * inv; v.y = o[i][1] * inv; v.z = o[i][2] * inv; v.w = o[i][3] * inv;
        *(float4*)&ao[(size_t)node * D + hh * DHD + tx * 4] = v;
    }
}

// ---------------- mean pool per graph ----------------
__global__ __launch_bounds__(256) void k_pool(const float* __restrict__ h, float* __restrict__ g) {
    int b = blockIdx.x, c = threadIdx.x;
    const float* p = h + (size_t)b * S_PG * D + c;
    float s = 0.f;
    for (int r = 0; r < S_PG; ++r) s += p[(size_t)r * D];
    g[b * D + c] = s * (1.f / (float)S_PG);
}

// ---------------- final head: z = relu(g@pw1+pb1)@pw2+pb2; z /= ||z|| ----------------
__global__ __launch_bounds__(256) void k_final(const float* __restrict__ g,
                                               const float* __restrict__ pw1,
                                               const float* __restrict__ pb1,
                                               const float* __restrict__ pw2,
                                               const float* __restrict__ pb2,
                                               float* __restrict__ out) {
    __shared__ float gs[D];
    __shared__ float ts[D];
    __shared__ float red[4];
    int b = blockIdx.x, tid = threadIdx.x;
    gs[tid] = g[b * D + tid];
    __syncthreads();
    float acc = pb1[tid];
    for (int d = 0; d < D; ++d) acc = fmaf(gs[d], pw1[d * D + tid], acc);
    ts[tid] = fmaxf(acc, 0.f);
    __syncthreads();
    float z[3];
#pragma unroll
    for (int rep = 0; rep < 3; ++rep) {
        int j = tid + rep * 256;
        float a = pb2[j];
        for (int d = 0; d < D; ++d) a = fmaf(ts[d], pw2[(size_t)d * OUTD + j], a);
        z[rep] = a;
    }
    float ss = z[0] * z[0] + z[1] * z[1] + z[2] * z[2];
#pragma unroll
    for (int o = 32; o >= 1; o >>= 1) ss += __shfl_xor(ss, o);
    if ((tid & 63) == 0) red[tid >> 6] = ss;
    __syncthreads();
    float rn = rsqrtf(red[0] + red[1] + red[2] + red[3]);
#pragma unroll
    for (int rep = 0; rep < 3; ++rep) out[b * OUTD + tid + rep * 256] = z[rep] * rn;
}

extern "C" void kernel_launch(void* const* d_in, const int* in_sizes, int n_in,
                              void* d_out, int out_size, void* d_ws, size_t ws_size,
                              hipStream_t stream) {
    const int* x        = (const int*)d_in[0];
    const int* ea       = (const int*)d_in[1];
    const int* eidx     = (const int*)d_in[2];
    const float* atom_tab = (const float*)d_in[4];
    const float* bond_tab = (const float*)d_in[5];
    const float* elin_w = (const float*)d_in[6];
    const float* elin_b = (const float*)d_in[7];
    const float* eps    = (const float*)d_in[8];
    const float* gw1    = (const float*)d_in[9];
    const float* gb1    = (const float*)d_in[10];
    const float* gw2    = (const float*)d_in[11];
    const float* gb2    = (const float*)d_in[12];
    const float* aw_in  = (const float*)d_in[13];
    const float* ab_in  = (const float*)d_in[14];
    const float* aw_out = (const float*)d_in[15];
    const float* ab_out = (const float*)d_in[16];
    const float* n1g    = (const float*)d_in[17];
    const float* n1b    = (const float*)d_in[18];
    const float* n2g    = (const float*)d_in[19];
    const float* n2b    = (const float*)d_in[20];
    const float* n3g    = (const float*)d_in[21];
    const float* n3b    = (const float*)d_in[22];
    const float* mw1    = (const float*)d_in[23];
    const float* mb1    = (const float*)d_in[24];
    const float* mw2    = (const float*)d_in[25];
    const float* mb2    = (const float*)d_in[26];
    const float* pw1    = (const float*)d_in[27];
    const float* pb1    = (const float*)d_in[28];
    const float* pw2    = (const float*)d_in[29];
    const float* pb2    = (const float*)d_in[30];

    // ---- compact workspace layout (~97 MiB) ----
    char* ws = (char*)d_ws;
    size_t off = 0;
    auto alloc = [&](size_t bytes) {
        void* p = ws + off;
        off += (bytes + 255) & ~(size_t)255;
        return p;
    };
    float* h    = (float*)alloc((size_t)N_NODES * D * 4);    // 16 MiB, layer state
    float* bufA = (float*)alloc((size_t)N_NODES * D * 4);    // 16 MiB: agg, then ao
    float* bufB = (float*)alloc((size_t)N_NODES * D * 4);    // 16 MiB: pre-bn1 -> hc -> out
    float* uni  = (float*)alloc((size_t)N_NODES * D3 * 4);   // 48 MiB: hidden512 / qkv / pre-bn2
    float* bw   = (float*)alloc((size_t)NL * 66 * D * 4);
    float* part = (float*)alloc((size_t)128 * 2 * D * 4);
    float* ms   = (float*)alloc((size_t)2 * D * 4);
    float* g    = (float*)alloc((size_t)NB * D * 4);
    (void)ws_size; (void)in_sizes; (void)n_in; (void)out_size;

    const int* srcp = eidx;
    const int* dstp = eidx + NE;
    const int EW = N_NODES * D / 1024;  // grid for 1-float4-per-thread elementwise

    k_atom_enc<<<N_NODES / 4, 256, 0, stream>>>(x, atom_tab, h);
    k_bondw<<<NL * 66, 256, 0, stream>>>(bond_tab, elin_w, bw);

    for (int l = 0; l < NL; ++l) {
        // --- GINE local branch (LDS-accumulated scatter, fused (1+eps)h) ---
        k_edge_lds<<<NB * 16, 256, 0, stream>>>(h, bw + (size_t)l * 66 * D, elin_b + l * D,
                                                eps, l, ea, srcp, dstp, bufA);
        k_gemm<1, 0><<<dim3(D2 / 128, N_NODES / 128), 256, 0, stream>>>(
            bufA, gw1 + (size_t)l * D * D2, gb1 + l * D2, nullptr, uni, N_NODES, D2, D);
        k_gemm<0, 1><<<dim3(D / 128, N_NODES / 128), 256, 0, stream>>>(
            uni, gw2 + (size_t)l * D2 * D, gb2 + l * D, h, bufB, N_NODES, D, D2);
        k_bn_stat1<<<128, 256, 0, stream>>>(bufB, part);
        k_bn_stat2<<<1, 256, 0, stream>>>(part, ms);
        k_bn_apply<0><<<EW, 256, 0, stream>>>(bufB, ms, n1g + l * D, n1b + l * D, bufB); // hc in-place
        // --- global attention (flash) ---
        k_gemm<0, 0><<<dim3(D3 / 128, N_NODES / 128), 256, 0, stream>>>(
            h, aw_in + (size_t)l * D * D3, ab_in + l * D3, nullptr, uni, N_NODES, D3, D);
        k_flash<<<dim3(NB * NH, S_PG / 64), 256, 0, stream>>>(uni, bufA);
        k_gemm<0, 1><<<dim3(D / 128, N_NODES / 128), 256, 0, stream>>>(
            bufA, aw_out + (size_t)l * D * D, ab_out + l * D, h, uni, N_NODES, D, D);  // pre-bn2
        k_bn_stat1<<<128, 256, 0, stream>>>(uni, part);
        k_bn_stat2<<<1, 256, 0, stream>>>(part, ms);
        k_bn_apply<1><<<EW, 256, 0, stream>>>(uni, ms, n2g + l * D, n2b + l * D, bufB); // bufB=hc+ha
        // --- combine + MLP ---
        k_gemm<1, 0><<<dim3(D2 / 128, N_NODES / 128), 256, 0, stream>>>(
            bufB, mw1 + (size_t)l * D * D2, mb1 + l * D2, nullptr, uni, N_NODES, D2, D);
        k_gemm<0, 1><<<dim3(D / 128, N_NODES / 128), 256, 0, stream>>>(
            uni, mw2 + (size_t)l * D2 * D, mb2 + l * D, bufB, h, N_NODES, D, D2);
        k_bn_stat1<<<128, 256, 0, stream>>>(h, part);
        k_bn_stat2<<<1, 256, 0, stream>>>(part, ms);
        k_bn_apply<0><<<EW, 256, 0, stream>>>(h, ms, n3g + l * D, n3b + l * D, h);      // in-place
    }
    k_pool<<<NB, 256, 0, stream>>>(h, g);
    k_final<<<NB, 256, 0, stream>>>(g, pw1, pb1, pw2, pb2, (float*)d_out);
}

// Round 4
// 1755.159 us; speedup vs baseline: 3.5323x; 2.2846x over previous
//
#include <hip/hip_runtime.h>
#include <hip/hip_bf16.h>
#include <math.h>

#define N_NODES 16384
#define NB      32
#define S_PG    512
#define NE      262144
#define EPG     8192
#define D       256
#define D2      512
#define D3      768
#define NL      4
#define NH      4
#define DHD     64
#define OUTD    768
#define NCOMBO  264
#define WT_PER_LAYER 786432

typedef short s8v __attribute__((ext_vector_type(8)));
typedef float f4v __attribute__((ext_vector_type(4)));

__device__ __forceinline__ unsigned bfr(float f) {   // fp32 -> bf16 bits, RNE
    unsigned u = __float_as_uint(f);
    return (u + 0x7fffu + ((u >> 16) & 1u)) >> 16;
}
__device__ __forceinline__ float b2f(unsigned short u) {
    return __uint_as_float(((unsigned)u) << 16);
}

// ---------------- Atom encoder ----------------
__global__ __launch_bounds__(256) void k_atom_enc(const int* __restrict__ x,
                                                  const float* __restrict__ tab,
                                                  float* __restrict__ h) {
    int node = blockIdx.x * 4 + (threadIdx.x >> 6);
    int lane = threadIdx.x & 63;
    int dd = lane << 2;
    float4 acc = {0.f, 0.f, 0.f, 0.f};
#pragma unroll
    for (int f = 0; f < 9; ++f) {
        int v = x[node * 9 + f];
        const float4 t = *(const float4*)&tab[((size_t)(f * 119 + v)) * D + dd];
        acc.x += t.x; acc.y += t.y; acc.z += t.z; acc.w += t.w;
    }
    *(float4*)&h[(size_t)node * D + dd] = acc;
}

// ---------------- bw[l,fv,:] = bond_tab[fv,:] @ elin_w[l] ----------------
__global__ __launch_bounds__(256) void k_bondw(const float* __restrict__ bond_tab,
                                               const float* __restrict__ elin_w,
                                               float* __restrict__ bw) {
    int blk = blockIdx.x;         // L*66
    int l = blk / 66, fv = blk % 66;
    int dout = threadIdx.x;
    const float* tabrow = bond_tab + (size_t)fv * D;
    const float* w = elin_w + (size_t)l * D * D;
    float acc = 0.f;
    for (int d = 0; d < D; ++d) acc = fmaf(tabrow[d], w[d * D + dout], acc);
    bw[((size_t)l * 66 + fv) * D + dout] = acc;
}

// ---------------- combo table: ct[l,cid,:] = bw0[a0]+bw1[a1]+bw2[a2]+elin_b[l] ----------------
__global__ __launch_bounds__(256) void k_combo(const float* __restrict__ bw,
                                               const float* __restrict__ elin_b,
                                               float* __restrict__ ct) {
    int b = blockIdx.x;           // NL*264
    int l = b / NCOMBO, cid = b % NCOMBO;
    int a0 = cid / 12, a1 = (cid % 12) / 2, a2 = cid & 1;
    int d = threadIdx.x;
    const float* bwl = bw + (size_t)l * 66 * D;
    ct[((size_t)l * NCOMBO + cid) * D + d] =
        bwl[(size_t)a0 * D + d] + bwl[(size_t)(22 + a1) * D + d] +
        bwl[(size_t)(44 + a2) * D + d] + elin_b[(size_t)l * D + d];
}

// ---------------- CSR build ----------------
__global__ __launch_bounds__(256) void k_zero16k(int* __restrict__ p) {
    p[blockIdx.x * 256 + threadIdx.x] = 0;
}
__global__ __launch_bounds__(256) void k_hist(const int* __restrict__ dst, int* __restrict__ deg) {
    int e = blockIdx.x * 256 + threadIdx.x;
    atomicAdd(&deg[dst[e]], 1);
}
__global__ __launch_bounds__(256) void k_scan(const int* __restrict__ deg,
                                              int* __restrict__ row_ptr,
                                              int* __restrict__ cursor) {
    __shared__ int partial[256];
    int t = threadIdx.x;
    int base = t * 64;
    int s = 0;
    for (int i = 0; i < 64; ++i) s += deg[base + i];
    partial[t] = s;
    __syncthreads();
    for (int dstp = 1; dstp < 256; dstp <<= 1) {
        int v = (t >= dstp) ? partial[t - dstp] : 0;
        __syncthreads();
        partial[t] += v;
        __syncthreads();
    }
    int run = partial[t] - s;   // exclusive start of this chunk
    for (int i = 0; i < 64; ++i) {
        int dcur = deg[base + i];
        row_ptr[base + i] = run;
        cursor[base + i] = run;
        run += dcur;
    }
    if (t == 255) row_ptr[N_NODES] = run;
}
__global__ __launch_bounds__(256) void k_scatter(const int* __restrict__ src,
                                                 const int* __restrict__ dst,
                                                 const int* __restrict__ ea,
                                                 int* __restrict__ cursor,
                                                 int2* __restrict__ sorted) {
    int e = blockIdx.x * 256 + threadIdx.x;
    int d = dst[e];
    int pos = atomicAdd(&cursor[d], 1);
    int cid = ea[e * 3] * 12 + ea[e * 3 + 1] * 2 + ea[e * 3 + 2];
    sorted[pos] = make_int2(src[e], cid);
}

// ---------------- GINE aggregation (gather, no atomics): one wave per node ----------------
__global__ __launch_bounds__(256) void k_gine_agg(const float* __restrict__ h,
                                                  const float* __restrict__ ct,   // this layer's 264x256
                                                  const float* __restrict__ eps, int l,
                                                  const int* __restrict__ row_ptr,
                                                  const int2* __restrict__ sorted,
                                                  unsigned short* __restrict__ aggb) {
    int w = threadIdx.x >> 6;
    int lane = threadIdx.x & 63;
    int n = blockIdx.x * 4 + w;
    int dd = lane << 2;
    int beg = row_ptr[n], end = row_ptr[n + 1];
    float4 acc = {0.f, 0.f, 0.f, 0.f};
    for (int i = beg; i < end; ++i) {
        int2 e = sorted[i];
        float4 hv = *(const float4*)&h[(size_t)e.x * D + dd];
        float4 cv = *(const float4*)&ct[(size_t)e.y * D + dd];
        acc.x += fmaxf(hv.x + cv.x, 0.f);
        acc.y += fmaxf(hv.y + cv.y, 0.f);
        acc.z += fmaxf(hv.z + cv.z, 0.f);
        acc.w += fmaxf(hv.w + cv.w, 0.f);
    }
    float s1p = 1.f + eps[l];
    float4 hn = *(const float4*)&h[(size_t)n * D + dd];
    ushort4 o;
    o.x = (unsigned short)bfr(s1p * hn.x + acc.x);
    o.y = (unsigned short)bfr(s1p * hn.y + acc.y);
    o.z = (unsigned short)bfr(s1p * hn.z + acc.z);
    o.w = (unsigned short)bfr(s1p * hn.w + acc.w);
    *(ushort4*)&aggb[(size_t)n * D + dd] = o;
}

// ---------------- weight transpose+convert: W[K][N] f32 -> WT[N][K] bf16 ----------------
__global__ __launch_bounds__(256) void k_wcvt(const float* __restrict__ gw1, const float* __restrict__ gw2,
                                              const float* __restrict__ aw_in, const float* __restrict__ aw_out,
                                              const float* __restrict__ mw1, const float* __restrict__ mw2,
                                              unsigned short* __restrict__ WT) {
    const int KS[6]   = {256, 512, 256, 256, 256, 512};
    const int NS[6]   = {512, 256, 768, 256, 512, 256};
    const int TOFF[7] = {0, 128, 256, 448, 512, 640, 768};
    const int DOFF[6] = {0, 131072, 262144, 458752, 524288, 655360};
    int b = blockIdx.x;
    int l = b / 768, wb = b % 768;
    int widx = 0;
    while (wb >= TOFF[widx + 1]) ++widx;
    int t = wb - TOFF[widx];
    int K = KS[widx], N = NS[widx];
    int nn = N / 32;
    int kt = t / nn, nt = t % nn;
    const float* srcs[6] = {gw1, gw2, aw_in, aw_out, mw1, mw2};
    const float* W = srcs[widx] + (size_t)l * K * N;
    unsigned short* WTp = WT + (size_t)l * WT_PER_LAYER + DOFF[widx];
    __shared__ float tile[32][33];
    int tid = threadIdx.x;
    int r = tid >> 3, c4 = (tid & 7) << 2;
    float4 v = *(const float4*)&W[(size_t)(kt * 32 + r) * N + nt * 32 + c4];
    tile[r][c4] = v.x; tile[r][c4 + 1] = v.y; tile[r][c4 + 2] = v.z; tile[r][c4 + 3] = v.w;
    __syncthreads();
    int nr = tid >> 3, kc = (tid & 7) << 2;
    ushort4 o;
    o.x = (unsigned short)bfr(tile[kc + 0][nr]);
    o.y = (unsigned short)bfr(tile[kc + 1][nr]);
    o.z = (unsigned short)bfr(tile[kc + 2][nr]);
    o.w = (unsigned short)bfr(tile[kc + 3][nr]);
    *(ushort4*)&WTp[(size_t)(nt * 32 + nr) * K + kt * 32 + kc] = o;
}

// ---------------- bf16 MFMA GEMM: C = op(A @ B + bias [+ res]) ----------------
// A: [M][K] bf16 (ABF=1) or f32 (ABF=0).  B: WT [N][K] bf16.  bias/res f32.
// 128x128 tile, 4 waves (2x2), each wave 64x64 via 4x4 x mfma_16x16x32_bf16.
template<int ABF, int RELU, int RES, int OBF>
__global__ __launch_bounds__(256) void k_mm(const void* __restrict__ Ap,
                                            const unsigned short* __restrict__ BT,
                                            const float* __restrict__ bias,
                                            const float* __restrict__ res,
                                            void* __restrict__ Cp,
                                            int M, int N, int K) {
    __shared__ unsigned short As[128][40];
    __shared__ unsigned short Bs[128][40];
    const int tid = threadIdx.x;
    const int row0 = blockIdx.y * 128, col0 = blockIdx.x * 128;
    const int l = tid & 63;
    const int w = tid >> 6;
    const int wm = w >> 1, wn = w & 1;
    const int srow = tid >> 1;            // 0..127 staging row (A) / col (B)
    const int skq = (tid & 1) * 16;       // staging k offset
    const int lr = l & 15, lq = l >> 4;
    const int koff = lq * 8;
    f4v acc[4][4] = {};

    for (int k0 = 0; k0 < K; k0 += 32) {
        if (ABF) {
            const unsigned short* Ab = (const unsigned short*)Ap;
            const unsigned short* ar = &Ab[(size_t)(row0 + srow) * K + k0 + skq];
            uint4 u0 = *(const uint4*)&ar[0];
            uint4 u1 = *(const uint4*)&ar[8];
            *(uint4*)&As[srow][skq] = u0;
            *(uint4*)&As[srow][skq + 8] = u1;
        } else {
            const float* Af = (const float*)Ap;
            const float* ar = &Af[(size_t)(row0 + srow) * K + k0 + skq];
            float4 f0 = *(const float4*)&ar[0];
            float4 f1 = *(const float4*)&ar[4];
            float4 f2 = *(const float4*)&ar[8];
            float4 f3 = *(const float4*)&ar[12];
            uint4 u0, u1;
            u0.x = bfr(f0.x) | (bfr(f0.y) << 16); u0.y = bfr(f0.z) | (bfr(f0.w) << 16);
            u0.z = bfr(f1.x) | (bfr(f1.y) << 16); u0.w = bfr(f1.z) | (bfr(f1.w) << 16);
            u1.x = bfr(f2.x) | (bfr(f2.y) << 16); u1.y = bfr(f2.z) | (bfr(f2.w) << 16);
            u1.z = bfr(f3.x) | (bfr(f3.y) << 16); u1.w = bfr(f3.z) | (bfr(f3.w) << 16);
            *(uint4*)&As[srow][skq] = u0;
            *(uint4*)&As[srow][skq + 8] = u1;
        }
        {
            const unsigned short* br = &BT[(size_t)(col0 + srow) * K + k0 + skq];
            uint4 u0 = *(const uint4*)&br[0];
            uint4 u1 = *(const uint4*)&br[8];
            *(uint4*)&Bs[srow][skq] = u0;
            *(uint4*)&Bs[srow][skq + 8] = u1;
        }
        __syncthreads();
        s8v af[4], bf[4];
#pragma unroll
        for (int m = 0; m < 4; ++m) af[m] = *(const s8v*)&As[wm * 64 + m * 16 + lr][koff];
#pragma unroll
        for (int n = 0; n < 4; ++n) bf[n] = *(const s8v*)&Bs[wn * 64 + n * 16 + lr][koff];
#pragma unroll
        for (int m = 0; m < 4; ++m)
#pragma unroll
            for (int n = 0; n < 4; ++n)
                acc[m][n] = __builtin_amdgcn_mfma_f32_16x16x32_bf16(af[m], bf[n], acc[m][n], 0, 0, 0);
        __syncthreads();
    }
#pragma unroll
    for (int n = 0; n < 4; ++n) {
        int c = col0 + wn * 64 + n * 16 + lr;
        float bv = bias[c];
#pragma unroll
        for (int m = 0; m < 4; ++m) {
#pragma unroll
            for (int j = 0; j < 4; ++j) {
                int r = row0 + wm * 64 + m * 16 + lq * 4 + j;
                float v = acc[m][n][j] + bv;
                if (RES) v += res[(size_t)r * N + c];
                if (RELU) v = fmaxf(v, 0.f);
                if (OBF) ((unsigned short*)Cp)[(size_t)r * N + c] = (unsigned short)bfr(v);
                else ((float*)Cp)[(size_t)r * N + c] = v;
            }
        }
    }
}

// ---------------- BatchNorm: two-stage stats + apply ----------------
__global__ __launch_bounds__(256) void k_bn_stat1(const float* __restrict__ x,
                                                  float* __restrict__ part) {
    int c = threadIdx.x;
    int blk = blockIdx.x;                    // 128 blocks x 128 rows
    const float* p = x + (size_t)blk * 128 * D + c;
    float s = 0.f, s2 = 0.f;
    for (int r = 0; r < 128; ++r) { float v = p[(size_t)r * D]; s += v; s2 += v * v; }
    part[blk * 2 * D + c] = s;
    part[blk * 2 * D + D + c] = s2;
}

__global__ __launch_bounds__(256) void k_bn_stat2(const float* __restrict__ part,
                                                  float* __restrict__ ms) {
    int c = threadIdx.x;
    float s = 0.f, s2 = 0.f;
    for (int p = 0; p < 128; ++p) { s += part[p * 2 * D + c]; s2 += part[p * 2 * D + D + c]; }
    float mean = s / (float)N_NODES;
    float var = s2 / (float)N_NODES - mean * mean;
    ms[c] = mean;
    ms[D + c] = rsqrtf(var + 1e-5f);
}

template<int ADD>
__global__ __launch_bounds__(256) void k_bn_apply(const float* __restrict__ x,
                                                  const float* __restrict__ ms,
                                                  const float* __restrict__ g,
                                                  const float* __restrict__ b,
                                                  float* __restrict__ y) {
    size_t i4 = (size_t)blockIdx.x * blockDim.x + threadIdx.x;
    int c = (int)((i4 & 63) << 2);
    float4 v = ((const float4*)x)[i4];
    v.x = (v.x - ms[c + 0]) * ms[D + c + 0] * g[c + 0] + b[c + 0];
    v.y = (v.y - ms[c + 1]) * ms[D + c + 1] * g[c + 1] + b[c + 1];
    v.z = (v.z - ms[c + 2]) * ms[D + c + 2] * g[c + 2] + b[c + 2];
    v.w = (v.w - ms[c + 3]) * ms[D + c + 3] * g[c + 3] + b[c + 3];
    if (ADD) {
        float4 o = ((const float4*)y)[i4];
        v.x += o.x; v.y += o.y; v.z += o.z; v.w += o.w;
    }
    ((float4*)y)[i4] = v;
}

// ---------------- flash attention (qkv bf16 in, ao bf16 out; fp32 compute) ----------------
__global__ __launch_bounds__(256) void k_flash(const unsigned short* __restrict__ qkv,
                                               unsigned short* __restrict__ ao) {
    __shared__ float Qs[64][65];
    __shared__ float KPs[64][65];   // K tile, then reused for P tile
    __shared__ float Vs[64][65];
    int bh = blockIdx.x;
    int b = bh >> 2, hh = bh & 3;
    int i0 = blockIdx.y << 6;
    int tid = threadIdx.x;
    int ty = tid >> 4, tx = tid & 15;
    int rr = tid >> 4, c4 = (tid & 15) << 2;
    const size_t base = (size_t)(b * S_PG) * D3 + (size_t)hh * DHD;

#pragma unroll
    for (int p = 0; p < 4; ++p) {
        int r = rr + p * 16;
        ushort4 q = *(const ushort4*)&qkv[base + (size_t)(i0 + r) * D3 + c4];
        Qs[r][c4] = b2f(q.x); Qs[r][c4 + 1] = b2f(q.y); Qs[r][c4 + 2] = b2f(q.z); Qs[r][c4 + 3] = b2f(q.w);
    }

    float m[4] = {-INFINITY, -INFINITY, -INFINITY, -INFINITY};
    float l[4] = {0.f, 0.f, 0.f, 0.f};
    float o[4][4] = {};

    for (int j0 = 0; j0 < S_PG; j0 += 64) {
#pragma unroll
        for (int p = 0; p < 4; ++p) {
            int r = rr + p * 16;
            ushort4 kk = *(const ushort4*)&qkv[base + D + (size_t)(j0 + r) * D3 + c4];
            KPs[r][c4] = b2f(kk.x); KPs[r][c4 + 1] = b2f(kk.y); KPs[r][c4 + 2] = b2f(kk.z); KPs[r][c4 + 3] = b2f(kk.w);
            ushort4 vv = *(const ushort4*)&qkv[base + D2 + (size_t)(j0 + r) * D3 + c4];
            Vs[r][c4] = b2f(vv.x); Vs[r][c4 + 1] = b2f(vv.y); Vs[r][c4 + 2] = b2f(vv.z); Vs[r][c4 + 3] = b2f(vv.w);
        }
        __syncthreads();
        float s[4][4] = {};
        for (int k = 0; k < 64; ++k) {
            float a[4], bb[4];
#pragma unroll
            for (int i = 0; i < 4; ++i) a[i] = Qs[ty * 4 + i][k];
#pragma unroll
            for (int j = 0; j < 4; ++j) bb[j] = KPs[tx * 4 + j][k];
#pragma unroll
            for (int i = 0; i < 4; ++i)
#pragma unroll
                for (int j = 0; j < 4; ++j) s[i][j] = fmaf(a[i], bb[j], s[i][j]);
        }
        float pv[4][4], alpha[4];
#pragma unroll
        for (int i = 0; i < 4; ++i) {
            float pm = -INFINITY;
#pragma unroll
            for (int j = 0; j < 4; ++j) { s[i][j] *= 0.125f; pm = fmaxf(pm, s[i][j]); }
#pragma unroll
            for (int off = 1; off < 16; off <<= 1) pm = fmaxf(pm, __shfl_xor(pm, off));
            float mn = fmaxf(m[i], pm);
            alpha[i] = __expf(m[i] - mn);
            float rs = 0.f;
#pragma unroll
            for (int j = 0; j < 4; ++j) { pv[i][j] = __expf(s[i][j] - mn); rs += pv[i][j]; }
#pragma unroll
            for (int off = 1; off < 16; off <<= 1) rs += __shfl_xor(rs, off);
            l[i] = l[i] * alpha[i] + rs;
            m[i] = mn;
        }
        __syncthreads();
#pragma unroll
        for (int i = 0; i < 4; ++i)
#pragma unroll
            for (int j = 0; j < 4; ++j) KPs[ty * 4 + i][tx * 4 + j] = pv[i][j];
#pragma unroll
        for (int i = 0; i < 4; ++i)
#pragma unroll
            for (int d = 0; d < 4; ++d) o[i][d] *= alpha[i];
        __syncthreads();
        for (int j = 0; j < 64; ++j) {
            float a[4], bb[4];
#pragma unroll
            for (int i = 0; i < 4; ++i) a[i] = KPs[ty * 4 + i][j];
#pragma unroll
            for (int d = 0; d < 4; ++d) bb[d] = Vs[j][tx * 4 + d];
#pragma unroll
            for (int i = 0; i < 4; ++i)
#pragma unroll
                for (int d = 0; d < 4; ++d) o[i][d] = fmaf(a[i], bb[d], o[i][d]);
        }
        __syncthreads();
    }
#pragma unroll
    for (int i = 0; i < 4; ++i) {
        float inv = 1.f / l[i];
        int node = b * S_PG + i0 + ty * 4 + i;
        ushort4 v;
        v.x = (unsigned short)bfr(o[i][0] * inv);
        v.y = (unsigned short)bfr(o[i][1] * inv);
        v.z = (unsigned short)bfr(o[i][2] * inv);
        v.w = (unsigned short)bfr(o[i][3] * inv);
        *(ushort4*)&ao[(size_t)node * D + hh * DHD + tx * 4] = v;
    }
}

// ---------------- mean pool per graph ----------------
__global__ __launch_bounds__(256) void k_pool(const float* __restrict__ h, float* __restrict__ g) {
    int b = blockIdx.x, c = threadIdx.x;
    const float* p = h + (size_t)b * S_PG * D + c;
    float s = 0.f;
    for (int r = 0; r < S_PG; ++r) s += p[(size_t)r * D];
    g[b * D + c] = s * (1.f / (float)S_PG);
}

// ---------------- final head ----------------
__global__ __launch_bounds__(256) void k_final(const float* __restrict__ g,
                                               const float* __restrict__ pw1,
                                               const float* __restrict__ pb1,
                                               const float* __restrict__ pw2,
                                               const float* __restrict__ pb2,
                                               float* __restrict__ out) {
    __shared__ float gs[D];
    __shared__ float ts[D];
    __shared__ float red[4];
    int b = blockIdx.x, tid = threadIdx.x;
    gs[tid] = g[b * D + tid];
    __syncthreads();
    float acc = pb1[tid];
    for (int d = 0; d < D; ++d) acc = fmaf(gs[d], pw1[d * D + tid], acc);
    ts[tid] = fmaxf(acc, 0.f);
    __syncthreads();
    float z[3];
#pragma unroll
    for (int rep = 0; rep < 3; ++rep) {
        int j = tid + rep * 256;
        float a = pb2[j];
        for (int d = 0; d < D; ++d) a = fmaf(ts[d], pw2[(size_t)d * OUTD + j], a);
        z[rep] = a;
    }
    float ss = z[0] * z[0] + z[1] * z[1] + z[2] * z[2];
#pragma unroll
    for (int o = 32; o >= 1; o >>= 1) ss += __shfl_xor(ss, o);
    if ((tid & 63) == 0) red[tid >> 6] = ss;
    __syncthreads();
    float rn = rsqrtf(red[0] + red[1] + red[2] + red[3]);
#pragma unroll
    for (int rep = 0; rep < 3; ++rep) out[b * OUTD + tid + rep * 256] = z[rep] * rn;
}

extern "C" void kernel_launch(void* const* d_in, const int* in_sizes, int n_in,
                              void* d_out, int out_size, void* d_ws, size_t ws_size,
                              hipStream_t stream) {
    const int* x        = (const int*)d_in[0];
    const int* ea       = (const int*)d_in[1];
    const int* eidx     = (const int*)d_in[2];
    const float* atom_tab = (const float*)d_in[4];
    const float* bond_tab = (const float*)d_in[5];
    const float* elin_w = (const float*)d_in[6];
    const float* elin_b = (const float*)d_in[7];
    const float* eps    = (const float*)d_in[8];
    const float* gw1    = (const float*)d_in[9];
    const float* gb1    = (const float*)d_in[10];
    const float* gw2    = (const float*)d_in[11];
    const float* gb2    = (const float*)d_in[12];
    const float* aw_in  = (const float*)d_in[13];
    const float* ab_in  = (const float*)d_in[14];
    const float* aw_out = (const float*)d_in[15];
    const float* ab_out = (const float*)d_in[16];
    const float* n1g    = (const float*)d_in[17];
    const float* n1b    = (const float*)d_in[18];
    const float* n2g    = (const float*)d_in[19];
    const float* n2b    = (const float*)d_in[20];
    const float* n3g    = (const float*)d_in[21];
    const float* n3b    = (const float*)d_in[22];
    const float* mw1    = (const float*)d_in[23];
    const float* mb1    = (const float*)d_in[24];
    const float* mw2    = (const float*)d_in[25];
    const float* mb2    = (const float*)d_in[26];
    const float* pw1    = (const float*)d_in[27];
    const float* pb1    = (const float*)d_in[28];
    const float* pw2    = (const float*)d_in[29];
    const float* pb2    = (const float*)d_in[30];

    // ---- workspace layout (~91 MiB) ----
    char* ws = (char*)d_ws;
    size_t off = 0;
    auto alloc = [&](size_t bytes) {
        void* p = ws + off;
        off += (bytes + 255) & ~(size_t)255;
        return p;
    };
    float*  h    = (float*)alloc((size_t)N_NODES * D * 4);          // 16 MiB layer state
    float*  bufB = (float*)alloc((size_t)N_NODES * D * 4);          // 16 MiB hc accumulator
    char*   U    = (char*)alloc((size_t)N_NODES * D3 * 2);          // 24 MiB: tmp f32 [N,256] / qkv bf16 [N,768]
    unsigned short* bfA = (unsigned short*)alloc((size_t)N_NODES * D3 * 2); // 24 MiB: agg/ao @0, hid @ N*D
    unsigned short* WT  = (unsigned short*)alloc((size_t)NL * WT_PER_LAYER * 2); // 6.3 MiB
    float*  bw   = (float*)alloc((size_t)NL * 66 * D * 4);
    float*  ct   = (float*)alloc((size_t)NL * NCOMBO * D * 4);
    int*    deg  = (int*)alloc((size_t)N_NODES * 4);
    int*    row_ptr = (int*)alloc((size_t)(N_NODES + 1) * 4);
    int*    cursor  = (int*)alloc((size_t)N_NODES * 4);
    int2*   sorted  = (int2*)alloc((size_t)NE * 8);
    float*  part = (float*)alloc((size_t)128 * 2 * D * 4);
    float*  ms   = (float*)alloc((size_t)2 * D * 4);
    float*  g    = (float*)alloc((size_t)NB * D * 4);
    (void)ws_size; (void)in_sizes; (void)n_in; (void)out_size;

    float* tmp = (float*)U;                       // [N,256] f32 (pre-BN)
    unsigned short* qkv = (unsigned short*)U;     // [N,768] bf16
    unsigned short* aggb = bfA;                   // [N,256] bf16
    unsigned short* hid  = bfA + (size_t)N_NODES * D;  // [N,512] bf16
    unsigned short* ao   = bfA;                   // [N,256] bf16 (reuse)

    const int* srcp = eidx;
    const int* dstp = eidx + NE;
    const int EW = N_NODES * D / 1024;

    // one-time per launch
    k_zero16k<<<N_NODES / 256, 256, 0, stream>>>(deg);
    k_hist<<<NE / 256, 256, 0, stream>>>(dstp, deg);
    k_scan<<<1, 256, 0, stream>>>(deg, row_ptr, cursor);
    k_scatter<<<NE / 256, 256, 0, stream>>>(srcp, dstp, ea, cursor, sorted);
    k_atom_enc<<<N_NODES / 4, 256, 0, stream>>>(x, atom_tab, h);
    k_bondw<<<NL * 66, 256, 0, stream>>>(bond_tab, elin_w, bw);
    k_combo<<<NL * NCOMBO, 256, 0, stream>>>(bw, elin_b, ct);
    k_wcvt<<<NL * 768, 256, 0, stream>>>(gw1, gw2, aw_in, aw_out, mw1, mw2, WT);

    for (int l = 0; l < NL; ++l) {
        const unsigned short* WTl = WT + (size_t)l * WT_PER_LAYER;
        // --- GINE local branch ---
        k_gine_agg<<<N_NODES / 4, 256, 0, stream>>>(h, ct + (size_t)l * NCOMBO * D, eps, l,
                                                    row_ptr, sorted, aggb);
        k_mm<1, 1, 0, 1><<<dim3(D2 / 128, N_NODES / 128), 256, 0, stream>>>(
            aggb, WTl + 0, gb1 + (size_t)l * D2, nullptr, hid, N_NODES, D2, D);
        k_mm<1, 0, 1, 0><<<dim3(D / 128, N_NODES / 128), 256, 0, stream>>>(
            hid, WTl + 131072, gb2 + (size_t)l * D, h, tmp, N_NODES, D, D2);
        k_bn_stat1<<<128, 256, 0, stream>>>(tmp, part);
        k_bn_stat2<<<1, 256, 0, stream>>>(part, ms);
        k_bn_apply<0><<<EW, 256, 0, stream>>>(tmp, ms, n1g + l * D, n1b + l * D, bufB);
        // --- global attention ---
        k_mm<0, 0, 0, 1><<<dim3(D3 / 128, N_NODES / 128), 256, 0, stream>>>(
            h, WTl + 262144, ab_in + (size_t)l * D3, nullptr, qkv, N_NODES, D3, D);
        k_flash<<<dim3(NB * NH, S_PG / 64), 256, 0, stream>>>(qkv, ao);
        k_mm<1, 0, 1, 0><<<dim3(D / 128, N_NODES / 128), 256, 0, stream>>>(
            ao, WTl + 458752, ab_out + (size_t)l * D, h, tmp, N_NODES, D, D);
        k_bn_stat1<<<128, 256, 0, stream>>>(tmp, part);
        k_bn_stat2<<<1, 256, 0, stream>>>(part, ms);
        k_bn_apply<1><<<EW, 256, 0, stream>>>(tmp, ms, n2g + l * D, n2b + l * D, bufB);
        // --- combine + MLP ---
        k_mm<0, 1, 0, 1><<<dim3(D2 / 128, N_NODES / 128), 256, 0, stream>>>(
            bufB, WTl + 524288, mb1 + (size_t)l * D2, nullptr, hid, N_NODES, D2, D);
        k_mm<1, 0, 1, 0><<<dim3(D / 128, N_NODES / 128), 256, 0, stream>>>(
            hid, WTl + 655360, mb2 + (size_t)l * D, bufB, tmp, N_NODES, D, D2);
        k_bn_stat1<<<128, 256, 0, stream>>>(tmp, part);
        k_bn_stat2<<<1, 256, 0, stream>>>(part, ms);
        k_bn_apply<0><<<EW, 256, 0, stream>>>(tmp, ms, n3g + l * D, n3b + l * D, h);
    }
    k_pool<<<NB, 256, 0, stream>>>(h, g);
    k_final<<<NB, 256, 0, stream>>>(g, pw1, pb1, pw2, pb2, (float*)d_out);
}

// Round 5
// 1155.523 us; speedup vs baseline: 5.3653x; 1.5189x over previous
//
#include <hip/hip_runtime.h>
#include <hip/hip_bf16.h>
#include <math.h>

#define N_NODES 16384
#define NB      32
#define S_PG    512
#define NE      262144
#define EPG     8192
#define D       256
#define D2      512
#define D3      768
#define NL      4
#define NH      4
#define DHD     64
#define OUTD    768
#define NCOMBO  264
#define WT_PER_LAYER 786432

typedef short s8v __attribute__((ext_vector_type(8)));
typedef float f4v __attribute__((ext_vector_type(4)));

__device__ __forceinline__ unsigned bfr(float f) {   // fp32 -> bf16 bits, RNE
    unsigned u = __float_as_uint(f);
    return (u + 0x7fffu + ((u >> 16) & 1u)) >> 16;
}
__device__ __forceinline__ float b2f(unsigned short u) {
    return __uint_as_float(((unsigned)u) << 16);
}

// ---------------- Atom encoder ----------------
__global__ __launch_bounds__(256) void k_atom_enc(const int* __restrict__ x,
                                                  const float* __restrict__ tab,
                                                  float* __restrict__ h) {
    int node = blockIdx.x * 4 + (threadIdx.x >> 6);
    int lane = threadIdx.x & 63;
    int dd = lane << 2;
    float4 acc = {0.f, 0.f, 0.f, 0.f};
#pragma unroll
    for (int f = 0; f < 9; ++f) {
        int v = x[node * 9 + f];
        const float4 t = *(const float4*)&tab[((size_t)(f * 119 + v)) * D + dd];
        acc.x += t.x; acc.y += t.y; acc.z += t.z; acc.w += t.w;
    }
    *(float4*)&h[(size_t)node * D + dd] = acc;
}

// ---------------- bw[l,fv,:] = bond_tab[fv,:] @ elin_w[l] ----------------
__global__ __launch_bounds__(256) void k_bondw(const float* __restrict__ bond_tab,
                                               const float* __restrict__ elin_w,
                                               float* __restrict__ bw) {
    int blk = blockIdx.x;         // L*66
    int l = blk / 66, fv = blk % 66;
    int dout = threadIdx.x;
    const float* tabrow = bond_tab + (size_t)fv * D;
    const float* w = elin_w + (size_t)l * D * D;
    float acc = 0.f;
    for (int d = 0; d < D; ++d) acc = fmaf(tabrow[d], w[d * D + dout], acc);
    bw[((size_t)l * 66 + fv) * D + dout] = acc;
}

// ---------------- combo table: ct[l,cid,:] = bw0[a0]+bw1[a1]+bw2[a2]+elin_b[l] ----------------
__global__ __launch_bounds__(256) void k_combo(const float* __restrict__ bw,
                                               const float* __restrict__ elin_b,
                                               float* __restrict__ ct) {
    int b = blockIdx.x;           // NL*264
    int l = b / NCOMBO, cid = b % NCOMBO;
    int a0 = cid / 12, a1 = (cid % 12) / 2, a2 = cid & 1;
    int d = threadIdx.x;
    const float* bwl = bw + (size_t)l * 66 * D;
    ct[((size_t)l * NCOMBO + cid) * D + d] =
        bwl[(size_t)a0 * D + d] + bwl[(size_t)(22 + a1) * D + d] +
        bwl[(size_t)(44 + a2) * D + d] + elin_b[(size_t)l * D + d];
}

// ---------------- CSR build ----------------
__global__ __launch_bounds__(256) void k_zero16k(int* __restrict__ p) {
    p[blockIdx.x * 256 + threadIdx.x] = 0;
}
__global__ __launch_bounds__(256) void k_hist(const int* __restrict__ dst, int* __restrict__ deg) {
    int e = blockIdx.x * 256 + threadIdx.x;
    atomicAdd(&deg[dst[e]], 1);
}
__global__ __launch_bounds__(256) void k_scan(const int* __restrict__ deg,
                                              int* __restrict__ row_ptr,
                                              int* __restrict__ cursor) {
    __shared__ int partial[256];
    int t = threadIdx.x;
    int base = t * 64;
    int s = 0;
    for (int i = 0; i < 64; ++i) s += deg[base + i];
    partial[t] = s;
    __syncthreads();
    for (int dstp = 1; dstp < 256; dstp <<= 1) {
        int v = (t >= dstp) ? partial[t - dstp] : 0;
        __syncthreads();
        partial[t] += v;
        __syncthreads();
    }
    int run = partial[t] - s;   // exclusive start of this chunk
    for (int i = 0; i < 64; ++i) {
        int dcur = deg[base + i];
        row_ptr[base + i] = run;
        cursor[base + i] = run;
        run += dcur;
    }
    if (t == 255) row_ptr[N_NODES] = run;
}
__global__ __launch_bounds__(256) void k_scatter(const int* __restrict__ src,
                                                 const int* __restrict__ dst,
                                                 const int* __restrict__ ea,
                                                 int* __restrict__ cursor,
                                                 int2* __restrict__ sorted) {
    int e = blockIdx.x * 256 + threadIdx.x;
    int d = dst[e];
    int pos = atomicAdd(&cursor[d], 1);
    int cid = ea[e * 3] * 12 + ea[e * 3 + 1] * 2 + ea[e * 3 + 2];
    sorted[pos] = make_int2(src[e], cid);
}

// ---------------- GINE aggregation (gather, no atomics): one wave per node ----------------
__global__ __launch_bounds__(256) void k_gine_agg(const float* __restrict__ h,
                                                  const float* __restrict__ ct,   // this layer's 264x256
                                                  const float* __restrict__ eps, int l,
                                                  const int* __restrict__ row_ptr,
                                                  const int2* __restrict__ sorted,
                                                  unsigned short* __restrict__ aggb) {
    int w = threadIdx.x >> 6;
    int lane = threadIdx.x & 63;
    int n = blockIdx.x * 4 + w;
    int dd = lane << 2;
    int beg = row_ptr[n], end = row_ptr[n + 1];
    float4 acc = {0.f, 0.f, 0.f, 0.f};
    for (int i = beg; i < end; ++i) {
        int2 e = sorted[i];
        float4 hv = *(const float4*)&h[(size_t)e.x * D + dd];
        float4 cv = *(const float4*)&ct[(size_t)e.y * D + dd];
        acc.x += fmaxf(hv.x + cv.x, 0.f);
        acc.y += fmaxf(hv.y + cv.y, 0.f);
        acc.z += fmaxf(hv.z + cv.z, 0.f);
        acc.w += fmaxf(hv.w + cv.w, 0.f);
    }
    float s1p = 1.f + eps[l];
    float4 hn = *(const float4*)&h[(size_t)n * D + dd];
    ushort4 o;
    o.x = (unsigned short)bfr(s1p * hn.x + acc.x);
    o.y = (unsigned short)bfr(s1p * hn.y + acc.y);
    o.z = (unsigned short)bfr(s1p * hn.z + acc.z);
    o.w = (unsigned short)bfr(s1p * hn.w + acc.w);
    *(ushort4*)&aggb[(size_t)n * D + dd] = o;
}

// ---------------- weight transpose+convert: W[K][N] f32 -> WT[N][K] bf16 ----------------
__global__ __launch_bounds__(256) void k_wcvt(const float* __restrict__ gw1, const float* __restrict__ gw2,
                                              const float* __restrict__ aw_in, const float* __restrict__ aw_out,
                                              const float* __restrict__ mw1, const float* __restrict__ mw2,
                                              unsigned short* __restrict__ WT) {
    const int KS[6]   = {256, 512, 256, 256, 256, 512};
    const int NS[6]   = {512, 256, 768, 256, 512, 256};
    const int TOFF[7] = {0, 128, 256, 448, 512, 640, 768};
    const int DOFF[6] = {0, 131072, 262144, 458752, 524288, 655360};
    int b = blockIdx.x;
    int l = b / 768, wb = b % 768;
    int widx = 0;
    while (wb >= TOFF[widx + 1]) ++widx;
    int t = wb - TOFF[widx];
    int K = KS[widx], N = NS[widx];
    int nn = N / 32;
    int kt = t / nn, nt = t % nn;
    const float* srcs[6] = {gw1, gw2, aw_in, aw_out, mw1, mw2};
    const float* W = srcs[widx] + (size_t)l * K * N;
    unsigned short* WTp = WT + (size_t)l * WT_PER_LAYER + DOFF[widx];
    __shared__ float tile[32][33];
    int tid = threadIdx.x;
    int r = tid >> 3, c4 = (tid & 7) << 2;
    float4 v = *(const float4*)&W[(size_t)(kt * 32 + r) * N + nt * 32 + c4];
    tile[r][c4] = v.x; tile[r][c4 + 1] = v.y; tile[r][c4 + 2] = v.z; tile[r][c4 + 3] = v.w;
    __syncthreads();
    int nr = tid >> 3, kc = (tid & 7) << 2;
    ushort4 o;
    o.x = (unsigned short)bfr(tile[kc + 0][nr]);
    o.y = (unsigned short)bfr(tile[kc + 1][nr]);
    o.z = (unsigned short)bfr(tile[kc + 2][nr]);
    o.w = (unsigned short)bfr(tile[kc + 3][nr]);
    *(ushort4*)&WTp[(size_t)(nt * 32 + nr) * K + kt * 32 + kc] = o;
}

// ---------------- bf16 MFMA GEMM: C = op(A @ B + bias [+ res]) ----------------
template<int ABF, int RELU, int RES, int OBF>
__global__ __launch_bounds__(256) void k_mm(const void* __restrict__ Ap,
                                            const unsigned short* __restrict__ BT,
                                            const float* __restrict__ bias,
                                            const float* __restrict__ res,
                                            void* __restrict__ Cp,
                                            int M, int N, int K) {
    __shared__ unsigned short As[128][40];
    __shared__ unsigned short Bs[128][40];
    const int tid = threadIdx.x;
    const int row0 = blockIdx.y * 128, col0 = blockIdx.x * 128;
    const int l = tid & 63;
    const int w = tid >> 6;
    const int wm = w >> 1, wn = w & 1;
    const int srow = tid >> 1;            // 0..127 staging row (A) / col (B)
    const int skq = (tid & 1) * 16;       // staging k offset
    const int lr = l & 15, lq = l >> 4;
    const int koff = lq * 8;
    f4v acc[4][4] = {};

    for (int k0 = 0; k0 < K; k0 += 32) {
        if (ABF) {
            const unsigned short* Ab = (const unsigned short*)Ap;
            const unsigned short* ar = &Ab[(size_t)(row0 + srow) * K + k0 + skq];
            uint4 u0 = *(const uint4*)&ar[0];
            uint4 u1 = *(const uint4*)&ar[8];
            *(uint4*)&As[srow][skq] = u0;
            *(uint4*)&As[srow][skq + 8] = u1;
        } else {
            const float* Af = (const float*)Ap;
            const float* ar = &Af[(size_t)(row0 + srow) * K + k0 + skq];
            float4 f0 = *(const float4*)&ar[0];
            float4 f1 = *(const float4*)&ar[4];
            float4 f2 = *(const float4*)&ar[8];
            float4 f3 = *(const float4*)&ar[12];
            uint4 u0, u1;
            u0.x = bfr(f0.x) | (bfr(f0.y) << 16); u0.y = bfr(f0.z) | (bfr(f0.w) << 16);
            u0.z = bfr(f1.x) | (bfr(f1.y) << 16); u0.w = bfr(f1.z) | (bfr(f1.w) << 16);
            u1.x = bfr(f2.x) | (bfr(f2.y) << 16); u1.y = bfr(f2.z) | (bfr(f2.w) << 16);
            u1.z = bfr(f3.x) | (bfr(f3.y) << 16); u1.w = bfr(f3.z) | (bfr(f3.w) << 16);
            *(uint4*)&As[srow][skq] = u0;
            *(uint4*)&As[srow][skq + 8] = u1;
        }
        {
            const unsigned short* br = &BT[(size_t)(col0 + srow) * K + k0 + skq];
            uint4 u0 = *(const uint4*)&br[0];
            uint4 u1 = *(const uint4*)&br[8];
            *(uint4*)&Bs[srow][skq] = u0;
            *(uint4*)&Bs[srow][skq + 8] = u1;
        }
        __syncthreads();
        s8v af[4], bf[4];
#pragma unroll
        for (int m = 0; m < 4; ++m) af[m] = *(const s8v*)&As[wm * 64 + m * 16 + lr][koff];
#pragma unroll
        for (int n = 0; n < 4; ++n) bf[n] = *(const s8v*)&Bs[wn * 64 + n * 16 + lr][koff];
#pragma unroll
        for (int m = 0; m < 4; ++m)
#pragma unroll
            for (int n = 0; n < 4; ++n)
                acc[m][n] = __builtin_amdgcn_mfma_f32_16x16x32_bf16(af[m], bf[n], acc[m][n], 0, 0, 0);
        __syncthreads();
    }
#pragma unroll
    for (int n = 0; n < 4; ++n) {
        int c = col0 + wn * 64 + n * 16 + lr;
        float bv = bias[c];
#pragma unroll
        for (int m = 0; m < 4; ++m) {
#pragma unroll
            for (int j = 0; j < 4; ++j) {
                int r = row0 + wm * 64 + m * 16 + lq * 4 + j;
                float v = acc[m][n][j] + bv;
                if (RES) v += res[(size_t)r * N + c];
                if (RELU) v = fmaxf(v, 0.f);
                if (OBF) ((unsigned short*)Cp)[(size_t)r * N + c] = (unsigned short)bfr(v);
                else ((float*)Cp)[(size_t)r * N + c] = v;
            }
        }
    }
}

// ---------------- BatchNorm: two-stage stats + apply ----------------
__global__ __launch_bounds__(256) void k_bn_stat1(const float* __restrict__ x,
                                                  float* __restrict__ part) {
    int c = threadIdx.x;
    int blk = blockIdx.x;                    // 128 blocks x 128 rows
    const float* p = x + (size_t)blk * 128 * D + c;
    float s = 0.f, s2 = 0.f;
    for (int r = 0; r < 128; ++r) { float v = p[(size_t)r * D]; s += v; s2 += v * v; }
    part[blk * 2 * D + c] = s;
    part[blk * 2 * D + D + c] = s2;
}

__global__ __launch_bounds__(256) void k_bn_stat2(const float* __restrict__ part,
                                                  float* __restrict__ ms) {
    int c = threadIdx.x;
    float s = 0.f, s2 = 0.f;
    for (int p = 0; p < 128; ++p) { s += part[p * 2 * D + c]; s2 += part[p * 2 * D + D + c]; }
    float mean = s / (float)N_NODES;
    float var = s2 / (float)N_NODES - mean * mean;
    ms[c] = mean;
    ms[D + c] = rsqrtf(var + 1e-5f);
}

template<int ADD>
__global__ __launch_bounds__(256) void k_bn_apply(const float* __restrict__ x,
                                                  const float* __restrict__ ms,
                                                  const float* __restrict__ g,
                                                  const float* __restrict__ b,
                                                  float* __restrict__ y) {
    size_t i4 = (size_t)blockIdx.x * blockDim.x + threadIdx.x;
    int c = (int)((i4 & 63) << 2);
    float4 v = ((const float4*)x)[i4];
    v.x = (v.x - ms[c + 0]) * ms[D + c + 0] * g[c + 0] + b[c + 0];
    v.y = (v.y - ms[c + 1]) * ms[D + c + 1] * g[c + 1] + b[c + 1];
    v.z = (v.z - ms[c + 2]) * ms[D + c + 2] * g[c + 2] + b[c + 2];
    v.w = (v.w - ms[c + 3]) * ms[D + c + 3] * g[c + 3] + b[c + 3];
    if (ADD) {
        float4 o = ((const float4*)y)[i4];
        v.x += o.x; v.y += o.y; v.z += o.z; v.w += o.w;
    }
    ((float4*)y)[i4] = v;
}

// ---------------- MFMA flash attention ----------------
// block = (bh, i0): 64 q rows, 4 waves x 16 q rows. kv tiles of 64, online softmax.
// qkv bf16 [N, 768] (q|k|v per head slice of 64), ao bf16 [N, 256].
__global__ __launch_bounds__(256) void k_flash_mfma(const unsigned short* __restrict__ qkv,
                                                    unsigned short* __restrict__ ao) {
    __shared__ unsigned short Ks[64][72];          // K tile  [kv][d], pad 72
    __shared__ unsigned short VT[64][66];          // V^T tile [d][kv], pad 66
    __shared__ unsigned short Ps[4][16][72];       // per-wave P tile [q][kv], pad 72
    const int bh = blockIdx.x;                     // 0..127
    const int b = bh >> 2, hh = bh & 3;
    const int i0 = blockIdx.y << 6;
    const int tid = threadIdx.x;
    const int w = tid >> 6, l = tid & 63;
    const int lr = l & 15, lq = l >> 4;
    const int hd = hh * DHD;
    const size_t rowbase = (size_t)(b * S_PG) * D3;

    // Q A-fragments for this wave's 16 q rows: lane holds Q[row=lr][k=lq*8..+8] per 32-k step
    s8v aq[2];
    {
        const unsigned short* qrow = &qkv[rowbase + (size_t)(i0 + w * 16 + lr) * D3 + hd + lq * 8];
        aq[0] = *(const s8v*)&qrow[0];
        aq[1] = *(const s8v*)&qrow[32];
    }

    float mrow[4] = {-INFINITY, -INFINITY, -INFINITY, -INFINITY};
    float lrow[4] = {0.f, 0.f, 0.f, 0.f};
    f4v oacc[4] = {};

    const int skv = tid >> 2;                      // staging kv row 0..63
    const int sd0 = (tid & 3) << 4;                // staging d segment 0,16,32,48

    for (int j0 = 0; j0 < S_PG; j0 += 64) {
        __syncthreads();                            // prior tile reads complete
        // stage K [kv][d] and V^T [d][kv]
        {
            const unsigned short* kr = &qkv[rowbase + (size_t)(j0 + skv) * D3 + D + hd + sd0];
            *(uint4*)&Ks[skv][sd0]     = *(const uint4*)&kr[0];
            *(uint4*)&Ks[skv][sd0 + 8] = *(const uint4*)&kr[8];
            const unsigned short* vr = &qkv[rowbase + (size_t)(j0 + skv) * D3 + D2 + hd + sd0];
            unsigned short vv[16];
            *(uint4*)&vv[0] = *(const uint4*)&vr[0];
            *(uint4*)&vv[8] = *(const uint4*)&vr[8];
#pragma unroll
            for (int i = 0; i < 16; ++i) VT[sd0 + i][skv] = vv[i];
        }
        __syncthreads();
        // scores: S[q=lq*4+j][kv=nt*16+lr]
        f4v sc[4] = {};
#pragma unroll
        for (int nt = 0; nt < 4; ++nt) {
            s8v bk0 = *(const s8v*)&Ks[nt * 16 + lr][lq * 8];
            s8v bk1 = *(const s8v*)&Ks[nt * 16 + lr][32 + lq * 8];
            sc[nt] = __builtin_amdgcn_mfma_f32_16x16x32_bf16(aq[0], bk0, sc[nt], 0, 0, 0);
            sc[nt] = __builtin_amdgcn_mfma_f32_16x16x32_bf16(aq[1], bk1, sc[nt], 0, 0, 0);
        }
        // online softmax per q-row j (row-reduce over nt regs + 16-lane lr group)
        float ps[4][4], alpha[4];
#pragma unroll
        for (int j = 0; j < 4; ++j) {
#pragma unroll
            for (int nt = 0; nt < 4; ++nt) ps[nt][j] = sc[nt][j] * 0.125f;
            float pm = fmaxf(fmaxf(ps[0][j], ps[1][j]), fmaxf(ps[2][j], ps[3][j]));
#pragma unroll
            for (int off = 1; off < 16; off <<= 1) pm = fmaxf(pm, __shfl_xor(pm, off));
            float mn = fmaxf(mrow[j], pm);
            alpha[j] = __expf(mrow[j] - mn);
            float rs = 0.f;
#pragma unroll
            for (int nt = 0; nt < 4; ++nt) { ps[nt][j] = __expf(ps[nt][j] - mn); rs += ps[nt][j]; }
#pragma unroll
            for (int off = 1; off < 16; off <<= 1) rs += __shfl_xor(rs, off);
            lrow[j] = lrow[j] * alpha[j] + rs;
            mrow[j] = mn;
        }
        // P -> LDS (C-layout write), rescale O
#pragma unroll
        for (int nt = 0; nt < 4; ++nt)
#pragma unroll
            for (int j = 0; j < 4; ++j)
                Ps[w][lq * 4 + j][nt * 16 + lr] = (unsigned short)bfr(ps[nt][j]);
#pragma unroll
        for (int ntd = 0; ntd < 4; ++ntd)
#pragma unroll
            for (int j = 0; j < 4; ++j) oacc[ntd][j] *= alpha[j];
        // PV: A=P [q][kv], B=V^T [d][kv]
        s8v pa0 = *(const s8v*)&Ps[w][lr][lq * 8];
        s8v pa1 = *(const s8v*)&Ps[w][lr][32 + lq * 8];
#pragma unroll
        for (int ntd = 0; ntd < 4; ++ntd) {
            s8v bv0 = *(const s8v*)&VT[ntd * 16 + lr][lq * 8];
            s8v bv1 = *(const s8v*)&VT[ntd * 16 + lr][32 + lq * 8];
            oacc[ntd] = __builtin_amdgcn_mfma_f32_16x16x32_bf16(pa0, bv0, oacc[ntd], 0, 0, 0);
            oacc[ntd] = __builtin_amdgcn_mfma_f32_16x16x32_bf16(pa1, bv1, oacc[ntd], 0, 0, 0);
        }
    }
    // epilogue: O /= l, write ao
#pragma unroll
    for (int j = 0; j < 4; ++j) {
        float inv = 1.f / lrow[j];
        int node = b * S_PG + i0 + w * 16 + lq * 4 + j;
#pragma unroll
        for (int ntd = 0; ntd < 4; ++ntd)
            ao[(size_t)node * D + hd + ntd * 16 + lr] = (unsigned short)bfr(oacc[ntd][j] * inv);
    }
}

// ---------------- mean pool per graph ----------------
__global__ __launch_bounds__(256) void k_pool(const float* __restrict__ h, float* __restrict__ g) {
    int b = blockIdx.x, c = threadIdx.x;
    const float* p = h + (size_t)b * S_PG * D + c;
    float s = 0.f;
    for (int r = 0; r < S_PG; ++r) s += p[(size_t)r * D];
    g[b * D + c] = s * (1.f / (float)S_PG);
}

// ---------------- final head ----------------
__global__ __launch_bounds__(256) void k_final(const float* __restrict__ g,
                                               const float* __restrict__ pw1,
                                               const float* __restrict__ pb1,
                                               const float* __restrict__ pw2,
                                               const float* __restrict__ pb2,
                                               float* __restrict__ out) {
    __shared__ float gs[D];
    __shared__ float ts[D];
    __shared__ float red[4];
    int b = blockIdx.x, tid = threadIdx.x;
    gs[tid] = g[b * D + tid];
    __syncthreads();
    float acc = pb1[tid];
    for (int d = 0; d < D; ++d) acc = fmaf(gs[d], pw1[d * D + tid], acc);
    ts[tid] = fmaxf(acc, 0.f);
    __syncthreads();
    float z[3];
#pragma unroll
    for (int rep = 0; rep < 3; ++rep) {
        int j = tid + rep * 256;
        float a = pb2[j];
        for (int d = 0; d < D; ++d) a = fmaf(ts[d], pw2[(size_t)d * OUTD + j], a);
        z[rep] = a;
    }
    float ss = z[0] * z[0] + z[1] * z[1] + z[2] * z[2];
#pragma unroll
    for (int o = 32; o >= 1; o >>= 1) ss += __shfl_xor(ss, o);
    if ((tid & 63) == 0) red[tid >> 6] = ss;
    __syncthreads();
    float rn = rsqrtf(red[0] + red[1] + red[2] + red[3]);
#pragma unroll
    for (int rep = 0; rep < 3; ++rep) out[b * OUTD + tid + rep * 256] = z[rep] * rn;
}

extern "C" void kernel_launch(void* const* d_in, const int* in_sizes, int n_in,
                              void* d_out, int out_size, void* d_ws, size_t ws_size,
                              hipStream_t stream) {
    const int* x        = (const int*)d_in[0];
    const int* ea       = (const int*)d_in[1];
    const int* eidx     = (const int*)d_in[2];
    const float* atom_tab = (const float*)d_in[4];
    const float* bond_tab = (const float*)d_in[5];
    const float* elin_w = (const float*)d_in[6];
    const float* elin_b = (const float*)d_in[7];
    const float* eps    = (const float*)d_in[8];
    const float* gw1    = (const float*)d_in[9];
    const float* gb1    = (const float*)d_in[10];
    const float* gw2    = (const float*)d_in[11];
    const float* gb2    = (const float*)d_in[12];
    const float* aw_in  = (const float*)d_in[13];
    const float* ab_in  = (const float*)d_in[14];
    const float* aw_out = (const float*)d_in[15];
    const float* ab_out = (const float*)d_in[16];
    const float* n1g    = (const float*)d_in[17];
    const float* n1b    = (const float*)d_in[18];
    const float* n2g    = (const float*)d_in[19];
    const float* n2b    = (const float*)d_in[20];
    const float* n3g    = (const float*)d_in[21];
    const float* n3b    = (const float*)d_in[22];
    const float* mw1    = (const float*)d_in[23];
    const float* mb1    = (const float*)d_in[24];
    const float* mw2    = (const float*)d_in[25];
    const float* mb2    = (const float*)d_in[26];
    const float* pw1    = (const float*)d_in[27];
    const float* pb1    = (const float*)d_in[28];
    const float* pw2    = (const float*)d_in[29];
    const float* pb2    = (const float*)d_in[30];

    // ---- workspace layout (~91 MiB) ----
    char* ws = (char*)d_ws;
    size_t off = 0;
    auto alloc = [&](size_t bytes) {
        void* p = ws + off;
        off += (bytes + 255) & ~(size_t)255;
        return p;
    };
    float*  h    = (float*)alloc((size_t)N_NODES * D * 4);          // 16 MiB layer state
    float*  bufB = (float*)alloc((size_t)N_NODES * D * 4);          // 16 MiB hc accumulator
    char*   U    = (char*)alloc((size_t)N_NODES * D3 * 2);          // 24 MiB: tmp f32 [N,256] / qkv bf16 [N,768]
    unsigned short* bfA = (unsigned short*)alloc((size_t)N_NODES * D3 * 2); // 24 MiB: agg/ao @0, hid @ N*D
    unsigned short* WT  = (unsigned short*)alloc((size_t)NL * WT_PER_LAYER * 2); // 6.3 MiB
    float*  bw   = (float*)alloc((size_t)NL * 66 * D * 4);
    float*  ct   = (float*)alloc((size_t)NL * NCOMBO * D * 4);
    int*    deg  = (int*)alloc((size_t)N_NODES * 4);
    int*    row_ptr = (int*)alloc((size_t)(N_NODES + 1) * 4);
    int*    cursor  = (int*)alloc((size_t)N_NODES * 4);
    int2*   sorted  = (int2*)alloc((size_t)NE * 8);
    float*  part = (float*)alloc((size_t)128 * 2 * D * 4);
    float*  ms   = (float*)alloc((size_t)2 * D * 4);
    float*  g    = (float*)alloc((size_t)NB * D * 4);
    (void)ws_size; (void)in_sizes; (void)n_in; (void)out_size;

    float* tmp = (float*)U;                       // [N,256] f32 (pre-BN)
    unsigned short* qkv = (unsigned short*)U;     // [N,768] bf16
    unsigned short* aggb = bfA;                   // [N,256] bf16
    unsigned short* hid  = bfA + (size_t)N_NODES * D;  // [N,512] bf16
    unsigned short* ao   = bfA;                   // [N,256] bf16 (reuse)

    const int* srcp = eidx;
    const int* dstp = eidx + NE;
    const int EW = N_NODES * D / 1024;

    // one-time per launch
    k_zero16k<<<N_NODES / 256, 256, 0, stream>>>(deg);
    k_hist<<<NE / 256, 256, 0, stream>>>(dstp, deg);
    k_scan<<<1, 256, 0, stream>>>(deg, row_ptr, cursor);
    k_scatter<<<NE / 256, 256, 0, stream>>>(srcp, dstp, ea, cursor, sorted);
    k_atom_enc<<<N_NODES / 4, 256, 0, stream>>>(x, atom_tab, h);
    k_bondw<<<NL * 66, 256, 0, stream>>>(bond_tab, elin_w, bw);
    k_combo<<<NL * NCOMBO, 256, 0, stream>>>(bw, elin_b, ct);
    k_wcvt<<<NL * 768, 256, 0, stream>>>(gw1, gw2, aw_in, aw_out, mw1, mw2, WT);

    for (int l = 0; l < NL; ++l) {
        const unsigned short* WTl = WT + (size_t)l * WT_PER_LAYER;
        // --- GINE local branch ---
        k_gine_agg<<<N_NODES / 4, 256, 0, stream>>>(h, ct + (size_t)l * NCOMBO * D, eps, l,
                                                    row_ptr, sorted, aggb);
        k_mm<1, 1, 0, 1><<<dim3(D2 / 128, N_NODES / 128), 256, 0, stream>>>(
            aggb, WTl + 0, gb1 + (size_t)l * D2, nullptr, hid, N_NODES, D2, D);
        k_mm<1, 0, 1, 0><<<dim3(D / 128, N_NODES / 128), 256, 0, stream>>>(
            hid, WTl + 131072, gb2 + (size_t)l * D, h, tmp, N_NODES, D, D2);
        k_bn_stat1<<<128, 256, 0, stream>>>(tmp, part);
        k_bn_stat2<<<1, 256, 0, stream>>>(part, ms);
        k_bn_apply<0><<<EW, 256, 0, stream>>>(tmp, ms, n1g + l * D, n1b + l * D, bufB);
        // --- global attention ---
        k_mm<0, 0, 0, 1><<<dim3(D3 / 128, N_NODES / 128), 256, 0, stream>>>(
            h, WTl + 262144, ab_in + (size_t)l * D3, nullptr, qkv, N_NODES, D3, D);
        k_flash_mfma<<<dim3(NB * NH, S_PG / 64), 256, 0, stream>>>(qkv, ao);
        k_mm<1, 0, 1, 0><<<dim3(D / 128, N_NODES / 128), 256, 0, stream>>>(
            ao, WTl + 458752, ab_out + (size_t)l * D, h, tmp, N_NODES, D, D);
        k_bn_stat1<<<128, 256, 0, stream>>>(tmp, part);
        k_bn_stat2<<<1, 256, 0, stream>>>(part, ms);
        k_bn_apply<1><<<EW, 256, 0, stream>>>(tmp, ms, n2g + l * D, n2b + l * D, bufB);
        // --- combine + MLP ---
        k_mm<0, 1, 0, 1><<<dim3(D2 / 128, N_NODES / 128), 256, 0, stream>>>(
            bufB, WTl + 524288, mb1 + (size_t)l * D2, nullptr, hid, N_NODES, D2, D);
        k_mm<1, 0, 1, 0><<<dim3(D / 128, N_NODES / 128), 256, 0, stream>>>(
            hid, WTl + 655360, mb2 + (size_t)l * D, bufB, tmp, N_NODES, D, D2);
        k_bn_stat1<<<128, 256, 0, stream>>>(tmp, part);
        k_bn_stat2<<<1, 256, 0, stream>>>(part, ms);
        k_bn_apply<0><<<EW, 256, 0, stream>>>(tmp, ms, n3g + l * D, n3b + l * D, h);
    }
    k_pool<<<NB, 256, 0, stream>>>(h, g);
    k_final<<<NB, 256, 0, stream>>>(g, pw1, pb1, pw2, pb2, (float*)d_out);
}

// Round 6
// 1144.387 us; speedup vs baseline: 5.4175x; 1.0097x over previous
//
#include <hip/hip_runtime.h>
#include <hip/hip_bf16.h>
#include <math.h>

#define N_NODES 16384
#define NB      32
#define S_PG    512
#define NE      262144
#define EPG     8192
#define D       256
#define D2      512
#define D3      768
#define NL      4
#define NH      4
#define DHD     64
#define OUTD    768
#define NCOMBO  264
#define WT_PER_LAYER 786432

typedef short s8v __attribute__((ext_vector_type(8)));
typedef float f4v __attribute__((ext_vector_type(4)));

__device__ __forceinline__ unsigned bfr(float f) {   // fp32 -> bf16 bits, RNE
    unsigned u = __float_as_uint(f);
    return (u + 0x7fffu + ((u >> 16) & 1u)) >> 16;
}
__device__ __forceinline__ float b2f(unsigned short u) {
    return __uint_as_float(((unsigned)u) << 16);
}

// ---------------- Atom encoder: h (f32) + hb (bf16) ----------------
__global__ __launch_bounds__(256) void k_atom_enc(const int* __restrict__ x,
                                                  const float* __restrict__ tab,
                                                  float* __restrict__ h,
                                                  unsigned short* __restrict__ hb) {
    int node = blockIdx.x * 4 + (threadIdx.x >> 6);
    int lane = threadIdx.x & 63;
    int dd = lane << 2;
    float4 acc = {0.f, 0.f, 0.f, 0.f};
#pragma unroll
    for (int f = 0; f < 9; ++f) {
        int v = x[node * 9 + f];
        const float4 t = *(const float4*)&tab[((size_t)(f * 119 + v)) * D + dd];
        acc.x += t.x; acc.y += t.y; acc.z += t.z; acc.w += t.w;
    }
    *(float4*)&h[(size_t)node * D + dd] = acc;
    ushort4 o;
    o.x = (unsigned short)bfr(acc.x); o.y = (unsigned short)bfr(acc.y);
    o.z = (unsigned short)bfr(acc.z); o.w = (unsigned short)bfr(acc.w);
    *(ushort4*)&hb[(size_t)node * D + dd] = o;
}

// ---------------- bw[l,fv,:] = bond_tab[fv,:] @ elin_w[l] ----------------
__global__ __launch_bounds__(256) void k_bondw(const float* __restrict__ bond_tab,
                                               const float* __restrict__ elin_w,
                                               float* __restrict__ bw) {
    int blk = blockIdx.x;         // L*66
    int l = blk / 66, fv = blk % 66;
    int dout = threadIdx.x;
    const float* tabrow = bond_tab + (size_t)fv * D;
    const float* w = elin_w + (size_t)l * D * D;
    float acc = 0.f;
    for (int d = 0; d < D; ++d) acc = fmaf(tabrow[d], w[d * D + dout], acc);
    bw[((size_t)l * 66 + fv) * D + dout] = acc;
}

// ---------------- combo table ----------------
__global__ __launch_bounds__(256) void k_combo(const float* __restrict__ bw,
                                               const float* __restrict__ elin_b,
                                               float* __restrict__ ct) {
    int b = blockIdx.x;           // NL*264
    int l = b / NCOMBO, cid = b % NCOMBO;
    int a0 = cid / 12, a1 = (cid % 12) / 2, a2 = cid & 1;
    int d = threadIdx.x;
    const float* bwl = bw + (size_t)l * 66 * D;
    ct[((size_t)l * NCOMBO + cid) * D + d] =
        bwl[(size_t)a0 * D + d] + bwl[(size_t)(22 + a1) * D + d] +
        bwl[(size_t)(44 + a2) * D + d] + elin_b[(size_t)l * D + d];
}

// ---------------- CSR build ----------------
__global__ __launch_bounds__(256) void k_zero16k(int* __restrict__ p) {
    p[blockIdx.x * 256 + threadIdx.x] = 0;
}
__global__ __launch_bounds__(256) void k_hist(const int* __restrict__ dst, int* __restrict__ deg) {
    int e = blockIdx.x * 256 + threadIdx.x;
    atomicAdd(&deg[dst[e]], 1);
}
__global__ __launch_bounds__(256) void k_scan(const int* __restrict__ deg,
                                              int* __restrict__ row_ptr,
                                              int* __restrict__ cursor) {
    __shared__ int partial[256];
    int t = threadIdx.x;
    int base = t * 64;
    int s = 0;
    for (int i = 0; i < 64; ++i) s += deg[base + i];
    partial[t] = s;
    __syncthreads();
    for (int dstp = 1; dstp < 256; dstp <<= 1) {
        int v = (t >= dstp) ? partial[t - dstp] : 0;
        __syncthreads();
        partial[t] += v;
        __syncthreads();
    }
    int run = partial[t] - s;   // exclusive start of this chunk
    for (int i = 0; i < 64; ++i) {
        int dcur = deg[base + i];
        row_ptr[base + i] = run;
        cursor[base + i] = run;
        run += dcur;
    }
    if (t == 255) row_ptr[N_NODES] = run;
}
__global__ __launch_bounds__(256) void k_scatter(const int* __restrict__ src,
                                                 const int* __restrict__ dst,
                                                 const int* __restrict__ ea,
                                                 int* __restrict__ cursor,
                                                 int2* __restrict__ sorted) {
    int e = blockIdx.x * 256 + threadIdx.x;
    int d = dst[e];
    int pos = atomicAdd(&cursor[d], 1);
    int cid = ea[e * 3] * 12 + ea[e * 3 + 1] * 2 + ea[e * 3 + 2];
    sorted[pos] = make_int2(src[e], cid);
}

// ---------------- GINE aggregation (gather, no atomics): one wave per node ----------------
__global__ __launch_bounds__(256) void k_gine_agg(const float* __restrict__ h,
                                                  const float* __restrict__ ct,
                                                  const float* __restrict__ eps, int l,
                                                  const int* __restrict__ row_ptr,
                                                  const int2* __restrict__ sorted,
                                                  unsigned short* __restrict__ aggb) {
    int w = threadIdx.x >> 6;
    int lane = threadIdx.x & 63;
    int n = blockIdx.x * 4 + w;
    int dd = lane << 2;
    int beg = row_ptr[n], end = row_ptr[n + 1];
    float4 acc = {0.f, 0.f, 0.f, 0.f};
    for (int i = beg; i < end; ++i) {
        int2 e = sorted[i];
        float4 hv = *(const float4*)&h[(size_t)e.x * D + dd];
        float4 cv = *(const float4*)&ct[(size_t)e.y * D + dd];
        acc.x += fmaxf(hv.x + cv.x, 0.f);
        acc.y += fmaxf(hv.y + cv.y, 0.f);
        acc.z += fmaxf(hv.z + cv.z, 0.f);
        acc.w += fmaxf(hv.w + cv.w, 0.f);
    }
    float s1p = 1.f + eps[l];
    float4 hn = *(const float4*)&h[(size_t)n * D + dd];
    ushort4 o;
    o.x = (unsigned short)bfr(s1p * hn.x + acc.x);
    o.y = (unsigned short)bfr(s1p * hn.y + acc.y);
    o.z = (unsigned short)bfr(s1p * hn.z + acc.z);
    o.w = (unsigned short)bfr(s1p * hn.w + acc.w);
    *(ushort4*)&aggb[(size_t)n * D + dd] = o;
}

// ---------------- weight transpose+convert: W[K][N] f32 -> WT[N][K] bf16 ----------------
__global__ __launch_bounds__(256) void k_wcvt(const float* __restrict__ gw1, const float* __restrict__ gw2,
                                              const float* __restrict__ aw_in, const float* __restrict__ aw_out,
                                              const float* __restrict__ mw1, const float* __restrict__ mw2,
                                              unsigned short* __restrict__ WT) {
    const int KS[6]   = {256, 512, 256, 256, 256, 512};
    const int NS[6]   = {512, 256, 768, 256, 512, 256};
    const int TOFF[7] = {0, 128, 256, 448, 512, 640, 768};
    const int DOFF[6] = {0, 131072, 262144, 458752, 524288, 655360};
    int b = blockIdx.x;
    int l = b / 768, wb = b % 768;
    int widx = 0;
    while (wb >= TOFF[widx + 1]) ++widx;
    int t = wb - TOFF[widx];
    int K = KS[widx], N = NS[widx];
    int nn = N / 32;
    int kt = t / nn, nt = t % nn;
    const float* srcs[6] = {gw1, gw2, aw_in, aw_out, mw1, mw2};
    const float* W = srcs[widx] + (size_t)l * K * N;
    unsigned short* WTp = WT + (size_t)l * WT_PER_LAYER + DOFF[widx];
    __shared__ float tile[32][33];
    int tid = threadIdx.x;
    int r = tid >> 3, c4 = (tid & 7) << 2;
    float4 v = *(const float4*)&W[(size_t)(kt * 32 + r) * N + nt * 32 + c4];
    tile[r][c4] = v.x; tile[r][c4 + 1] = v.y; tile[r][c4 + 2] = v.z; tile[r][c4 + 3] = v.w;
    __syncthreads();
    int nr = tid >> 3, kc = (tid & 7) << 2;
    ushort4 o;
    o.x = (unsigned short)bfr(tile[kc + 0][nr]);
    o.y = (unsigned short)bfr(tile[kc + 1][nr]);
    o.z = (unsigned short)bfr(tile[kc + 2][nr]);
    o.w = (unsigned short)bfr(tile[kc + 3][nr]);
    *(ushort4*)&WTp[(size_t)(nt * 32 + nr) * K + kt * 32 + kc] = o;
}

// ---------------- m97-style bf16 MFMA GEMM: C = op(A @ BT^T + bias [+ res]) ----------------
// A [M][K] bf16 row-major; BT [N][K] bf16 row-major. BK=64, linear LDS, global_load_lds w16.
template<int RELU, int RES, int OBF>
__global__ __launch_bounds__(256) void k_mm2(const unsigned short* __restrict__ A,
                                             const unsigned short* __restrict__ BT,
                                             const float* __restrict__ bias,
                                             const float* __restrict__ res,
                                             void* __restrict__ Cp,
                                             int M, int N, int K) {
    __shared__ unsigned short As[128 * 64];
    __shared__ unsigned short Bs[128 * 64];
    const int tid = threadIdx.x;
    const int row0 = blockIdx.y * 128, col0 = blockIdx.x * 128;
    const int w = tid >> 6, l = tid & 63;
    const int wm = w >> 1, wn = w & 1;
    const int lr = l & 15, lq = l >> 4;
    const int srow = l >> 3;            // 0..7: row within an 8-row group
    const int scol = (l & 7) * 8;       // shorts: 16B column segment
    f4v acc[4][4] = {};

    const unsigned short* Ag = A + (size_t)(row0 + w * 32 + srow) * K + scol;
    const unsigned short* Bg = BT + (size_t)(col0 + w * 32 + srow) * K + scol;
    unsigned short* Al = &As[(w * 32) * 64];
    unsigned short* Bl = &Bs[(w * 32) * 64];

    for (int k0 = 0; k0 < K; k0 += 64) {
#pragma unroll
        for (int it = 0; it < 4; ++it) {
            __builtin_amdgcn_global_load_lds(
                (const __attribute__((address_space(1))) unsigned*)(Ag + (size_t)(it * 8) * K + k0),
                (__attribute__((address_space(3))) unsigned*)(Al + it * 8 * 64), 16, 0, 0);
            __builtin_amdgcn_global_load_lds(
                (const __attribute__((address_space(1))) unsigned*)(Bg + (size_t)(it * 8) * K + k0),
                (__attribute__((address_space(3))) unsigned*)(Bl + it * 8 * 64), 16, 0, 0);
        }
        asm volatile("s_waitcnt vmcnt(0)" ::: "memory");
        __syncthreads();
#pragma unroll
        for (int kk = 0; kk < 2; ++kk) {
            s8v af[4], bf[4];
#pragma unroll
            for (int m = 0; m < 4; ++m)
                af[m] = *(const s8v*)&As[(wm * 64 + m * 16 + lr) * 64 + kk * 32 + lq * 8];
#pragma unroll
            for (int n = 0; n < 4; ++n)
                bf[n] = *(const s8v*)&Bs[(wn * 64 + n * 16 + lr) * 64 + kk * 32 + lq * 8];
#pragma unroll
            for (int m = 0; m < 4; ++m)
#pragma unroll
                for (int n = 0; n < 4; ++n)
                    acc[m][n] = __builtin_amdgcn_mfma_f32_16x16x32_bf16(af[m], bf[n], acc[m][n], 0, 0, 0);
        }
        __syncthreads();
    }
#pragma unroll
    for (int n = 0; n < 4; ++n) {
        int c = col0 + wn * 64 + n * 16 + lr;
        float bv = bias[c];
#pragma unroll
        for (int m = 0; m < 4; ++m) {
#pragma unroll
            for (int j = 0; j < 4; ++j) {
                int r = row0 + wm * 64 + m * 16 + lq * 4 + j;
                float v = acc[m][n][j] + bv;
                if (RES) v += res[(size_t)r * N + c];
                if (RELU) v = fmaxf(v, 0.f);
                if (OBF) ((unsigned short*)Cp)[(size_t)r * N + c] = (unsigned short)bfr(v);
                else ((float*)Cp)[(size_t)r * N + c] = v;
            }
        }
    }
}

// ---------------- BatchNorm: two-stage stats + apply ----------------
__global__ __launch_bounds__(256) void k_bn_stat1(const float* __restrict__ x,
                                                  float* __restrict__ part) {
    int c = threadIdx.x;
    int blk = blockIdx.x;                    // 128 blocks x 128 rows
    const float* p = x + (size_t)blk * 128 * D + c;
    float s = 0.f, s2 = 0.f;
    for (int r = 0; r < 128; ++r) { float v = p[(size_t)r * D]; s += v; s2 += v * v; }
    part[blk * 2 * D + c] = s;
    part[blk * 2 * D + D + c] = s2;
}

__global__ __launch_bounds__(256) void k_bn_stat2(const float* __restrict__ part,
                                                  float* __restrict__ ms) {
    int c = threadIdx.x;
    float s = 0.f, s2 = 0.f;
    for (int p = 0; p < 128; ++p) { s += part[p * 2 * D + c]; s2 += part[p * 2 * D + D + c]; }
    float mean = s / (float)N_NODES;
    float var = s2 / (float)N_NODES - mean * mean;
    ms[c] = mean;
    ms[D + c] = rsqrtf(var + 1e-5f);
}

// ADD=0: y = bn(x).  ADD=1: y += bn(x).  BF=1: also write bf16 copy to yb.
template<int ADD, int BF>
__global__ __launch_bounds__(256) void k_bn_apply(const float* __restrict__ x,
                                                  const float* __restrict__ ms,
                                                  const float* __restrict__ g,
                                                  const float* __restrict__ b,
                                                  float* __restrict__ y,
                                                  unsigned short* __restrict__ yb) {
    size_t i4 = (size_t)blockIdx.x * blockDim.x + threadIdx.x;
    int c = (int)((i4 & 63) << 2);
    float4 v = ((const float4*)x)[i4];
    v.x = (v.x - ms[c + 0]) * ms[D + c + 0] * g[c + 0] + b[c + 0];
    v.y = (v.y - ms[c + 1]) * ms[D + c + 1] * g[c + 1] + b[c + 1];
    v.z = (v.z - ms[c + 2]) * ms[D + c + 2] * g[c + 2] + b[c + 2];
    v.w = (v.w - ms[c + 3]) * ms[D + c + 3] * g[c + 3] + b[c + 3];
    if (ADD) {
        float4 o = ((const float4*)y)[i4];
        v.x += o.x; v.y += o.y; v.z += o.z; v.w += o.w;
    }
    ((float4*)y)[i4] = v;
    if (BF) {
        ushort4 o;
        o.x = (unsigned short)bfr(v.x); o.y = (unsigned short)bfr(v.y);
        o.z = (unsigned short)bfr(v.z); o.w = (unsigned short)bfr(v.w);
        ((ushort4*)yb)[i4] = o;
    }
}

// ---------------- MFMA flash attention ----------------
__global__ __launch_bounds__(256) void k_flash_mfma(const unsigned short* __restrict__ qkv,
                                                    unsigned short* __restrict__ ao) {
    __shared__ unsigned short Ks[64][72];          // K tile  [kv][d], pad 72
    __shared__ unsigned short VT[64][66];          // V^T tile [d][kv], pad 66
    __shared__ unsigned short Ps[4][16][72];       // per-wave P tile [q][kv], pad 72
    const int bh = blockIdx.x;                     // 0..127
    const int b = bh >> 2, hh = bh & 3;
    const int i0 = blockIdx.y << 6;
    const int tid = threadIdx.x;
    const int w = tid >> 6, l = tid & 63;
    const int lr = l & 15, lq = l >> 4;
    const int hd = hh * DHD;
    const size_t rowbase = (size_t)(b * S_PG) * D3;

    s8v aq[2];
    {
        const unsigned short* qrow = &qkv[rowbase + (size_t)(i0 + w * 16 + lr) * D3 + hd + lq * 8];
        aq[0] = *(const s8v*)&qrow[0];
        aq[1] = *(const s8v*)&qrow[32];
    }

    float mrow[4] = {-INFINITY, -INFINITY, -INFINITY, -INFINITY};
    float lrow[4] = {0.f, 0.f, 0.f, 0.f};
    f4v oacc[4] = {};

    const int skv = tid >> 2;                      // staging kv row 0..63
    const int sd0 = (tid & 3) << 4;                // staging d segment 0,16,32,48

    for (int j0 = 0; j0 < S_PG; j0 += 64) {
        __syncthreads();
        {
            const unsigned short* kr = &qkv[rowbase + (size_t)(j0 + skv) * D3 + D + hd + sd0];
            *(uint4*)&Ks[skv][sd0]     = *(const uint4*)&kr[0];
            *(uint4*)&Ks[skv][sd0 + 8] = *(const uint4*)&kr[8];
            const unsigned short* vr = &qkv[rowbase + (size_t)(j0 + skv) * D3 + D2 + hd + sd0];
            unsigned short vv[16];
            *(uint4*)&vv[0] = *(const uint4*)&vr[0];
            *(uint4*)&vv[8] = *(const uint4*)&vr[8];
#pragma unroll
            for (int i = 0; i < 16; ++i) VT[sd0 + i][skv] = vv[i];
        }
        __syncthreads();
        f4v sc[4] = {};
#pragma unroll
        for (int nt = 0; nt < 4; ++nt) {
            s8v bk0 = *(const s8v*)&Ks[nt * 16 + lr][lq * 8];
            s8v bk1 = *(const s8v*)&Ks[nt * 16 + lr][32 + lq * 8];
            sc[nt] = __builtin_amdgcn_mfma_f32_16x16x32_bf16(aq[0], bk0, sc[nt], 0, 0, 0);
            sc[nt] = __builtin_amdgcn_mfma_f32_16x16x32_bf16(aq[1], bk1, sc[nt], 0, 0, 0);
        }
        float ps[4][4], alpha[4];
#pragma unroll
        for (int j = 0; j < 4; ++j) {
#pragma unroll
            for (int nt = 0; nt < 4; ++nt) ps[nt][j] = sc[nt][j] * 0.125f;
            float pm = fmaxf(fmaxf(ps[0][j], ps[1][j]), fmaxf(ps[2][j], ps[3][j]));
#pragma unroll
            for (int off = 1; off < 16; off <<= 1) pm = fmaxf(pm, __shfl_xor(pm, off));
            float mn = fmaxf(mrow[j], pm);
            alpha[j] = __expf(mrow[j] - mn);
            float rs = 0.f;
#pragma unroll
            for (int nt = 0; nt < 4; ++nt) { ps[nt][j] = __expf(ps[nt][j] - mn); rs += ps[nt][j]; }
#pragma unroll
            for (int off = 1; off < 16; off <<= 1) rs += __shfl_xor(rs, off);
            lrow[j] = lrow[j] * alpha[j] + rs;
            mrow[j] = mn;
        }
#pragma unroll
        for (int nt = 0; nt < 4; ++nt)
#pragma unroll
            for (int j = 0; j < 4; ++j)
                Ps[w][lq * 4 + j][nt * 16 + lr] = (unsigned short)bfr(ps[nt][j]);
#pragma unroll
        for (int ntd = 0; ntd < 4; ++ntd)
#pragma unroll
            for (int j = 0; j < 4; ++j) oacc[ntd][j] *= alpha[j];
        s8v pa0 = *(const s8v*)&Ps[w][lr][lq * 8];
        s8v pa1 = *(const s8v*)&Ps[w][lr][32 + lq * 8];
#pragma unroll
        for (int ntd = 0; ntd < 4; ++ntd) {
            s8v bv0 = *(const s8v*)&VT[ntd * 16 + lr][lq * 8];
            s8v bv1 = *(const s8v*)&VT[ntd * 16 + lr][32 + lq * 8];
            oacc[ntd] = __builtin_amdgcn_mfma_f32_16x16x32_bf16(pa0, bv0, oacc[ntd], 0, 0, 0);
            oacc[ntd] = __builtin_amdgcn_mfma_f32_16x16x32_bf16(pa1, bv1, oacc[ntd], 0, 0, 0);
        }
    }
#pragma unroll
    for (int j = 0; j < 4; ++j) {
        float inv = 1.f / lrow[j];
        int node = b * S_PG + i0 + w * 16 + lq * 4 + j;
#pragma unroll
        for (int ntd = 0; ntd < 4; ++ntd)
            ao[(size_t)node * D + hd + ntd * 16 + lr] = (unsigned short)bfr(oacc[ntd][j] * inv);
    }
}

// ---------------- mean pool per graph ----------------
__global__ __launch_bounds__(256) void k_pool(const float* __restrict__ h, float* __restrict__ g) {
    int b = blockIdx.x, c = threadIdx.x;
    const float* p = h + (size_t)b * S_PG * D + c;
    float s = 0.f;
    for (int r = 0; r < S_PG; ++r) s += p[(size_t)r * D];
    g[b * D + c] = s * (1.f / (float)S_PG);
}

// ---------------- final head ----------------
__global__ __launch_bounds__(256) void k_final(const float* __restrict__ g,
                                               const float* __restrict__ pw1,
                                               const float* __restrict__ pb1,
                                               const float* __restrict__ pw2,
                                               const float* __restrict__ pb2,
                                               float* __restrict__ out) {
    __shared__ float gs[D];
    __shared__ float ts[D];
    __shared__ float red[4];
    int b = blockIdx.x, tid = threadIdx.x;
    gs[tid] = g[b * D + tid];
    __syncthreads();
    float acc = pb1[tid];
    for (int d = 0; d < D; ++d) acc = fmaf(gs[d], pw1[d * D + tid], acc);
    ts[tid] = fmaxf(acc, 0.f);
    __syncthreads();
    float z[3];
#pragma unroll
    for (int rep = 0; rep < 3; ++rep) {
        int j = tid + rep * 256;
        float a = pb2[j];
        for (int d = 0; d < D; ++d) a = fmaf(ts[d], pw2[(size_t)d * OUTD + j], a);
        z[rep] = a;
    }
    float ss = z[0] * z[0] + z[1] * z[1] + z[2] * z[2];
#pragma unroll
    for (int o = 32; o >= 1; o >>= 1) ss += __shfl_xor(ss, o);
    if ((tid & 63) == 0) red[tid >> 6] = ss;
    __syncthreads();
    float rn = rsqrtf(red[0] + red[1] + red[2] + red[3]);
#pragma unroll
    for (int rep = 0; rep < 3; ++rep) out[b * OUTD + tid + rep * 256] = z[rep] * rn;
}

extern "C" void kernel_launch(void* const* d_in, const int* in_sizes, int n_in,
                              void* d_out, int out_size, void* d_ws, size_t ws_size,
                              hipStream_t stream) {
    const int* x        = (const int*)d_in[0];
    const int* ea       = (const int*)d_in[1];
    const int* eidx     = (const int*)d_in[2];
    const float* atom_tab = (const float*)d_in[4];
    const float* bond_tab = (const float*)d_in[5];
    const float* elin_w = (const float*)d_in[6];
    const float* elin_b = (const float*)d_in[7];
    const float* eps    = (const float*)d_in[8];
    const float* gw1    = (const float*)d_in[9];
    const float* gb1    = (const float*)d_in[10];
    const float* gw2    = (const float*)d_in[11];
    const float* gb2    = (const float*)d_in[12];
    const float* aw_in  = (const float*)d_in[13];
    const float* ab_in  = (const float*)d_in[14];
    const float* aw_out = (const float*)d_in[15];
    const float* ab_out = (const float*)d_in[16];
    const float* n1g    = (const float*)d_in[17];
    const float* n1b    = (const float*)d_in[18];
    const float* n2g    = (const float*)d_in[19];
    const float* n2b    = (const float*)d_in[20];
    const float* n3g    = (const float*)d_in[21];
    const float* n3b    = (const float*)d_in[22];
    const float* mw1    = (const float*)d_in[23];
    const float* mb1    = (const float*)d_in[24];
    const float* mw2    = (const float*)d_in[25];
    const float* mb2    = (const float*)d_in[26];
    const float* pw1    = (const float*)d_in[27];
    const float* pb1    = (const float*)d_in[28];
    const float* pw2    = (const float*)d_in[29];
    const float* pb2    = (const float*)d_in[30];

    // ---- workspace layout (~99 MiB) ----
    char* ws = (char*)d_ws;
    size_t off = 0;
    auto alloc = [&](size_t bytes) {
        void* p = ws + off;
        off += (bytes + 255) & ~(size_t)255;
        return p;
    };
    float*  h    = (float*)alloc((size_t)N_NODES * D * 4);          // 16 MiB layer state (f32)
    float*  bufB = (float*)alloc((size_t)N_NODES * D * 4);          // 16 MiB hc accumulator (f32)
    unsigned short* hb = (unsigned short*)alloc((size_t)N_NODES * D * 2);  // 8 MiB bf16 copy of h
    char*   U    = (char*)alloc((size_t)N_NODES * D3 * 2);          // 24 MiB: tmp f32 [N,256] / qkv bf16 [N,768]
    unsigned short* bfA = (unsigned short*)alloc((size_t)N_NODES * D3 * 2); // 24 MiB: agg/ao/bufBb @0, hid @ N*D
    unsigned short* WT  = (unsigned short*)alloc((size_t)NL * WT_PER_LAYER * 2); // 6.3 MiB
    float*  bw   = (float*)alloc((size_t)NL * 66 * D * 4);
    float*  ct   = (float*)alloc((size_t)NL * NCOMBO * D * 4);
    int*    deg  = (int*)alloc((size_t)N_NODES * 4);
    int*    row_ptr = (int*)alloc((size_t)(N_NODES + 1) * 4);
    int*    cursor  = (int*)alloc((size_t)N_NODES * 4);
    int2*   sorted  = (int2*)alloc((size_t)NE * 8);
    float*  part = (float*)alloc((size_t)128 * 2 * D * 4);
    float*  ms   = (float*)alloc((size_t)2 * D * 4);
    float*  g    = (float*)alloc((size_t)NB * D * 4);
    (void)ws_size; (void)in_sizes; (void)n_in; (void)out_size;

    float* tmp = (float*)U;                       // [N,256] f32 (pre-BN)
    unsigned short* qkv = (unsigned short*)U;     // [N,768] bf16
    unsigned short* aggb  = bfA;                  // [N,256] bf16 (lifetime: agg -> GEMM1)
    unsigned short* ao    = bfA;                  // [N,256] bf16 (lifetime: flash -> aw_out)
    unsigned short* bufBb = bfA;                  // [N,256] bf16 (lifetime: bn2-apply -> mw1)
    unsigned short* hid   = bfA + (size_t)N_NODES * D;  // [N,512] bf16

    const int* srcp = eidx;
    const int* dstp = eidx + NE;
    const int EW = N_NODES * D / 1024;

    // one-time per launch
    k_zero16k<<<N_NODES / 256, 256, 0, stream>>>(deg);
    k_hist<<<NE / 256, 256, 0, stream>>>(dstp, deg);
    k_scan<<<1, 256, 0, stream>>>(deg, row_ptr, cursor);
    k_scatter<<<NE / 256, 256, 0, stream>>>(srcp, dstp, ea, cursor, sorted);
    k_atom_enc<<<N_NODES / 4, 256, 0, stream>>>(x, atom_tab, h, hb);
    k_bondw<<<NL * 66, 256, 0, stream>>>(bond_tab, elin_w, bw);
    k_combo<<<NL * NCOMBO, 256, 0, stream>>>(bw, elin_b, ct);
    k_wcvt<<<NL * 768, 256, 0, stream>>>(gw1, gw2, aw_in, aw_out, mw1, mw2, WT);

    for (int l = 0; l < NL; ++l) {
        const unsigned short* WTl = WT + (size_t)l * WT_PER_LAYER;
        // --- GINE local branch ---
        k_gine_agg<<<N_NODES / 4, 256, 0, stream>>>(h, ct + (size_t)l * NCOMBO * D, eps, l,
                                                    row_ptr, sorted, aggb);
        k_mm2<1, 0, 1><<<dim3(D2 / 128, N_NODES / 128), 256, 0, stream>>>(
            aggb, WTl + 0, gb1 + (size_t)l * D2, nullptr, hid, N_NODES, D2, D);
        k_mm2<0, 1, 0><<<dim3(D / 128, N_NODES / 128), 256, 0, stream>>>(
            hid, WTl + 131072, gb2 + (size_t)l * D, h, tmp, N_NODES, D, D2);
        k_bn_stat1<<<128, 256, 0, stream>>>(tmp, part);
        k_bn_stat2<<<1, 256, 0, stream>>>(part, ms);
        k_bn_apply<0, 0><<<EW, 256, 0, stream>>>(tmp, ms, n1g + l * D, n1b + l * D, bufB, nullptr);
        // --- global attention ---
        k_mm2<0, 0, 1><<<dim3(D3 / 128, N_NODES / 128), 256, 0, stream>>>(
            hb, WTl + 262144, ab_in + (size_t)l * D3, nullptr, qkv, N_NODES, D3, D);
        k_flash_mfma<<<dim3(NB * NH, S_PG / 64), 256, 0, stream>>>(qkv, ao);
        k_mm2<0, 1, 0><<<dim3(D / 128, N_NODES / 128), 256, 0, stream>>>(
            ao, WTl + 458752, ab_out + (size_t)l * D, h, tmp, N_NODES, D, D);
        k_bn_stat1<<<128, 256, 0, stream>>>(tmp, part);
        k_bn_stat2<<<1, 256, 0, stream>>>(part, ms);
        k_bn_apply<1, 1><<<EW, 256, 0, stream>>>(tmp, ms, n2g + l * D, n2b + l * D, bufB, bufBb);
        // --- combine + MLP ---
        k_mm2<1, 0, 1><<<dim3(D2 / 128, N_NODES / 128), 256, 0, stream>>>(
            bufBb, WTl + 524288, mb1 + (size_t)l * D2, nullptr, hid, N_NODES, D2, D);
        k_mm2<0, 1, 0><<<dim3(D / 128, N_NODES / 128), 256, 0, stream>>>(
            hid, WTl + 655360, mb2 + (size_t)l * D, bufB, tmp, N_NODES, D, D2);
        k_bn_stat1<<<128, 256, 0, stream>>>(tmp, part);
        k_bn_stat2<<<1, 256, 0, stream>>>(part, ms);
        k_bn_apply<0, 1><<<EW, 256, 0, stream>>>(tmp, ms, n3g + l * D, n3b + l * D, h, hb);
    }
    k_pool<<<NB, 256, 0, stream>>>(h, g);
    k_final<<<NB, 256, 0, stream>>>(g, pw1, pb1, pw2, pb2, (float*)d_out);
}

// Round 7
// 1008.646 us; speedup vs baseline: 6.1466x; 1.1346x over previous
//
#include <hip/hip_runtime.h>
#include <hip/hip_bf16.h>
#include <math.h>

#define N_NODES 16384
#define NB      32
#define S_PG    512
#define NE      262144
#define EPG     8192
#define D       256
#define D2      512
#define D3      768
#define NL      4
#define NH      4
#define DHD     64
#define OUTD    768
#define NCOMBO  264
#define WT_PER_LAYER 786432

typedef short s8v __attribute__((ext_vector_type(8)));
typedef float f4v __attribute__((ext_vector_type(4)));

__device__ __forceinline__ unsigned bfr(float f) {   // fp32 -> bf16 bits, RNE
    unsigned u = __float_as_uint(f);
    return (u + 0x7fffu + ((u >> 16) & 1u)) >> 16;
}
__device__ __forceinline__ float b2f(unsigned short u) {
    return __uint_as_float(((unsigned)u) << 16);
}

// ---------------- Atom encoder: h (f32) + hb (bf16) ----------------
__global__ __launch_bounds__(256) void k_atom_enc(const int* __restrict__ x,
                                                  const float* __restrict__ tab,
                                                  float* __restrict__ h,
                                                  unsigned short* __restrict__ hb) {
    int node = blockIdx.x * 4 + (threadIdx.x >> 6);
    int lane = threadIdx.x & 63;
    int dd = lane << 2;
    float4 acc = {0.f, 0.f, 0.f, 0.f};
#pragma unroll
    for (int f = 0; f < 9; ++f) {
        int v = x[node * 9 + f];
        const float4 t = *(const float4*)&tab[((size_t)(f * 119 + v)) * D + dd];
        acc.x += t.x; acc.y += t.y; acc.z += t.z; acc.w += t.w;
    }
    *(float4*)&h[(size_t)node * D + dd] = acc;
    ushort4 o;
    o.x = (unsigned short)bfr(acc.x); o.y = (unsigned short)bfr(acc.y);
    o.z = (unsigned short)bfr(acc.z); o.w = (unsigned short)bfr(acc.w);
    *(ushort4*)&hb[(size_t)node * D + dd] = o;
}

// ---------------- bw[l,fv,:] = bond_tab[fv,:] @ elin_w[l] ----------------
__global__ __launch_bounds__(256) void k_bondw(const float* __restrict__ bond_tab,
                                               const float* __restrict__ elin_w,
                                               float* __restrict__ bw) {
    int blk = blockIdx.x;         // L*66
    int l = blk / 66, fv = blk % 66;
    int dout = threadIdx.x;
    const float* tabrow = bond_tab + (size_t)fv * D;
    const float* w = elin_w + (size_t)l * D * D;
    float acc = 0.f;
    for (int d = 0; d < D; ++d) acc = fmaf(tabrow[d], w[d * D + dout], acc);
    bw[((size_t)l * 66 + fv) * D + dout] = acc;
}

// ---------------- combo table (bf16): ctb[l,cid,:] ----------------
__global__ __launch_bounds__(256) void k_combo(const float* __restrict__ bw,
                                               const float* __restrict__ elin_b,
                                               unsigned short* __restrict__ ctb) {
    int b = blockIdx.x;           // NL*264
    int l = b / NCOMBO, cid = b % NCOMBO;
    int a0 = cid / 12, a1 = (cid % 12) / 2, a2 = cid & 1;
    int d = threadIdx.x;
    const float* bwl = bw + (size_t)l * 66 * D;
    float v = bwl[(size_t)a0 * D + d] + bwl[(size_t)(22 + a1) * D + d] +
              bwl[(size_t)(44 + a2) * D + d] + elin_b[(size_t)l * D + d];
    ctb[((size_t)l * NCOMBO + cid) * D + d] = (unsigned short)bfr(v);
}

// ---------------- CSR build ----------------
__global__ __launch_bounds__(256) void k_zero16k(int* __restrict__ p) {
    p[blockIdx.x * 256 + threadIdx.x] = 0;
}
__global__ __launch_bounds__(256) void k_zero_stats(float* __restrict__ p) {
    for (int i = 0; i < 6; ++i) p[i * 256 + threadIdx.x] = 0.f;   // 3 slots x 512
}
__global__ __launch_bounds__(256) void k_hist(const int* __restrict__ dst, int* __restrict__ deg) {
    int e = blockIdx.x * 256 + threadIdx.x;
    atomicAdd(&deg[dst[e]], 1);
}
__global__ __launch_bounds__(256) void k_scan(const int* __restrict__ deg,
                                              int* __restrict__ row_ptr,
                                              int* __restrict__ cursor) {
    __shared__ int partial[256];
    int t = threadIdx.x;
    int base = t * 64;
    int s = 0;
    for (int i = 0; i < 64; ++i) s += deg[base + i];
    partial[t] = s;
    __syncthreads();
    for (int dstp = 1; dstp < 256; dstp <<= 1) {
        int v = (t >= dstp) ? partial[t - dstp] : 0;
        __syncthreads();
        partial[t] += v;
        __syncthreads();
    }
    int run = partial[t] - s;   // exclusive start of this chunk
    for (int i = 0; i < 64; ++i) {
        int dcur = deg[base + i];
        row_ptr[base + i] = run;
        cursor[base + i] = run;
        run += dcur;
    }
    if (t == 255) row_ptr[N_NODES] = run;
}
__global__ __launch_bounds__(256) void k_scatter(const int* __restrict__ src,
                                                 const int* __restrict__ dst,
                                                 const int* __restrict__ ea,
                                                 int* __restrict__ cursor,
                                                 int2* __restrict__ sorted) {
    int e = blockIdx.x * 256 + threadIdx.x;
    int d = dst[e];
    int pos = atomicAdd(&cursor[d], 1);
    int cid = ea[e * 3] * 12 + ea[e * 3 + 1] * 2 + ea[e * 3 + 2];
    sorted[pos] = make_int2(src[e], cid);
}

// ---------------- GINE aggregation (bf16 gather, no atomics): one wave per node ----------------
__global__ __launch_bounds__(256) void k_gine_agg(const unsigned short* __restrict__ hb,
                                                  const float* __restrict__ h,
                                                  const unsigned short* __restrict__ ctb,
                                                  const float* __restrict__ eps, int l,
                                                  const int* __restrict__ row_ptr,
                                                  const int2* __restrict__ sorted,
                                                  unsigned short* __restrict__ aggb) {
    int w = threadIdx.x >> 6;
    int lane = threadIdx.x & 63;
    int n = blockIdx.x * 4 + w;
    int dd = lane << 2;
    int beg = row_ptr[n], end = row_ptr[n + 1];
    float4 acc = {0.f, 0.f, 0.f, 0.f};
    int i = beg;
    for (; i + 2 <= end; i += 2) {
        int2 e0 = sorted[i];
        int2 e1 = sorted[i + 1];
        ushort4 h0 = *(const ushort4*)&hb[(size_t)e0.x * D + dd];
        ushort4 c0 = *(const ushort4*)&ctb[(size_t)e0.y * D + dd];
        ushort4 h1 = *(const ushort4*)&hb[(size_t)e1.x * D + dd];
        ushort4 c1 = *(const ushort4*)&ctb[(size_t)e1.y * D + dd];
        acc.x += fmaxf(b2f(h0.x) + b2f(c0.x), 0.f) + fmaxf(b2f(h1.x) + b2f(c1.x), 0.f);
        acc.y += fmaxf(b2f(h0.y) + b2f(c0.y), 0.f) + fmaxf(b2f(h1.y) + b2f(c1.y), 0.f);
        acc.z += fmaxf(b2f(h0.z) + b2f(c0.z), 0.f) + fmaxf(b2f(h1.z) + b2f(c1.z), 0.f);
        acc.w += fmaxf(b2f(h0.w) + b2f(c0.w), 0.f) + fmaxf(b2f(h1.w) + b2f(c1.w), 0.f);
    }
    if (i < end) {
        int2 e0 = sorted[i];
        ushort4 h0 = *(const ushort4*)&hb[(size_t)e0.x * D + dd];
        ushort4 c0 = *(const ushort4*)&ctb[(size_t)e0.y * D + dd];
        acc.x += fmaxf(b2f(h0.x) + b2f(c0.x), 0.f);
        acc.y += fmaxf(b2f(h0.y) + b2f(c0.y), 0.f);
        acc.z += fmaxf(b2f(h0.z) + b2f(c0.z), 0.f);
        acc.w += fmaxf(b2f(h0.w) + b2f(c0.w), 0.f);
    }
    float s1p = 1.f + eps[l];
    float4 hn = *(const float4*)&h[(size_t)n * D + dd];
    ushort4 o;
    o.x = (unsigned short)bfr(s1p * hn.x + acc.x);
    o.y = (unsigned short)bfr(s1p * hn.y + acc.y);
    o.z = (unsigned short)bfr(s1p * hn.z + acc.z);
    o.w = (unsigned short)bfr(s1p * hn.w + acc.w);
    *(ushort4*)&aggb[(size_t)n * D + dd] = o;
}

// ---------------- weight transpose+convert: W[K][N] f32 -> WT[N][K] bf16 ----------------
__global__ __launch_bounds__(256) void k_wcvt(const float* __restrict__ gw1, const float* __restrict__ gw2,
                                              const float* __restrict__ aw_in, const float* __restrict__ aw_out,
                                              const float* __restrict__ mw1, const float* __restrict__ mw2,
                                              unsigned short* __restrict__ WT) {
    const int KS[6]   = {256, 512, 256, 256, 256, 512};
    const int NS[6]   = {512, 256, 768, 256, 512, 256};
    const int TOFF[7] = {0, 128, 256, 448, 512, 640, 768};
    const int DOFF[6] = {0, 131072, 262144, 458752, 524288, 655360};
    int b = blockIdx.x;
    int l = b / 768, wb = b % 768;
    int widx = 0;
    while (wb >= TOFF[widx + 1]) ++widx;
    int t = wb - TOFF[widx];
    int K = KS[widx], N = NS[widx];
    int nn = N / 32;
    int kt = t / nn, nt = t % nn;
    const float* srcs[6] = {gw1, gw2, aw_in, aw_out, mw1, mw2};
    const float* W = srcs[widx] + (size_t)l * K * N;
    unsigned short* WTp = WT + (size_t)l * WT_PER_LAYER + DOFF[widx];
    __shared__ float tile[32][33];
    int tid = threadIdx.x;
    int r = tid >> 3, c4 = (tid & 7) << 2;
    float4 v = *(const float4*)&W[(size_t)(kt * 32 + r) * N + nt * 32 + c4];
    tile[r][c4] = v.x; tile[r][c4 + 1] = v.y; tile[r][c4 + 2] = v.z; tile[r][c4 + 3] = v.w;
    __syncthreads();
    int nr = tid >> 3, kc = (tid & 7) << 2;
    ushort4 o;
    o.x = (unsigned short)bfr(tile[kc + 0][nr]);
    o.y = (unsigned short)bfr(tile[kc + 1][nr]);
    o.z = (unsigned short)bfr(tile[kc + 2][nr]);
    o.w = (unsigned short)bfr(tile[kc + 3][nr]);
    *(ushort4*)&WTp[(size_t)(nt * 32 + nr) * K + kt * 32 + kc] = o;
}

// ---------------- m97-style bf16 MFMA GEMM: C = op(A @ BT^T + bias [+ res]) ----------------
// STAT=1: also accumulate per-column sum/sum^2 into stat[c], stat[256+c] (N must be 256).
template<int RELU, int RES, int OBF, int STAT>
__global__ __launch_bounds__(256) void k_mm2(const unsigned short* __restrict__ A,
                                             const unsigned short* __restrict__ BT,
                                             const float* __restrict__ bias,
                                             const float* __restrict__ res,
                                             void* __restrict__ Cp,
                                             float* __restrict__ stat,
                                             int M, int N, int K) {
    __shared__ unsigned short As[128 * 64];
    __shared__ unsigned short Bs[128 * 64];
    const int tid = threadIdx.x;
    const int row0 = blockIdx.y * 128, col0 = blockIdx.x * 128;
    const int w = tid >> 6, l = tid & 63;
    const int wm = w >> 1, wn = w & 1;
    const int lr = l & 15, lq = l >> 4;
    const int srow = l >> 3;
    const int scol = (l & 7) * 8;
    f4v acc[4][4] = {};

    const unsigned short* Ag = A + (size_t)(row0 + w * 32 + srow) * K + scol;
    const unsigned short* Bg = BT + (size_t)(col0 + w * 32 + srow) * K + scol;
    unsigned short* Al = &As[(w * 32) * 64];
    unsigned short* Bl = &Bs[(w * 32) * 64];

    for (int k0 = 0; k0 < K; k0 += 64) {
#pragma unroll
        for (int it = 0; it < 4; ++it) {
            __builtin_amdgcn_global_load_lds(
                (const __attribute__((address_space(1))) unsigned*)(Ag + (size_t)(it * 8) * K + k0),
                (__attribute__((address_space(3))) unsigned*)(Al + it * 8 * 64), 16, 0, 0);
            __builtin_amdgcn_global_load_lds(
                (const __attribute__((address_space(1))) unsigned*)(Bg + (size_t)(it * 8) * K + k0),
                (__attribute__((address_space(3))) unsigned*)(Bl + it * 8 * 64), 16, 0, 0);
        }
        asm volatile("s_waitcnt vmcnt(0)" ::: "memory");
        __syncthreads();
#pragma unroll
        for (int kk = 0; kk < 2; ++kk) {
            s8v af[4], bf[4];
#pragma unroll
            for (int m = 0; m < 4; ++m)
                af[m] = *(const s8v*)&As[(wm * 64 + m * 16 + lr) * 64 + kk * 32 + lq * 8];
#pragma unroll
            for (int n = 0; n < 4; ++n)
                bf[n] = *(const s8v*)&Bs[(wn * 64 + n * 16 + lr) * 64 + kk * 32 + lq * 8];
#pragma unroll
            for (int m = 0; m < 4; ++m)
#pragma unroll
                for (int n = 0; n < 4; ++n)
                    acc[m][n] = __builtin_amdgcn_mfma_f32_16x16x32_bf16(af[m], bf[n], acc[m][n], 0, 0, 0);
        }
        __syncthreads();
    }
    float cs[4], cs2[4];
#pragma unroll
    for (int n = 0; n < 4; ++n) { cs[n] = 0.f; cs2[n] = 0.f; }
#pragma unroll
    for (int n = 0; n < 4; ++n) {
        int c = col0 + wn * 64 + n * 16 + lr;
        float bv = bias[c];
#pragma unroll
        for (int m = 0; m < 4; ++m) {
#pragma unroll
            for (int j = 0; j < 4; ++j) {
                int r = row0 + wm * 64 + m * 16 + lq * 4 + j;
                float v = acc[m][n][j] + bv;
                if (RES) v += res[(size_t)r * N + c];
                if (STAT) { cs[n] += v; cs2[n] += v * v; }
                if (RELU) v = fmaxf(v, 0.f);
                if (OBF) ((unsigned short*)Cp)[(size_t)r * N + c] = (unsigned short)bfr(v);
                else ((float*)Cp)[(size_t)r * N + c] = v;
            }
        }
    }
    if (STAT) {
#pragma unroll
        for (int n = 0; n < 4; ++n) {
            float s = cs[n], s2 = cs2[n];
            s += __shfl_xor(s, 16);  s2 += __shfl_xor(s2, 16);
            s += __shfl_xor(s, 32);  s2 += __shfl_xor(s2, 32);
            if (lq == 0) {
                int c = col0 + wn * 64 + n * 16 + lr;
                atomicAdd(&stat[c], s);
                atomicAdd(&stat[256 + c], s2);
            }
        }
    }
}

// ---------------- BN finish: stats -> mean/rstd, and re-zero accumulator ----------------
__global__ __launch_bounds__(256) void k_bn_finish(float* __restrict__ acc,
                                                   float* __restrict__ ms) {
    int c = threadIdx.x;
    float s = acc[c], s2 = acc[256 + c];
    float mean = s / (float)N_NODES;
    float var = s2 / (float)N_NODES - mean * mean;
    ms[c] = mean;
    ms[D + c] = rsqrtf(var + 1e-5f);
    acc[c] = 0.f;
    acc[256 + c] = 0.f;
}

// ---------------- fused: y = bn1(t1) + bn2(t2), dual write f32 + bf16 ----------------
__global__ __launch_bounds__(256) void k_bn12(const float* __restrict__ t1,
                                              const float* __restrict__ ms1,
                                              const float* __restrict__ g1,
                                              const float* __restrict__ b1,
                                              const float* __restrict__ t2,
                                              const float* __restrict__ ms2,
                                              const float* __restrict__ g2,
                                              const float* __restrict__ b2,
                                              float* __restrict__ y,
                                              unsigned short* __restrict__ yb) {
    size_t i4 = (size_t)blockIdx.x * blockDim.x + threadIdx.x;
    int c = (int)((i4 & 63) << 2);
    float4 v1 = ((const float4*)t1)[i4];
    float4 v2 = ((const float4*)t2)[i4];
    float4 v;
    v.x = (v1.x - ms1[c + 0]) * ms1[D + c + 0] * g1[c + 0] + b1[c + 0]
        + (v2.x - ms2[c + 0]) * ms2[D + c + 0] * g2[c + 0] + b2[c + 0];
    v.y = (v1.y - ms1[c + 1]) * ms1[D + c + 1] * g1[c + 1] + b1[c + 1]
        + (v2.y - ms2[c + 1]) * ms2[D + c + 1] * g2[c + 1] + b2[c + 1];
    v.z = (v1.z - ms1[c + 2]) * ms1[D + c + 2] * g1[c + 2] + b1[c + 2]
        + (v2.z - ms2[c + 2]) * ms2[D + c + 2] * g2[c + 2] + b2[c + 2];
    v.w = (v1.w - ms1[c + 3]) * ms1[D + c + 3] * g1[c + 3] + b1[c + 3]
        + (v2.w - ms2[c + 3]) * ms2[D + c + 3] * g2[c + 3] + b2[c + 3];
    ((float4*)y)[i4] = v;
    ushort4 o;
    o.x = (unsigned short)bfr(v.x); o.y = (unsigned short)bfr(v.y);
    o.z = (unsigned short)bfr(v.z); o.w = (unsigned short)bfr(v.w);
    ((ushort4*)yb)[i4] = o;
}

// ---------------- bn apply (single), dual write ----------------
__global__ __launch_bounds__(256) void k_bn_apply(const float* __restrict__ x,
                                                  const float* __restrict__ ms,
                                                  const float* __restrict__ g,
                                                  const float* __restrict__ b,
                                                  float* __restrict__ y,
                                                  unsigned short* __restrict__ yb) {
    size_t i4 = (size_t)blockIdx.x * blockDim.x + threadIdx.x;
    int c = (int)((i4 & 63) << 2);
    float4 v = ((const float4*)x)[i4];
    v.x = (v.x - ms[c + 0]) * ms[D + c + 0] * g[c + 0] + b[c + 0];
    v.y = (v.y - ms[c + 1]) * ms[D + c + 1] * g[c + 1] + b[c + 1];
    v.z = (v.z - ms[c + 2]) * ms[D + c + 2] * g[c + 2] + b[c + 2];
    v.w = (v.w - ms[c + 3]) * ms[D + c + 3] * g[c + 3] + b[c + 3];
    ((float4*)y)[i4] = v;
    ushort4 o;
    o.x = (unsigned short)bfr(v.x); o.y = (unsigned short)bfr(v.y);
    o.z = (unsigned short)bfr(v.z); o.w = (unsigned short)bfr(v.w);
    ((ushort4*)yb)[i4] = o;
}

// ---------------- MFMA flash attention ----------------
__global__ __launch_bounds__(256) void k_flash_mfma(const unsigned short* __restrict__ qkv,
                                                    unsigned short* __restrict__ ao) {
    __shared__ unsigned short Ks[64][72];
    __shared__ unsigned short VT[64][66];
    __shared__ unsigned short Ps[4][16][72];
    const int bh = blockIdx.x;
    const int b = bh >> 2, hh = bh & 3;
    const int i0 = blockIdx.y << 6;
    const int tid = threadIdx.x;
    const int w = tid >> 6, l = tid & 63;
    const int lr = l & 15, lq = l >> 4;
    const int hd = hh * DHD;
    const size_t rowbase = (size_t)(b * S_PG) * D3;

    s8v aq[2];
    {
        const unsigned short* qrow = &qkv[rowbase + (size_t)(i0 + w * 16 + lr) * D3 + hd + lq * 8];
        aq[0] = *(const s8v*)&qrow[0];
        aq[1] = *(const s8v*)&qrow[32];
    }

    float mrow[4] = {-INFINITY, -INFINITY, -INFINITY, -INFINITY};
    float lrow[4] = {0.f, 0.f, 0.f, 0.f};
    f4v oacc[4] = {};

    const int skv = tid >> 2;
    const int sd0 = (tid & 3) << 4;

    for (int j0 = 0; j0 < S_PG; j0 += 64) {
        __syncthreads();
        {
            const unsigned short* kr = &qkv[rowbase + (size_t)(j0 + skv) * D3 + D + hd + sd0];
            *(uint4*)&Ks[skv][sd0]     = *(const uint4*)&kr[0];
            *(uint4*)&Ks[skv][sd0 + 8] = *(const uint4*)&kr[8];
            const unsigned short* vr = &qkv[rowbase + (size_t)(j0 + skv) * D3 + D2 + hd + sd0];
            unsigned short vv[16];
            *(uint4*)&vv[0] = *(const uint4*)&vr[0];
            *(uint4*)&vv[8] = *(const uint4*)&vr[8];
#pragma unroll
            for (int i = 0; i < 16; ++i) VT[sd0 + i][skv] = vv[i];
        }
        __syncthreads();
        f4v sc[4] = {};
#pragma unroll
        for (int nt = 0; nt < 4; ++nt) {
            s8v bk0 = *(const s8v*)&Ks[nt * 16 + lr][lq * 8];
            s8v bk1 = *(const s8v*)&Ks[nt * 16 + lr][32 + lq * 8];
            sc[nt] = __builtin_amdgcn_mfma_f32_16x16x32_bf16(aq[0], bk0, sc[nt], 0, 0, 0);
            sc[nt] = __builtin_amdgcn_mfma_f32_16x16x32_bf16(aq[1], bk1, sc[nt], 0, 0, 0);
        }
        float ps[4][4], alpha[4];
#pragma unroll
        for (int j = 0; j < 4; ++j) {
#pragma unroll
            for (int nt = 0; nt < 4; ++nt) ps[nt][j] = sc[nt][j] * 0.125f;
            float pm = fmaxf(fmaxf(ps[0][j], ps[1][j]), fmaxf(ps[2][j], ps[3][j]));
#pragma unroll
            for (int off = 1; off < 16; off <<= 1) pm = fmaxf(pm, __shfl_xor(pm, off));
            float mn = fmaxf(mrow[j], pm);
            alpha[j] = __expf(mrow[j] - mn);
            float rs = 0.f;
#pragma unroll
            for (int nt = 0; nt < 4; ++nt) { ps[nt][j] = __expf(ps[nt][j] - mn); rs += ps[nt][j]; }
#pragma unroll
            for (int off = 1; off < 16; off <<= 1) rs += __shfl_xor(rs, off);
            lrow[j] = lrow[j] * alpha[j] + rs;
            mrow[j] = mn;
        }
#pragma unroll
        for (int nt = 0; nt < 4; ++nt)
#pragma unroll
            for (int j = 0; j < 4; ++j)
                Ps[w][lq * 4 + j][nt * 16 + lr] = (unsigned short)bfr(ps[nt][j]);
#pragma unroll
        for (int ntd = 0; ntd < 4; ++ntd)
#pragma unroll
            for (int j = 0; j < 4; ++j) oacc[ntd][j] *= alpha[j];
        s8v pa0 = *(const s8v*)&Ps[w][lr][lq * 8];
        s8v pa1 = *(const s8v*)&Ps[w][lr][32 + lq * 8];
#pragma unroll
        for (int ntd = 0; ntd < 4; ++ntd) {
            s8v bv0 = *(const s8v*)&VT[ntd * 16 + lr][lq * 8];
            s8v bv1 = *(const s8v*)&VT[ntd * 16 + lr][32 + lq * 8];
            oacc[ntd] = __builtin_amdgcn_mfma_f32_16x16x32_bf16(pa0, bv0, oacc[ntd], 0, 0, 0);
            oacc[ntd] = __builtin_amdgcn_mfma_f32_16x16x32_bf16(pa1, bv1, oacc[ntd], 0, 0, 0);
        }
    }
#pragma unroll
    for (int j = 0; j < 4; ++j) {
        float inv = 1.f / lrow[j];
        int node = b * S_PG + i0 + w * 16 + lq * 4 + j;
#pragma unroll
        for (int ntd = 0; ntd < 4; ++ntd)
            ao[(size_t)node * D + hd + ntd * 16 + lr] = (unsigned short)bfr(oacc[ntd][j] * inv);
    }
}

// ---------------- mean pool per graph ----------------
__global__ __launch_bounds__(256) void k_pool(const float* __restrict__ h, float* __restrict__ g) {
    int b = blockIdx.x, c = threadIdx.x;
    const float* p = h + (size_t)b * S_PG * D + c;
    float s = 0.f;
    for (int r = 0; r < S_PG; ++r) s += p[(size_t)r * D];
    g[b * D + c] = s * (1.f / (float)S_PG);
}

// ---------------- final head ----------------
__global__ __launch_bounds__(256) void k_final(const float* __restrict__ g,
                                               const float* __restrict__ pw1,
                                               const float* __restrict__ pb1,
                                               const float* __restrict__ pw2,
                                               const float* __restrict__ pb2,
                                               float* __restrict__ out) {
    __shared__ float gs[D];
    __shared__ float ts[D];
    __shared__ float red[4];
    int b = blockIdx.x, tid = threadIdx.x;
    gs[tid] = g[b * D + tid];
    __syncthreads();
    float acc = pb1[tid];
    for (int d = 0; d < D; ++d) acc = fmaf(gs[d], pw1[d * D + tid], acc);
    ts[tid] = fmaxf(acc, 0.f);
    __syncthreads();
    float z[3];
#pragma unroll
    for (int rep = 0; rep < 3; ++rep) {
        int j = tid + rep * 256;
        float a = pb2[j];
        for (int d = 0; d < D; ++d) a = fmaf(ts[d], pw2[(size_t)d * OUTD + j], a);
        z[rep] = a;
    }
    float ss = z[0] * z[0] + z[1] * z[1] + z[2] * z[2];
#pragma unroll
    for (int o = 32; o >= 1; o >>= 1) ss += __shfl_xor(ss, o);
    if ((tid & 63) == 0) red[tid >> 6] = ss;
    __syncthreads();
    float rn = rsqrtf(red[0] + red[1] + red[2] + red[3]);
#pragma unroll
    for (int rep = 0; rep < 3; ++rep) out[b * OUTD + tid + rep * 256] = z[rep] * rn;
}

extern "C" void kernel_launch(void* const* d_in, const int* in_sizes, int n_in,
                              void* d_out, int out_size, void* d_ws, size_t ws_size,
                              hipStream_t stream) {
    const int* x        = (const int*)d_in[0];
    const int* ea       = (const int*)d_in[1];
    const int* eidx     = (const int*)d_in[2];
    const float* atom_tab = (const float*)d_in[4];
    const float* bond_tab = (const float*)d_in[5];
    const float* elin_w = (const float*)d_in[6];
    const float* elin_b = (const float*)d_in[7];
    const float* eps    = (const float*)d_in[8];
    const float* gw1    = (const float*)d_in[9];
    const float* gb1    = (const float*)d_in[10];
    const float* gw2    = (const float*)d_in[11];
    const float* gb2    = (const float*)d_in[12];
    const float* aw_in  = (const float*)d_in[13];
    const float* ab_in  = (const float*)d_in[14];
    const float* aw_out = (const float*)d_in[15];
    const float* ab_out = (const float*)d_in[16];
    const float* n1g    = (const float*)d_in[17];
    const float* n1b    = (const float*)d_in[18];
    const float* n2g    = (const float*)d_in[19];
    const float* n2b    = (const float*)d_in[20];
    const float* n3g    = (const float*)d_in[21];
    const float* n3b    = (const float*)d_in[22];
    const float* mw1    = (const float*)d_in[23];
    const float* mb1    = (const float*)d_in[24];
    const float* mw2    = (const float*)d_in[25];
    const float* mb2    = (const float*)d_in[26];
    const float* pw1    = (const float*)d_in[27];
    const float* pb1    = (const float*)d_in[28];
    const float* pw2    = (const float*)d_in[29];
    const float* pb2    = (const float*)d_in[30];

    // ---- workspace layout (~113 MiB of 256 MiB) ----
    char* ws = (char*)d_ws;
    size_t off = 0;
    auto alloc = [&](size_t bytes) {
        void* p = ws + off;
        off += (bytes + 255) & ~(size_t)255;
        return p;
    };
    float*  h    = (float*)alloc((size_t)N_NODES * D * 4);          // layer state f32
    float*  bufB = (float*)alloc((size_t)N_NODES * D * 4);          // combined out f32
    float*  tmp1 = (float*)alloc((size_t)N_NODES * D * 4);          // pre-bn1 f32
    unsigned short* hb = (unsigned short*)alloc((size_t)N_NODES * D * 2);  // bf16 h
    char*   U    = (char*)alloc((size_t)N_NODES * D3 * 2);          // qkv bf16 / tmp2 / tmp3 f32
    unsigned short* bfA = (unsigned short*)alloc((size_t)N_NODES * D3 * 2); // aggb/ao/bufBb @0, hid @ N*D
    unsigned short* WT  = (unsigned short*)alloc((size_t)NL * WT_PER_LAYER * 2);
    float*  bw   = (float*)alloc((size_t)NL * 66 * D * 4);
    unsigned short* ctb = (unsigned short*)alloc((size_t)NL * NCOMBO * D * 2);
    int*    deg  = (int*)alloc((size_t)N_NODES * 4);
    int*    row_ptr = (int*)alloc((size_t)(N_NODES + 1) * 4);
    int*    cursor  = (int*)alloc((size_t)N_NODES * 4);
    int2*   sorted  = (int2*)alloc((size_t)NE * 8);
    float*  statacc = (float*)alloc((size_t)3 * 512 * 4);           // 3 slots [sum|sum2]
    float*  msbuf   = (float*)alloc((size_t)3 * 2 * D * 4);         // 3 x (mean|rstd)
    float*  g    = (float*)alloc((size_t)NB * D * 4);
    (void)ws_size; (void)in_sizes; (void)n_in; (void)out_size;

    float* tmp23 = (float*)U;                     // [N,256] f32 (pre-bn2 then pre-bn3)
    unsigned short* qkv = (unsigned short*)U;     // [N,768] bf16
    unsigned short* aggb  = bfA;                  // agg -> gw1
    unsigned short* ao    = bfA;                  // flash -> aw_out
    unsigned short* bufBb = bfA;                  // bn12 -> mw1
    unsigned short* hid   = bfA + (size_t)N_NODES * D;  // [N,512] bf16
    float* ms1 = msbuf, *ms2 = msbuf + 2 * D, *ms3 = msbuf + 4 * D;

    const int* srcp = eidx;
    const int* dstp = eidx + NE;
    const int EW = N_NODES * D / 1024;

    // one-time per launch
    k_zero16k<<<N_NODES / 256, 256, 0, stream>>>(deg);
    k_zero_stats<<<1, 256, 0, stream>>>(statacc);
    k_hist<<<NE / 256, 256, 0, stream>>>(dstp, deg);
    k_scan<<<1, 256, 0, stream>>>(deg, row_ptr, cursor);
    k_scatter<<<NE / 256, 256, 0, stream>>>(srcp, dstp, ea, cursor, sorted);
    k_atom_enc<<<N_NODES / 4, 256, 0, stream>>>(x, atom_tab, h, hb);
    k_bondw<<<NL * 66, 256, 0, stream>>>(bond_tab, elin_w, bw);
    k_combo<<<NL * NCOMBO, 256, 0, stream>>>(bw, elin_b, ctb);
    k_wcvt<<<NL * 768, 256, 0, stream>>>(gw1, gw2, aw_in, aw_out, mw1, mw2, WT);

    for (int l = 0; l < NL; ++l) {
        const unsigned short* WTl = WT + (size_t)l * WT_PER_LAYER;
        // --- GINE local branch ---
        k_gine_agg<<<N_NODES / 4, 256, 0, stream>>>(hb, h, ctb + (size_t)l * NCOMBO * D, eps, l,
                                                    row_ptr, sorted, aggb);
        k_mm2<1, 0, 1, 0><<<dim3(D2 / 128, N_NODES / 128), 256, 0, stream>>>(
            aggb, WTl + 0, gb1 + (size_t)l * D2, nullptr, hid, nullptr, N_NODES, D2, D);
        k_mm2<0, 1, 0, 1><<<dim3(D / 128, N_NODES / 128), 256, 0, stream>>>(
            hid, WTl + 131072, gb2 + (size_t)l * D, h, tmp1, statacc, N_NODES, D, D2);
        k_bn_finish<<<1, 256, 0, stream>>>(statacc, ms1);
        // --- global attention ---
        k_mm2<0, 0, 1, 0><<<dim3(D3 / 128, N_NODES / 128), 256, 0, stream>>>(
            hb, WTl + 262144, ab_in + (size_t)l * D3, nullptr, qkv, nullptr, N_NODES, D3, D);
        k_flash_mfma<<<dim3(NB * NH, S_PG / 64), 256, 0, stream>>>(qkv, ao);
        k_mm2<0, 1, 0, 1><<<dim3(D / 128, N_NODES / 128), 256, 0, stream>>>(
            ao, WTl + 458752, ab_out + (size_t)l * D, h, tmp23, statacc + 512, N_NODES, D, D);
        k_bn_finish<<<1, 256, 0, stream>>>(statacc + 512, ms2);
        // --- combine (fused bn1+bn2) + MLP ---
        k_bn12<<<EW, 256, 0, stream>>>(tmp1, ms1, n1g + l * D, n1b + l * D,
                                       tmp23, ms2, n2g + l * D, n2b + l * D, bufB, bufBb);
        k_mm2<1, 0, 1, 0><<<dim3(D2 / 128, N_NODES / 128), 256, 0, stream>>>(
            bufBb, WTl + 524288, mb1 + (size_t)l * D2, nullptr, hid, nullptr, N_NODES, D2, D);
        k_mm2<0, 1, 0, 1><<<dim3(D / 128, N_NODES / 128), 256, 0, stream>>>(
            hid, WTl + 655360, mb2 + (size_t)l * D, bufB, tmp23, statacc + 1024, N_NODES, D, D2);
        k_bn_finish<<<1, 256, 0, stream>>>(statacc + 1024, ms3);
        k_bn_apply<<<EW, 256, 0, stream>>>(tmp23, ms3, n3g + l * D, n3b + l * D, h, hb);
    }
    k_pool<<<NB, 256, 0, stream>>>(h, g);
    k_final<<<NB, 256, 0, stream>>>(g, pw1, pb1, pw2, pb2, (float*)d_out);
}

// Round 8
// 942.904 us; speedup vs baseline: 6.5751x; 1.0697x over previous
//
#include <hip/hip_runtime.h>
#include <hip/hip_bf16.h>
#include <math.h>

#define N_NODES 16384
#define NB      32
#define S_PG    512
#define NE      262144
#define EPG     8192
#define D       256
#define D2      512
#define D3      768
#define NL      4
#define NH      4
#define DHD     64
#define OUTD    768
#define NCOMBO  264
#define WT_PER_LAYER 786432

typedef short s8v __attribute__((ext_vector_type(8)));
typedef float f4v __attribute__((ext_vector_type(4)));

__device__ __forceinline__ unsigned bfr(float f) {   // fp32 -> bf16 bits, RNE
    unsigned u = __float_as_uint(f);
    return (u + 0x7fffu + ((u >> 16) & 1u)) >> 16;
}
__device__ __forceinline__ float b2f(unsigned short u) {
    return __uint_as_float(((unsigned)u) << 16);
}

// ---------------- Atom encoder: h (f32) + hb (bf16) ----------------
__global__ __launch_bounds__(256) void k_atom_enc(const int* __restrict__ x,
                                                  const float* __restrict__ tab,
                                                  float* __restrict__ h,
                                                  unsigned short* __restrict__ hb) {
    int node = blockIdx.x * 4 + (threadIdx.x >> 6);
    int lane = threadIdx.x & 63;
    int dd = lane << 2;
    float4 acc = {0.f, 0.f, 0.f, 0.f};
#pragma unroll
    for (int f = 0; f < 9; ++f) {
        int v = x[node * 9 + f];
        const float4 t = *(const float4*)&tab[((size_t)(f * 119 + v)) * D + dd];
        acc.x += t.x; acc.y += t.y; acc.z += t.z; acc.w += t.w;
    }
    *(float4*)&h[(size_t)node * D + dd] = acc;
    ushort4 o;
    o.x = (unsigned short)bfr(acc.x); o.y = (unsigned short)bfr(acc.y);
    o.z = (unsigned short)bfr(acc.z); o.w = (unsigned short)bfr(acc.w);
    *(ushort4*)&hb[(size_t)node * D + dd] = o;
}

// ---------------- bw[l,fv,:] = bond_tab[fv,:] @ elin_w[l] ----------------
__global__ __launch_bounds__(256) void k_bondw(const float* __restrict__ bond_tab,
                                               const float* __restrict__ elin_w,
                                               float* __restrict__ bw) {
    int blk = blockIdx.x;         // L*66
    int l = blk / 66, fv = blk % 66;
    int dout = threadIdx.x;
    const float* tabrow = bond_tab + (size_t)fv * D;
    const float* w = elin_w + (size_t)l * D * D;
    float acc = 0.f;
    for (int d = 0; d < D; ++d) acc = fmaf(tabrow[d], w[d * D + dout], acc);
    bw[((size_t)l * 66 + fv) * D + dout] = acc;
}

// ---------------- combo table (bf16) ----------------
__global__ __launch_bounds__(256) void k_combo(const float* __restrict__ bw,
                                               const float* __restrict__ elin_b,
                                               unsigned short* __restrict__ ctb) {
    int b = blockIdx.x;           // NL*264
    int l = b / NCOMBO, cid = b % NCOMBO;
    int a0 = cid / 12, a1 = (cid % 12) / 2, a2 = cid & 1;
    int d = threadIdx.x;
    const float* bwl = bw + (size_t)l * 66 * D;
    float v = bwl[(size_t)a0 * D + d] + bwl[(size_t)(22 + a1) * D + d] +
              bwl[(size_t)(44 + a2) * D + d] + elin_b[(size_t)l * D + d];
    ctb[((size_t)l * NCOMBO + cid) * D + d] = (unsigned short)bfr(v);
}

// ---------------- CSR build ----------------
__global__ __launch_bounds__(256) void k_zero16k(int* __restrict__ p) {
    p[blockIdx.x * 256 + threadIdx.x] = 0;
}
__global__ __launch_bounds__(256) void k_zero_stats(float* __restrict__ p) {
    for (int i = 0; i < 6; ++i) p[i * 256 + threadIdx.x] = 0.f;
}
__global__ __launch_bounds__(256) void k_hist(const int* __restrict__ dst, int* __restrict__ deg) {
    int e = blockIdx.x * 256 + threadIdx.x;
    atomicAdd(&deg[dst[e]], 1);
}
__global__ __launch_bounds__(256) void k_scan(const int* __restrict__ deg,
                                              int* __restrict__ row_ptr,
                                              int* __restrict__ cursor) {
    __shared__ int partial[256];
    int t = threadIdx.x;
    int base = t * 64;
    int s = 0;
    for (int i = 0; i < 64; ++i) s += deg[base + i];
    partial[t] = s;
    __syncthreads();
    for (int dstp = 1; dstp < 256; dstp <<= 1) {
        int v = (t >= dstp) ? partial[t - dstp] : 0;
        __syncthreads();
        partial[t] += v;
        __syncthreads();
    }
    int run = partial[t] - s;
    for (int i = 0; i < 64; ++i) {
        int dcur = deg[base + i];
        row_ptr[base + i] = run;
        cursor[base + i] = run;
        run += dcur;
    }
    if (t == 255) row_ptr[N_NODES] = run;
}
__global__ __launch_bounds__(256) void k_scatter(const int* __restrict__ src,
                                                 const int* __restrict__ dst,
                                                 const int* __restrict__ ea,
                                                 int* __restrict__ cursor,
                                                 int2* __restrict__ sorted) {
    int e = blockIdx.x * 256 + threadIdx.x;
    int d = dst[e];
    int pos = atomicAdd(&cursor[d], 1);
    int cid = ea[e * 3] * 12 + ea[e * 3 + 1] * 2 + ea[e * 3 + 2];
    sorted[pos] = make_int2(src[e], cid);
}

// ---------------- GINE aggregation (bf16 gather) ----------------
__global__ __launch_bounds__(256) void k_gine_agg(const unsigned short* __restrict__ hb,
                                                  const float* __restrict__ h,
                                                  const unsigned short* __restrict__ ctb,
                                                  const float* __restrict__ eps, int l,
                                                  const int* __restrict__ row_ptr,
                                                  const int2* __restrict__ sorted,
                                                  unsigned short* __restrict__ aggb) {
    int w = threadIdx.x >> 6;
    int lane = threadIdx.x & 63;
    int n = blockIdx.x * 4 + w;
    int dd = lane << 2;
    int beg = row_ptr[n], end = row_ptr[n + 1];
    float4 acc = {0.f, 0.f, 0.f, 0.f};
    int i = beg;
    for (; i + 2 <= end; i += 2) {
        int2 e0 = sorted[i];
        int2 e1 = sorted[i + 1];
        ushort4 h0 = *(const ushort4*)&hb[(size_t)e0.x * D + dd];
        ushort4 c0 = *(const ushort4*)&ctb[(size_t)e0.y * D + dd];
        ushort4 h1 = *(const ushort4*)&hb[(size_t)e1.x * D + dd];
        ushort4 c1 = *(const ushort4*)&ctb[(size_t)e1.y * D + dd];
        acc.x += fmaxf(b2f(h0.x) + b2f(c0.x), 0.f) + fmaxf(b2f(h1.x) + b2f(c1.x), 0.f);
        acc.y += fmaxf(b2f(h0.y) + b2f(c0.y), 0.f) + fmaxf(b2f(h1.y) + b2f(c1.y), 0.f);
        acc.z += fmaxf(b2f(h0.z) + b2f(c0.z), 0.f) + fmaxf(b2f(h1.z) + b2f(c1.z), 0.f);
        acc.w += fmaxf(b2f(h0.w) + b2f(c0.w), 0.f) + fmaxf(b2f(h1.w) + b2f(c1.w), 0.f);
    }
    if (i < end) {
        int2 e0 = sorted[i];
        ushort4 h0 = *(const ushort4*)&hb[(size_t)e0.x * D + dd];
        ushort4 c0 = *(const ushort4*)&ctb[(size_t)e0.y * D + dd];
        acc.x += fmaxf(b2f(h0.x) + b2f(c0.x), 0.f);
        acc.y += fmaxf(b2f(h0.y) + b2f(c0.y), 0.f);
        acc.z += fmaxf(b2f(h0.z) + b2f(c0.z), 0.f);
        acc.w += fmaxf(b2f(h0.w) + b2f(c0.w), 0.f);
    }
    float s1p = 1.f + eps[l];
    float4 hn = *(const float4*)&h[(size_t)n * D + dd];
    ushort4 o;
    o.x = (unsigned short)bfr(s1p * hn.x + acc.x);
    o.y = (unsigned short)bfr(s1p * hn.y + acc.y);
    o.z = (unsigned short)bfr(s1p * hn.z + acc.z);
    o.w = (unsigned short)bfr(s1p * hn.w + acc.w);
    *(ushort4*)&aggb[(size_t)n * D + dd] = o;
}

// ---------------- weight transpose+convert ----------------
__global__ __launch_bounds__(256) void k_wcvt(const float* __restrict__ gw1, const float* __restrict__ gw2,
                                              const float* __restrict__ aw_in, const float* __restrict__ aw_out,
                                              const float* __restrict__ mw1, const float* __restrict__ mw2,
                                              unsigned short* __restrict__ WT) {
    const int KS[6]   = {256, 512, 256, 256, 256, 512};
    const int NS[6]   = {512, 256, 768, 256, 512, 256};
    const int TOFF[7] = {0, 128, 256, 448, 512, 640, 768};
    const int DOFF[6] = {0, 131072, 262144, 458752, 524288, 655360};
    int b = blockIdx.x;
    int l = b / 768, wb = b % 768;
    int widx = 0;
    while (wb >= TOFF[widx + 1]) ++widx;
    int t = wb - TOFF[widx];
    int K = KS[widx], N = NS[widx];
    int nn = N / 32;
    int kt = t / nn, nt = t % nn;
    const float* srcs[6] = {gw1, gw2, aw_in, aw_out, mw1, mw2};
    const float* W = srcs[widx] + (size_t)l * K * N;
    unsigned short* WTp = WT + (size_t)l * WT_PER_LAYER + DOFF[widx];
    __shared__ float tile[32][33];
    int tid = threadIdx.x;
    int r = tid >> 3, c4 = (tid & 7) << 2;
    float4 v = *(const float4*)&W[(size_t)(kt * 32 + r) * N + nt * 32 + c4];
    tile[r][c4] = v.x; tile[r][c4 + 1] = v.y; tile[r][c4 + 2] = v.z; tile[r][c4 + 3] = v.w;
    __syncthreads();
    int nr = tid >> 3, kc = (tid & 7) << 2;
    ushort4 o;
    o.x = (unsigned short)bfr(tile[kc + 0][nr]);
    o.y = (unsigned short)bfr(tile[kc + 1][nr]);
    o.z = (unsigned short)bfr(tile[kc + 2][nr]);
    o.w = (unsigned short)bfr(tile[kc + 3][nr]);
    *(ushort4*)&WTp[(size_t)(nt * 32 + nr) * K + kt * 32 + kc] = o;
}

// ---------------- BM=128 bf16 MFMA GEMM (single) ----------------
template<int RELU, int RES, int OBF, int STAT>
__global__ __launch_bounds__(256) void k_mm2(const unsigned short* __restrict__ A,
                                             const unsigned short* __restrict__ BT,
                                             const float* __restrict__ bias,
                                             const float* __restrict__ res,
                                             void* __restrict__ Cp,
                                             float* __restrict__ stat,
                                             int M, int N, int K) {
    __shared__ unsigned short As[128 * 64];
    __shared__ unsigned short Bs[128 * 64];
    const int tid = threadIdx.x;
    const int row0 = blockIdx.y * 128, col0 = blockIdx.x * 128;
    const int w = tid >> 6, l = tid & 63;
    const int wm = w >> 1, wn = w & 1;
    const int lr = l & 15, lq = l >> 4;
    const int srow = l >> 3;
    const int scol = (l & 7) * 8;
    f4v acc[4][4] = {};

    const unsigned short* Ag = A + (size_t)(row0 + w * 32 + srow) * K + scol;
    const unsigned short* Bg = BT + (size_t)(col0 + w * 32 + srow) * K + scol;
    unsigned short* Al = &As[(w * 32) * 64];
    unsigned short* Bl = &Bs[(w * 32) * 64];

    for (int k0 = 0; k0 < K; k0 += 64) {
#pragma unroll
        for (int it = 0; it < 4; ++it) {
            __builtin_amdgcn_global_load_lds(
                (const __attribute__((address_space(1))) unsigned*)(Ag + (size_t)(it * 8) * K + k0),
                (__attribute__((address_space(3))) unsigned*)(Al + it * 8 * 64), 16, 0, 0);
            __builtin_amdgcn_global_load_lds(
                (const __attribute__((address_space(1))) unsigned*)(Bg + (size_t)(it * 8) * K + k0),
                (__attribute__((address_space(3))) unsigned*)(Bl + it * 8 * 64), 16, 0, 0);
        }
        asm volatile("s_waitcnt vmcnt(0)" ::: "memory");
        __syncthreads();
#pragma unroll
        for (int kk = 0; kk < 2; ++kk) {
            s8v af[4], bf[4];
#pragma unroll
            for (int m = 0; m < 4; ++m)
                af[m] = *(const s8v*)&As[(wm * 64 + m * 16 + lr) * 64 + kk * 32 + lq * 8];
#pragma unroll
            for (int n = 0; n < 4; ++n)
                bf[n] = *(const s8v*)&Bs[(wn * 64 + n * 16 + lr) * 64 + kk * 32 + lq * 8];
#pragma unroll
            for (int m = 0; m < 4; ++m)
#pragma unroll
                for (int n = 0; n < 4; ++n)
                    acc[m][n] = __builtin_amdgcn_mfma_f32_16x16x32_bf16(af[m], bf[n], acc[m][n], 0, 0, 0);
        }
        __syncthreads();
    }
    float cs[4], cs2[4];
#pragma unroll
    for (int n = 0; n < 4; ++n) { cs[n] = 0.f; cs2[n] = 0.f; }
#pragma unroll
    for (int n = 0; n < 4; ++n) {
        int c = col0 + wn * 64 + n * 16 + lr;
        float bv = bias[c];
#pragma unroll
        for (int m = 0; m < 4; ++m) {
#pragma unroll
            for (int j = 0; j < 4; ++j) {
                int r = row0 + wm * 64 + m * 16 + lq * 4 + j;
                float v = acc[m][n][j] + bv;
                if (RES) v += res[(size_t)r * N + c];
                if (STAT) { cs[n] += v; cs2[n] += v * v; }
                if (RELU) v = fmaxf(v, 0.f);
                if (OBF) ((unsigned short*)Cp)[(size_t)r * N + c] = (unsigned short)bfr(v);
                else ((float*)Cp)[(size_t)r * N + c] = v;
            }
        }
    }
    if (STAT) {
#pragma unroll
        for (int n = 0; n < 4; ++n) {
            float s = cs[n], s2 = cs2[n];
            s += __shfl_xor(s, 16);  s2 += __shfl_xor(s2, 16);
            s += __shfl_xor(s, 32);  s2 += __shfl_xor(s2, 32);
            if (lq == 0) {
                int c = col0 + wn * 64 + n * 16 + lr;
                atomicAdd(&stat[c], s);
                atomicAdd(&stat[256 + c], s2);
            }
        }
    }
}

// ---------------- dual GEMM dispatch: blocks [0,nb1) -> problem1, rest -> problem2 ----------------
// Both: K shared, OBF=1, no res/stat. relu: problem1=1, problem2=0.
__global__ __launch_bounds__(256) void k_mm2_dual(const unsigned short* __restrict__ A1,
                                                  const unsigned short* __restrict__ B1,
                                                  const float* __restrict__ bias1,
                                                  unsigned short* __restrict__ C1, int N1, int nb1,
                                                  const unsigned short* __restrict__ A2,
                                                  const unsigned short* __restrict__ B2,
                                                  const float* __restrict__ bias2,
                                                  unsigned short* __restrict__ C2, int N2,
                                                  int K) {
    __shared__ unsigned short As[128 * 64];
    __shared__ unsigned short Bs[128 * 64];
    const unsigned short* A; const unsigned short* BT; const float* bias;
    unsigned short* C; int N, cb, relu;
    if ((int)blockIdx.x < nb1) { A = A1; BT = B1; bias = bias1; C = C1; N = N1; cb = blockIdx.x; relu = 1; }
    else { A = A2; BT = B2; bias = bias2; C = C2; N = N2; cb = blockIdx.x - nb1; relu = 0; }
    const int tid = threadIdx.x;
    const int row0 = blockIdx.y * 128, col0 = cb * 128;
    const int w = tid >> 6, l = tid & 63;
    const int wm = w >> 1, wn = w & 1;
    const int lr = l & 15, lq = l >> 4;
    const int srow = l >> 3;
    const int scol = (l & 7) * 8;
    f4v acc[4][4] = {};

    const unsigned short* Ag = A + (size_t)(row0 + w * 32 + srow) * K + scol;
    const unsigned short* Bg = BT + (size_t)(col0 + w * 32 + srow) * K + scol;
    unsigned short* Al = &As[(w * 32) * 64];
    unsigned short* Bl = &Bs[(w * 32) * 64];

    for (int k0 = 0; k0 < K; k0 += 64) {
#pragma unroll
        for (int it = 0; it < 4; ++it) {
            __builtin_amdgcn_global_load_lds(
                (const __attribute__((address_space(1))) unsigned*)(Ag + (size_t)(it * 8) * K + k0),
                (__attribute__((address_space(3))) unsigned*)(Al + it * 8 * 64), 16, 0, 0);
            __builtin_amdgcn_global_load_lds(
                (const __attribute__((address_space(1))) unsigned*)(Bg + (size_t)(it * 8) * K + k0),
                (__attribute__((address_space(3))) unsigned*)(Bl + it * 8 * 64), 16, 0, 0);
        }
        asm volatile("s_waitcnt vmcnt(0)" ::: "memory");
        __syncthreads();
#pragma unroll
        for (int kk = 0; kk < 2; ++kk) {
            s8v af[4], bf[4];
#pragma unroll
            for (int m = 0; m < 4; ++m)
                af[m] = *(const s8v*)&As[(wm * 64 + m * 16 + lr) * 64 + kk * 32 + lq * 8];
#pragma unroll
            for (int n = 0; n < 4; ++n)
                bf[n] = *(const s8v*)&Bs[(wn * 64 + n * 16 + lr) * 64 + kk * 32 + lq * 8];
#pragma unroll
            for (int m = 0; m < 4; ++m)
#pragma unroll
                for (int n = 0; n < 4; ++n)
                    acc[m][n] = __builtin_amdgcn_mfma_f32_16x16x32_bf16(af[m], bf[n], acc[m][n], 0, 0, 0);
        }
        __syncthreads();
    }
#pragma unroll
    for (int n = 0; n < 4; ++n) {
        int c = col0 + wn * 64 + n * 16 + lr;
        float bv = bias[c];
#pragma unroll
        for (int m = 0; m < 4; ++m) {
#pragma unroll
            for (int j = 0; j < 4; ++j) {
                int r = row0 + wm * 64 + m * 16 + lq * 4 + j;
                float v = acc[m][n][j] + bv;
                if (relu) v = fmaxf(v, 0.f);
                C[(size_t)r * N + c] = (unsigned short)bfr(v);
            }
        }
    }
}

// ---------------- BM=64 bf16 MFMA GEMM (for N=256 shapes; grid (N/128, M/64)) ----------------
template<int RELU, int RES, int OBF, int STAT>
__global__ __launch_bounds__(256) void k_mm64(const unsigned short* __restrict__ A,
                                              const unsigned short* __restrict__ BT,
                                              const float* __restrict__ bias,
                                              const float* __restrict__ res,
                                              void* __restrict__ Cp,
                                              float* __restrict__ stat,
                                              int M, int N, int K) {
    __shared__ unsigned short As[64 * 64];
    __shared__ unsigned short Bs[128 * 64];
    const int tid = threadIdx.x;
    const int row0 = blockIdx.y * 64, col0 = blockIdx.x * 128;
    const int w = tid >> 6, l = tid & 63;
    const int wn = w;                     // 4 col strips of 32
    const int lr = l & 15, lq = l >> 4;
    const int srow = l >> 3;
    const int scol = (l & 7) * 8;
    f4v acc[4][2] = {};

    const unsigned short* Ag = A + (size_t)(row0 + w * 16 + srow) * K + scol;
    const unsigned short* Bg = BT + (size_t)(col0 + w * 32 + srow) * K + scol;
    unsigned short* Al = &As[(w * 16) * 64];
    unsigned short* Bl = &Bs[(w * 32) * 64];

    for (int k0 = 0; k0 < K; k0 += 64) {
#pragma unroll
        for (int it = 0; it < 2; ++it)
            __builtin_amdgcn_global_load_lds(
                (const __attribute__((address_space(1))) unsigned*)(Ag + (size_t)(it * 8) * K + k0),
                (__attribute__((address_space(3))) unsigned*)(Al + it * 8 * 64), 16, 0, 0);
#pragma unroll
        for (int it = 0; it < 4; ++it)
            __builtin_amdgcn_global_load_lds(
                (const __attribute__((address_space(1))) unsigned*)(Bg + (size_t)(it * 8) * K + k0),
                (__attribute__((address_space(3))) unsigned*)(Bl + it * 8 * 64), 16, 0, 0);
        asm volatile("s_waitcnt vmcnt(0)" ::: "memory");
        __syncthreads();
#pragma unroll
        for (int kk = 0; kk < 2; ++kk) {
            s8v af[4], bf[2];
#pragma unroll
            for (int m = 0; m < 4; ++m)
                af[m] = *(const s8v*)&As[(m * 16 + lr) * 64 + kk * 32 + lq * 8];
#pragma unroll
            for (int n = 0; n < 2; ++n)
                bf[n] = *(const s8v*)&Bs[(wn * 32 + n * 16 + lr) * 64 + kk * 32 + lq * 8];
#pragma unroll
            for (int m = 0; m < 4; ++m)
#pragma unroll
                for (int n = 0; n < 2; ++n)
                    acc[m][n] = __builtin_amdgcn_mfma_f32_16x16x32_bf16(af[m], bf[n], acc[m][n], 0, 0, 0);
        }
        __syncthreads();
    }
    float cs[2], cs2[2];
#pragma unroll
    for (int n = 0; n < 2; ++n) { cs[n] = 0.f; cs2[n] = 0.f; }
#pragma unroll
    for (int n = 0; n < 2; ++n) {
        int c = col0 + wn * 32 + n * 16 + lr;
        float bv = bias[c];
#pragma unroll
        for (int m = 0; m < 4; ++m) {
#pragma unroll
            for (int j = 0; j < 4; ++j) {
                int r = row0 + m * 16 + lq * 4 + j;
                float v = acc[m][n][j] + bv;
                if (RES) v += res[(size_t)r * N + c];
                if (STAT) { cs[n] += v; cs2[n] += v * v; }
                if (RELU) v = fmaxf(v, 0.f);
                if (OBF) ((unsigned short*)Cp)[(size_t)r * N + c] = (unsigned short)bfr(v);
                else ((float*)Cp)[(size_t)r * N + c] = v;
            }
        }
    }
    if (STAT) {
#pragma unroll
        for (int n = 0; n < 2; ++n) {
            float s = cs[n], s2 = cs2[n];
            s += __shfl_xor(s, 16);  s2 += __shfl_xor(s2, 16);
            s += __shfl_xor(s, 32);  s2 += __shfl_xor(s2, 32);
            if (lq == 0) {
                int c = col0 + wn * 32 + n * 16 + lr;
                atomicAdd(&stat[c], s);
                atomicAdd(&stat[256 + c], s2);
            }
        }
    }
}

// ---------------- BN finish ----------------
__global__ __launch_bounds__(256) void k_bn_finish(float* __restrict__ acc,
                                                   float* __restrict__ ms) {
    int c = threadIdx.x;
    float s = acc[c], s2 = acc[256 + c];
    float mean = s / (float)N_NODES;
    float var = s2 / (float)N_NODES - mean * mean;
    ms[c] = mean;
    ms[D + c] = rsqrtf(var + 1e-5f);
    acc[c] = 0.f;
    acc[256 + c] = 0.f;
}
// two slots in one launch: block s handles acc+ s*512 -> ms + s*2D
__global__ __launch_bounds__(256) void k_bn_finish2(float* __restrict__ acc,
                                                    float* __restrict__ ms) {
    int s0 = blockIdx.x;
    float* a = acc + (size_t)s0 * 512;
    float* m = ms + (size_t)s0 * 2 * D;
    int c = threadIdx.x;
    float s = a[c], s2 = a[256 + c];
    float mean = s / (float)N_NODES;
    float var = s2 / (float)N_NODES - mean * mean;
    m[c] = mean;
    m[D + c] = rsqrtf(var + 1e-5f);
    a[c] = 0.f;
    a[256 + c] = 0.f;
}

// ---------------- fused: y = bn1(t1) + bn2(t2), dual write ----------------
__global__ __launch_bounds__(256) void k_bn12(const float* __restrict__ t1,
                                              const float* __restrict__ ms1,
                                              const float* __restrict__ g1,
                                              const float* __restrict__ b1,
                                              const float* __restrict__ t2,
                                              const float* __restrict__ ms2,
                                              const float* __restrict__ g2,
                                              const float* __restrict__ b2,
                                              float* __restrict__ y,
                                              unsigned short* __restrict__ yb) {
    size_t i4 = (size_t)blockIdx.x * blockDim.x + threadIdx.x;
    int c = (int)((i4 & 63) << 2);
    float4 v1 = ((const float4*)t1)[i4];
    float4 v2 = ((const float4*)t2)[i4];
    float4 v;
    v.x = (v1.x - ms1[c + 0]) * ms1[D + c + 0] * g1[c + 0] + b1[c + 0]
        + (v2.x - ms2[c + 0]) * ms2[D + c + 0] * g2[c + 0] + b2[c + 0];
    v.y = (v1.y - ms1[c + 1]) * ms1[D + c + 1] * g1[c + 1] + b1[c + 1]
        + (v2.y - ms2[c + 1]) * ms2[D + c + 1] * g2[c + 1] + b2[c + 1];
    v.z = (v1.z - ms1[c + 2]) * ms1[D + c + 2] * g1[c + 2] + b1[c + 2]
        + (v2.z - ms2[c + 2]) * ms2[D + c + 2] * g2[c + 2] + b2[c + 2];
    v.w = (v1.w - ms1[c + 3]) * ms1[D + c + 3] * g1[c + 3] + b1[c + 3]
        + (v2.w - ms2[c + 3]) * ms2[D + c + 3] * g2[c + 3] + b2[c + 3];
    ((float4*)y)[i4] = v;
    ushort4 o;
    o.x = (unsigned short)bfr(v.x); o.y = (unsigned short)bfr(v.y);
    o.z = (unsigned short)bfr(v.z); o.w = (unsigned short)bfr(v.w);
    ((ushort4*)yb)[i4] = o;
}

// ---------------- bn apply (single), dual write ----------------
__global__ __launch_bounds__(256) void k_bn_apply(const float* __restrict__ x,
                                                  const float* __restrict__ ms,
                                                  const float* __restrict__ g,
                                                  const float* __restrict__ b,
                                                  float* __restrict__ y,
                                                  unsigned short* __restrict__ yb) {
    size_t i4 = (size_t)blockIdx.x * blockDim.x + threadIdx.x;
    int c = (int)((i4 & 63) << 2);
    float4 v = ((const float4*)x)[i4];
    v.x = (v.x - ms[c + 0]) * ms[D + c + 0] * g[c + 0] + b[c + 0];
    v.y = (v.y - ms[c + 1]) * ms[D + c + 1] * g[c + 1] + b[c + 1];
    v.z = (v.z - ms[c + 2]) * ms[D + c + 2] * g[c + 2] + b[c + 2];
    v.w = (v.w - ms[c + 3]) * ms[D + c + 3] * g[c + 3] + b[c + 3];
    ((float4*)y)[i4] = v;
    ushort4 o;
    o.x = (unsigned short)bfr(v.x); o.y = (unsigned short)bfr(v.y);
    o.z = (unsigned short)bfr(v.z); o.w = (unsigned short)bfr(v.w);
    ((ushort4*)yb)[i4] = o;
}

// ---------------- MFMA flash attention ----------------
__global__ __launch_bounds__(256) void k_flash_mfma(const unsigned short* __restrict__ qkv,
                                                    unsigned short* __restrict__ ao) {
    __shared__ unsigned short Ks[64][72];
    __shared__ unsigned short VT[64][72];
    __shared__ unsigned short Ps[4][16][72];
    const int bh = blockIdx.x;
    const int b = bh >> 2, hh = bh & 3;
    const int i0 = blockIdx.y << 6;
    const int tid = threadIdx.x;
    const int w = tid >> 6, l = tid & 63;
    const int lr = l & 15, lq = l >> 4;
    const int hd = hh * DHD;
    const size_t rowbase = (size_t)(b * S_PG) * D3;

    s8v aq[2];
    {
        const unsigned short* qrow = &qkv[rowbase + (size_t)(i0 + w * 16 + lr) * D3 + hd + lq * 8];
        aq[0] = *(const s8v*)&qrow[0];
        aq[1] = *(const s8v*)&qrow[32];
    }

    float mrow[4] = {-INFINITY, -INFINITY, -INFINITY, -INFINITY};
    float lrow[4] = {0.f, 0.f, 0.f, 0.f};
    f4v oacc[4] = {};

    const int skv = tid >> 2;                  // K staging: kv row 0..63
    const int sd0 = (tid & 3) << 4;            // K staging: d segment
    const int d0v = (tid >> 4) << 2;           // V staging: d block 0..60
    const int kv0 = (tid & 15) << 2;           // V staging: kv block 0..60

    for (int j0 = 0; j0 < S_PG; j0 += 64) {
        __syncthreads();
        {
            // K tile row-major (coalesced uint4)
            const unsigned short* kr = &qkv[rowbase + (size_t)(j0 + skv) * D3 + D + hd + sd0];
            *(uint4*)&Ks[skv][sd0]     = *(const uint4*)&kr[0];
            *(uint4*)&Ks[skv][sd0 + 8] = *(const uint4*)&kr[8];
            // V tile: 4x4 register transpose, b64 LDS writes
            unsigned short vv[4][4];
#pragma unroll
            for (int i = 0; i < 4; ++i) {
                uint2 lv = *(const uint2*)&qkv[rowbase + (size_t)(j0 + kv0 + i) * D3 + D2 + hd + d0v];
                vv[i][0] = (unsigned short)(lv.x & 0xffffu);
                vv[i][1] = (unsigned short)(lv.x >> 16);
                vv[i][2] = (unsigned short)(lv.y & 0xffffu);
                vv[i][3] = (unsigned short)(lv.y >> 16);
            }
#pragma unroll
            for (int i2 = 0; i2 < 4; ++i2) {
                ushort4 o4;
                o4.x = vv[0][i2]; o4.y = vv[1][i2]; o4.z = vv[2][i2]; o4.w = vv[3][i2];
                *(ushort4*)&VT[d0v + i2][kv0] = o4;
            }
        }
        __syncthreads();
        f4v sc[4] = {};
#pragma unroll
        for (int nt = 0; nt < 4; ++nt) {
            s8v bk0 = *(const s8v*)&Ks[nt * 16 + lr][lq * 8];
            s8v bk1 = *(const s8v*)&Ks[nt * 16 + lr][32 + lq * 8];
            sc[nt] = __builtin_amdgcn_mfma_f32_16x16x32_bf16(aq[0], bk0, sc[nt], 0, 0, 0);
            sc[nt] = __builtin_amdgcn_mfma_f32_16x16x32_bf16(aq[1], bk1, sc[nt], 0, 0, 0);
        }
        float ps[4][4], alpha[4];
#pragma unroll
        for (int j = 0; j < 4; ++j) {
#pragma unroll
            for (int nt = 0; nt < 4; ++nt) ps[nt][j] = sc[nt][j] * 0.125f;
            float pm = fmaxf(fmaxf(ps[0][j], ps[1][j]), fmaxf(ps[2][j], ps[3][j]));
#pragma unroll
            for (int off = 1; off < 16; off <<= 1) pm = fmaxf(pm, __shfl_xor(pm, off));
            float mn = fmaxf(mrow[j], pm);
            alpha[j] = __expf(mrow[j] - mn);
            float rs = 0.f;
#pragma unroll
            for (int nt = 0; nt < 4; ++nt) { ps[nt][j] = __expf(ps[nt][j] - mn); rs += ps[nt][j]; }
#pragma unroll
            for (int off = 1; off < 16; off <<= 1) rs += __shfl_xor(rs, off);
            lrow[j] = lrow[j] * alpha[j] + rs;
            mrow[j] = mn;
        }
#pragma unroll
        for (int nt = 0; nt < 4; ++nt)
#pragma unroll
            for (int j = 0; j < 4; ++j)
                Ps[w][lq * 4 + j][nt * 16 + lr] = (unsigned short)bfr(ps[nt][j]);
#pragma unroll
        for (int ntd = 0; ntd < 4; ++ntd)
#pragma unroll
            for (int j = 0; j < 4; ++j) oacc[ntd][j] *= alpha[j];
        s8v pa0 = *(const s8v*)&Ps[w][lr][lq * 8];
        s8v pa1 = *(const s8v*)&Ps[w][lr][32 + lq * 8];
#pragma unroll
        for (int ntd = 0; ntd < 4; ++ntd) {
            s8v bv0 = *(const s8v*)&VT[ntd * 16 + lr][lq * 8];
            s8v bv1 = *(const s8v*)&VT[ntd * 16 + lr][32 + lq * 8];
            oacc[ntd] = __builtin_amdgcn_mfma_f32_16x16x32_bf16(pa0, bv0, oacc[ntd], 0, 0, 0);
            oacc[ntd] = __builtin_amdgcn_mfma_f32_16x16x32_bf16(pa1, bv1, oacc[ntd], 0, 0, 0);
        }
    }
#pragma unroll
    for (int j = 0; j < 4; ++j) {
        float inv = 1.f / lrow[j];
        int node = b * S_PG + i0 + w * 16 + lq * 4 + j;
#pragma unroll
        for (int ntd = 0; ntd < 4; ++ntd)
            ao[(size_t)node * D + hd + ntd * 16 + lr] = (unsigned short)bfr(oacc[ntd][j] * inv);
    }
}

// ---------------- mean pool per graph ----------------
__global__ __launch_bounds__(256) void k_pool(const float* __restrict__ h, float* __restrict__ g) {
    int b = blockIdx.x, c = threadIdx.x;
    const float* p = h + (size_t)b * S_PG * D + c;
    float s = 0.f;
    for (int r = 0; r < S_PG; ++r) s += p[(size_t)r * D];
    g[b * D + c] = s * (1.f / (float)S_PG);
}

// ---------------- final head ----------------
__global__ __launch_bounds__(256) void k_final(const float* __restrict__ g,
                                               const float* __restrict__ pw1,
                                               const float* __restrict__ pb1,
                                               const float* __restrict__ pw2,
                                               const float* __restrict__ pb2,
                                               float* __restrict__ out) {
    __shared__ float gs[D];
    __shared__ float ts[D];
    __shared__ float red[4];
    int b = blockIdx.x, tid = threadIdx.x;
    gs[tid] = g[b * D + tid];
    __syncthreads();
    float acc = pb1[tid];
    for (int d = 0; d < D; ++d) acc = fmaf(gs[d], pw1[d * D + tid], acc);
    ts[tid] = fmaxf(acc, 0.f);
    __syncthreads();
    float z[3];
#pragma unroll
    for (int rep = 0; rep < 3; ++rep) {
        int j = tid + rep * 256;
        float a = pb2[j];
        for (int d = 0; d < D; ++d) a = fmaf(ts[d], pw2[(size_t)d * OUTD + j], a);
        z[rep] = a;
    }
    float ss = z[0] * z[0] + z[1] * z[1] + z[2] * z[2];
#pragma unroll
    for (int o = 32; o >= 1; o >>= 1) ss += __shfl_xor(ss, o);
    if ((tid & 63) == 0) red[tid >> 6] = ss;
    __syncthreads();
    float rn = rsqrtf(red[0] + red[1] + red[2] + red[3]);
#pragma unroll
    for (int rep = 0; rep < 3; ++rep) out[b * OUTD + tid + rep * 256] = z[rep] * rn;
}

extern "C" void kernel_launch(void* const* d_in, const int* in_sizes, int n_in,
                              void* d_out, int out_size, void* d_ws, size_t ws_size,
                              hipStream_t stream) {
    const int* x        = (const int*)d_in[0];
    const int* ea       = (const int*)d_in[1];
    const int* eidx     = (const int*)d_in[2];
    const float* atom_tab = (const float*)d_in[4];
    const float* bond_tab = (const float*)d_in[5];
    const float* elin_w = (const float*)d_in[6];
    const float* elin_b = (const float*)d_in[7];
    const float* eps    = (const float*)d_in[8];
    const float* gw1    = (const float*)d_in[9];
    const float* gb1    = (const float*)d_in[10];
    const float* gw2    = (const float*)d_in[11];
    const float* gb2    = (const float*)d_in[12];
    const float* aw_in  = (const float*)d_in[13];
    const float* ab_in  = (const float*)d_in[14];
    const float* aw_out = (const float*)d_in[15];
    const float* ab_out = (const float*)d_in[16];
    const float* n1g    = (const float*)d_in[17];
    const float* n1b    = (const float*)d_in[18];
    const float* n2g    = (const float*)d_in[19];
    const float* n2b    = (const float*)d_in[20];
    const float* n3g    = (const float*)d_in[21];
    const float* n3b    = (const float*)d_in[22];
    const float* mw1    = (const float*)d_in[23];
    const float* mb1    = (const float*)d_in[24];
    const float* mw2    = (const float*)d_in[25];
    const float* mb2    = (const float*)d_in[26];
    const float* pw1    = (const float*)d_in[27];
    const float* pb1    = (const float*)d_in[28];
    const float* pw2    = (const float*)d_in[29];
    const float* pb2    = (const float*)d_in[30];

    char* ws = (char*)d_ws;
    size_t off = 0;
    auto alloc = [&](size_t bytes) {
        void* p = ws + off;
        off += (bytes + 255) & ~(size_t)255;
        return p;
    };
    float*  h    = (float*)alloc((size_t)N_NODES * D * 4);
    float*  bufB = (float*)alloc((size_t)N_NODES * D * 4);
    float*  tmp1 = (float*)alloc((size_t)N_NODES * D * 4);
    unsigned short* hb = (unsigned short*)alloc((size_t)N_NODES * D * 2);
    char*   U    = (char*)alloc((size_t)N_NODES * D3 * 2);
    unsigned short* bfA = (unsigned short*)alloc((size_t)N_NODES * D3 * 2);
    unsigned short* WT  = (unsigned short*)alloc((size_t)NL * WT_PER_LAYER * 2);
    float*  bw   = (float*)alloc((size_t)NL * 66 * D * 4);
    unsigned short* ctb = (unsigned short*)alloc((size_t)NL * NCOMBO * D * 2);
    int*    deg  = (int*)alloc((size_t)N_NODES * 4);
    int*    row_ptr = (int*)alloc((size_t)(N_NODES + 1) * 4);
    int*    cursor  = (int*)alloc((size_t)N_NODES * 4);
    int2*   sorted  = (int2*)alloc((size_t)NE * 8);
    float*  statacc = (float*)alloc((size_t)3 * 512 * 4);
    float*  msbuf   = (float*)alloc((size_t)3 * 2 * D * 4);
    float*  g    = (float*)alloc((size_t)NB * D * 4);
    (void)ws_size; (void)in_sizes; (void)n_in; (void)out_size;

    float* tmp23 = (float*)U;
    unsigned short* qkv = (unsigned short*)U;
    unsigned short* aggb  = bfA;
    unsigned short* ao    = bfA;
    unsigned short* bufBb = bfA;
    unsigned short* hid   = bfA + (size_t)N_NODES * D;
    float* ms1 = msbuf, *ms3 = msbuf + 4 * D;

    const int* srcp = eidx;
    const int* dstp = eidx + NE;
    const int EW = N_NODES * D / 1024;

    k_zero16k<<<N_NODES / 256, 256, 0, stream>>>(deg);
    k_zero_stats<<<1, 256, 0, stream>>>(statacc);
    k_hist<<<NE / 256, 256, 0, stream>>>(dstp, deg);
    k_scan<<<1, 256, 0, stream>>>(deg, row_ptr, cursor);
    k_scatter<<<NE / 256, 256, 0, stream>>>(srcp, dstp, ea, cursor, sorted);
    k_atom_enc<<<N_NODES / 4, 256, 0, stream>>>(x, atom_tab, h, hb);
    k_bondw<<<NL * 66, 256, 0, stream>>>(bond_tab, elin_w, bw);
    k_combo<<<NL * NCOMBO, 256, 0, stream>>>(bw, elin_b, ctb);
    k_wcvt<<<NL * 768, 256, 0, stream>>>(gw1, gw2, aw_in, aw_out, mw1, mw2, WT);

    for (int l = 0; l < NL; ++l) {
        const unsigned short* WTl = WT + (size_t)l * WT_PER_LAYER;
        // --- GINE aggregation ---
        k_gine_agg<<<N_NODES / 4, 256, 0, stream>>>(hb, h, ctb + (size_t)l * NCOMBO * D, eps, l,
                                                    row_ptr, sorted, aggb);
        // --- merged gw1 (relu, ->hid) + aw_in (->qkv): 1280 blocks ---
        k_mm2_dual<<<dim3(10, N_NODES / 128), 256, 0, stream>>>(
            aggb, WTl + 0, gb1 + (size_t)l * D2, hid, D2, 4,
            hb, WTl + 262144, ab_in + (size_t)l * D3, qkv, D3, D);
        // --- gw2 (+res h, stat slot0, ->tmp1 f32) ---
        k_mm64<0, 1, 0, 1><<<dim3(D / 128, N_NODES / 64), 256, 0, stream>>>(
            hid, WTl + 131072, gb2 + (size_t)l * D, h, tmp1, statacc, N_NODES, D, D2);
        // --- flash attention ---
        k_flash_mfma<<<dim3(NB * NH, S_PG / 64), 256, 0, stream>>>(qkv, ao);
        // --- aw_out (+res h, stat slot1, ->tmp23 f32) ---
        k_mm64<0, 1, 0, 1><<<dim3(D / 128, N_NODES / 64), 256, 0, stream>>>(
            ao, WTl + 458752, ab_out + (size_t)l * D, h, tmp23, statacc + 512, N_NODES, D, D);
        // --- finish bn1+bn2 stats in one launch ---
        k_bn_finish2<<<2, 256, 0, stream>>>(statacc, msbuf);
        // --- combine bn1+bn2 ---
        k_bn12<<<EW, 256, 0, stream>>>(tmp1, ms1, n1g + l * D, n1b + l * D,
                                       tmp23, msbuf + 2 * D, n2g + l * D, n2b + l * D, bufB, bufBb);
        // --- MLP ---
        k_mm2<1, 0, 1, 0><<<dim3(D2 / 128, N_NODES / 128), 256, 0, stream>>>(
            bufBb, WTl + 524288, mb1 + (size_t)l * D2, nullptr, hid, nullptr, N_NODES, D2, D);
        k_mm64<0, 1, 0, 1><<<dim3(D / 128, N_NODES / 64), 256, 0, stream>>>(
            hid, WTl + 655360, mb2 + (size_t)l * D, bufB, tmp23, statacc + 1024, N_NODES, D, D2);
        k_bn_finish<<<1, 256, 0, stream>>>(statacc + 1024, ms3);
        k_bn_apply<<<EW, 256, 0, stream>>>(tmp23, ms3, n3g + l * D, n3b + l * D, h, hb);
    }
    k_pool<<<NB, 256, 0, stream>>>(h, g);
    k_final<<<NB, 256, 0, stream>>>(g, pw1, pb1, pw2, pb2, (float*)d_out);
}

// Round 9
// 909.184 us; speedup vs baseline: 6.8190x; 1.0371x over previous
//
#include <hip/hip_runtime.h>
#include <hip/hip_bf16.h>
#include <math.h>

#define N_NODES 16384
#define NB      32
#define S_PG    512
#define NE      262144
#define EPG     8192
#define D       256
#define D2      512
#define D3      768
#define NL      4
#define NH      4
#define DHD     64
#define OUTD    768
#define NCOMBO  264
#define WT_PER_LAYER 786432
#define INV_N   (1.0f / (float)N_NODES)

typedef short s8v __attribute__((ext_vector_type(8)));
typedef float f4v __attribute__((ext_vector_type(4)));

__device__ __forceinline__ unsigned bfr(float f) {   // fp32 -> bf16 bits, RNE
    unsigned u = __float_as_uint(f);
    return (u + 0x7fffu + ((u >> 16) & 1u)) >> 16;
}
__device__ __forceinline__ float b2f(unsigned short u) {
    return __uint_as_float(((unsigned)u) << 16);
}

// ---------------- Atom encoder: h (f32) + hb (bf16) ----------------
__global__ __launch_bounds__(256) void k_atom_enc(const int* __restrict__ x,
                                                  const float* __restrict__ tab,
                                                  float* __restrict__ h,
                                                  unsigned short* __restrict__ hb) {
    int node = blockIdx.x * 4 + (threadIdx.x >> 6);
    int lane = threadIdx.x & 63;
    int dd = lane << 2;
    float4 acc = {0.f, 0.f, 0.f, 0.f};
#pragma unroll
    for (int f = 0; f < 9; ++f) {
        int v = x[node * 9 + f];
        const float4 t = *(const float4*)&tab[((size_t)(f * 119 + v)) * D + dd];
        acc.x += t.x; acc.y += t.y; acc.z += t.z; acc.w += t.w;
    }
    *(float4*)&h[(size_t)node * D + dd] = acc;
    ushort4 o;
    o.x = (unsigned short)bfr(acc.x); o.y = (unsigned short)bfr(acc.y);
    o.z = (unsigned short)bfr(acc.z); o.w = (unsigned short)bfr(acc.w);
    *(ushort4*)&hb[(size_t)node * D + dd] = o;
}

// ---------------- bw[l,fv,:] = bond_tab[fv,:] @ elin_w[l] ----------------
__global__ __launch_bounds__(256) void k_bondw(const float* __restrict__ bond_tab,
                                               const float* __restrict__ elin_w,
                                               float* __restrict__ bw) {
    int blk = blockIdx.x;         // L*66
    int l = blk / 66, fv = blk % 66;
    int dout = threadIdx.x;
    const float* tabrow = bond_tab + (size_t)fv * D;
    const float* w = elin_w + (size_t)l * D * D;
    float acc = 0.f;
    for (int d = 0; d < D; ++d) acc = fmaf(tabrow[d], w[d * D + dout], acc);
    bw[((size_t)l * 66 + fv) * D + dout] = acc;
}

// ---------------- combo table (bf16) ----------------
__global__ __launch_bounds__(256) void k_combo(const float* __restrict__ bw,
                                               const float* __restrict__ elin_b,
                                               unsigned short* __restrict__ ctb) {
    int b = blockIdx.x;           // NL*264
    int l = b / NCOMBO, cid = b % NCOMBO;
    int a0 = cid / 12, a1 = (cid % 12) / 2, a2 = cid & 1;
    int d = threadIdx.x;
    const float* bwl = bw + (size_t)l * 66 * D;
    float v = bwl[(size_t)a0 * D + d] + bwl[(size_t)(22 + a1) * D + d] +
              bwl[(size_t)(44 + a2) * D + d] + elin_b[(size_t)l * D + d];
    ctb[((size_t)l * NCOMBO + cid) * D + d] = (unsigned short)bfr(v);
}

// ---------------- CSR build ----------------
__global__ __launch_bounds__(256) void k_zero16k(int* __restrict__ p) {
    p[blockIdx.x * 256 + threadIdx.x] = 0;
}
__global__ __launch_bounds__(256) void k_zero_stats12(float* __restrict__ p) {
    for (int i = 0; i < 24; ++i) p[i * 256 + threadIdx.x] = 0.f;   // 12 slots x 512
}
__global__ __launch_bounds__(256) void k_hist(const int* __restrict__ dst, int* __restrict__ deg) {
    int e = blockIdx.x * 256 + threadIdx.x;
    atomicAdd(&deg[dst[e]], 1);
}
__global__ __launch_bounds__(256) void k_scan(const int* __restrict__ deg,
                                              int* __restrict__ row_ptr,
                                              int* __restrict__ cursor) {
    __shared__ int partial[256];
    int t = threadIdx.x;
    int base = t * 64;
    int s = 0;
    for (int i = 0; i < 64; ++i) s += deg[base + i];
    partial[t] = s;
    __syncthreads();
    for (int dstp = 1; dstp < 256; dstp <<= 1) {
        int v = (t >= dstp) ? partial[t - dstp] : 0;
        __syncthreads();
        partial[t] += v;
        __syncthreads();
    }
    int run = partial[t] - s;
    for (int i = 0; i < 64; ++i) {
        int dcur = deg[base + i];
        row_ptr[base + i] = run;
        cursor[base + i] = run;
        run += dcur;
    }
    if (t == 255) row_ptr[N_NODES] = run;
}
__global__ __launch_bounds__(256) void k_scatter(const int* __restrict__ src,
                                                 const int* __restrict__ dst,
                                                 const int* __restrict__ ea,
                                                 int* __restrict__ cursor,
                                                 int2* __restrict__ sorted) {
    int e = blockIdx.x * 256 + threadIdx.x;
    int d = dst[e];
    int pos = atomicAdd(&cursor[d], 1);
    int cid = ea[e * 3] * 12 + ea[e * 3 + 1] * 2 + ea[e * 3 + 2];
    sorted[pos] = make_int2(src[e], cid);
}

// ---------------- GINE aggregation (bf16 gather) ----------------
__global__ __launch_bounds__(256) void k_gine_agg(const unsigned short* __restrict__ hb,
                                                  const float* __restrict__ h,
                                                  const unsigned short* __restrict__ ctb,
                                                  const float* __restrict__ eps, int l,
                                                  const int* __restrict__ row_ptr,
                                                  const int2* __restrict__ sorted,
                                                  unsigned short* __restrict__ aggb) {
    int w = threadIdx.x >> 6;
    int lane = threadIdx.x & 63;
    int n = blockIdx.x * 4 + w;
    int dd = lane << 2;
    int beg = row_ptr[n], end = row_ptr[n + 1];
    float4 acc = {0.f, 0.f, 0.f, 0.f};
    int i = beg;
    for (; i + 2 <= end; i += 2) {
        int2 e0 = sorted[i];
        int2 e1 = sorted[i + 1];
        ushort4 h0 = *(const ushort4*)&hb[(size_t)e0.x * D + dd];
        ushort4 c0 = *(const ushort4*)&ctb[(size_t)e0.y * D + dd];
        ushort4 h1 = *(const ushort4*)&hb[(size_t)e1.x * D + dd];
        ushort4 c1 = *(const ushort4*)&ctb[(size_t)e1.y * D + dd];
        acc.x += fmaxf(b2f(h0.x) + b2f(c0.x), 0.f) + fmaxf(b2f(h1.x) + b2f(c1.x), 0.f);
        acc.y += fmaxf(b2f(h0.y) + b2f(c0.y), 0.f) + fmaxf(b2f(h1.y) + b2f(c1.y), 0.f);
        acc.z += fmaxf(b2f(h0.z) + b2f(c0.z), 0.f) + fmaxf(b2f(h1.z) + b2f(c1.z), 0.f);
        acc.w += fmaxf(b2f(h0.w) + b2f(c0.w), 0.f) + fmaxf(b2f(h1.w) + b2f(c1.w), 0.f);
    }
    if (i < end) {
        int2 e0 = sorted[i];
        ushort4 h0 = *(const ushort4*)&hb[(size_t)e0.x * D + dd];
        ushort4 c0 = *(const ushort4*)&ctb[(size_t)e0.y * D + dd];
        acc.x += fmaxf(b2f(h0.x) + b2f(c0.x), 0.f);
        acc.y += fmaxf(b2f(h0.y) + b2f(c0.y), 0.f);
        acc.z += fmaxf(b2f(h0.z) + b2f(c0.z), 0.f);
        acc.w += fmaxf(b2f(h0.w) + b2f(c0.w), 0.f);
    }
    float s1p = 1.f + eps[l];
    float4 hn = *(const float4*)&h[(size_t)n * D + dd];
    ushort4 o;
    o.x = (unsigned short)bfr(s1p * hn.x + acc.x);
    o.y = (unsigned short)bfr(s1p * hn.y + acc.y);
    o.z = (unsigned short)bfr(s1p * hn.z + acc.z);
    o.w = (unsigned short)bfr(s1p * hn.w + acc.w);
    *(ushort4*)&aggb[(size_t)n * D + dd] = o;
}

// ---------------- weight transpose+convert ----------------
__global__ __launch_bounds__(256) void k_wcvt(const float* __restrict__ gw1, const float* __restrict__ gw2,
                                              const float* __restrict__ aw_in, const float* __restrict__ aw_out,
                                              const float* __restrict__ mw1, const float* __restrict__ mw2,
                                              unsigned short* __restrict__ WT) {
    const int KS[6]   = {256, 512, 256, 256, 256, 512};
    const int NS[6]   = {512, 256, 768, 256, 512, 256};
    const int TOFF[7] = {0, 128, 256, 448, 512, 640, 768};
    const int DOFF[6] = {0, 131072, 262144, 458752, 524288, 655360};
    int b = blockIdx.x;
    int l = b / 768, wb = b % 768;
    int widx = 0;
    while (wb >= TOFF[widx + 1]) ++widx;
    int t = wb - TOFF[widx];
    int K = KS[widx], N = NS[widx];
    int nn = N / 32;
    int kt = t / nn, nt = t % nn;
    const float* srcs[6] = {gw1, gw2, aw_in, aw_out, mw1, mw2};
    const float* W = srcs[widx] + (size_t)l * K * N;
    unsigned short* WTp = WT + (size_t)l * WT_PER_LAYER + DOFF[widx];
    __shared__ float tile[32][33];
    int tid = threadIdx.x;
    int r = tid >> 3, c4 = (tid & 7) << 2;
    float4 v = *(const float4*)&W[(size_t)(kt * 32 + r) * N + nt * 32 + c4];
    tile[r][c4] = v.x; tile[r][c4 + 1] = v.y; tile[r][c4 + 2] = v.z; tile[r][c4 + 3] = v.w;
    __syncthreads();
    int nr = tid >> 3, kc = (tid & 7) << 2;
    ushort4 o;
    o.x = (unsigned short)bfr(tile[kc + 0][nr]);
    o.y = (unsigned short)bfr(tile[kc + 1][nr]);
    o.z = (unsigned short)bfr(tile[kc + 2][nr]);
    o.w = (unsigned short)bfr(tile[kc + 3][nr]);
    *(ushort4*)&WTp[(size_t)(nt * 32 + nr) * K + kt * 32 + kc] = o;
}

// ---------------- BM=128 bf16 MFMA GEMM (single) ----------------
template<int RELU, int RES, int OBF, int STAT>
__global__ __launch_bounds__(256) void k_mm2(const unsigned short* __restrict__ A,
                                             const unsigned short* __restrict__ BT,
                                             const float* __restrict__ bias,
                                             const float* __restrict__ res,
                                             void* __restrict__ Cp,
                                             float* __restrict__ stat,
                                             int M, int N, int K) {
    __shared__ unsigned short As[128 * 64];
    __shared__ unsigned short Bs[128 * 64];
    const int tid = threadIdx.x;
    const int row0 = blockIdx.y * 128, col0 = blockIdx.x * 128;
    const int w = tid >> 6, l = tid & 63;
    const int wm = w >> 1, wn = w & 1;
    const int lr = l & 15, lq = l >> 4;
    const int srow = l >> 3;
    const int scol = (l & 7) * 8;
    f4v acc[4][4] = {};

    const unsigned short* Ag = A + (size_t)(row0 + w * 32 + srow) * K + scol;
    const unsigned short* Bg = BT + (size_t)(col0 + w * 32 + srow) * K + scol;
    unsigned short* Al = &As[(w * 32) * 64];
    unsigned short* Bl = &Bs[(w * 32) * 64];

    for (int k0 = 0; k0 < K; k0 += 64) {
#pragma unroll
        for (int it = 0; it < 4; ++it) {
            __builtin_amdgcn_global_load_lds(
                (const __attribute__((address_space(1))) unsigned*)(Ag + (size_t)(it * 8) * K + k0),
                (__attribute__((address_space(3))) unsigned*)(Al + it * 8 * 64), 16, 0, 0);
            __builtin_amdgcn_global_load_lds(
                (const __attribute__((address_space(1))) unsigned*)(Bg + (size_t)(it * 8) * K + k0),
                (__attribute__((address_space(3))) unsigned*)(Bl + it * 8 * 64), 16, 0, 0);
        }
        asm volatile("s_waitcnt vmcnt(0)" ::: "memory");
        __syncthreads();
#pragma unroll
        for (int kk = 0; kk < 2; ++kk) {
            s8v af[4], bf[4];
#pragma unroll
            for (int m = 0; m < 4; ++m)
                af[m] = *(const s8v*)&As[(wm * 64 + m * 16 + lr) * 64 + kk * 32 + lq * 8];
#pragma unroll
            for (int n = 0; n < 4; ++n)
                bf[n] = *(const s8v*)&Bs[(wn * 64 + n * 16 + lr) * 64 + kk * 32 + lq * 8];
#pragma unroll
            for (int m = 0; m < 4; ++m)
#pragma unroll
                for (int n = 0; n < 4; ++n)
                    acc[m][n] = __builtin_amdgcn_mfma_f32_16x16x32_bf16(af[m], bf[n], acc[m][n], 0, 0, 0);
        }
        __syncthreads();
    }
    float cs[4], cs2[4];
#pragma unroll
    for (int n = 0; n < 4; ++n) { cs[n] = 0.f; cs2[n] = 0.f; }
#pragma unroll
    for (int n = 0; n < 4; ++n) {
        int c = col0 + wn * 64 + n * 16 + lr;
        float bv = bias[c];
#pragma unroll
        for (int m = 0; m < 4; ++m) {
#pragma unroll
            for (int j = 0; j < 4; ++j) {
                int r = row0 + wm * 64 + m * 16 + lq * 4 + j;
                float v = acc[m][n][j] + bv;
                if (RES) v += res[(size_t)r * N + c];
                if (STAT) { cs[n] += v; cs2[n] += v * v; }
                if (RELU) v = fmaxf(v, 0.f);
                if (OBF) ((unsigned short*)Cp)[(size_t)r * N + c] = (unsigned short)bfr(v);
                else ((float*)Cp)[(size_t)r * N + c] = v;
            }
        }
    }
    if (STAT) {
#pragma unroll
        for (int n = 0; n < 4; ++n) {
            float s = cs[n], s2 = cs2[n];
            s += __shfl_xor(s, 16);  s2 += __shfl_xor(s2, 16);
            s += __shfl_xor(s, 32);  s2 += __shfl_xor(s2, 32);
            if (lq == 0) {
                int c = col0 + wn * 64 + n * 16 + lr;
                atomicAdd(&stat[c], s);
                atomicAdd(&stat[256 + c], s2);
            }
        }
    }
}

// ---------------- dual GEMM dispatch (BM=128): gw1 (relu) + aw_in ----------------
__global__ __launch_bounds__(256) void k_mm2_dual(const unsigned short* __restrict__ A1,
                                                  const unsigned short* __restrict__ B1,
                                                  const float* __restrict__ bias1,
                                                  unsigned short* __restrict__ C1, int N1, int nb1,
                                                  const unsigned short* __restrict__ A2,
                                                  const unsigned short* __restrict__ B2,
                                                  const float* __restrict__ bias2,
                                                  unsigned short* __restrict__ C2, int N2,
                                                  int K) {
    __shared__ unsigned short As[128 * 64];
    __shared__ unsigned short Bs[128 * 64];
    const unsigned short* A; const unsigned short* BT; const float* bias;
    unsigned short* C; int N, cb, relu;
    if ((int)blockIdx.x < nb1) { A = A1; BT = B1; bias = bias1; C = C1; N = N1; cb = blockIdx.x; relu = 1; }
    else { A = A2; BT = B2; bias = bias2; C = C2; N = N2; cb = blockIdx.x - nb1; relu = 0; }
    const int tid = threadIdx.x;
    const int row0 = blockIdx.y * 128, col0 = cb * 128;
    const int w = tid >> 6, l = tid & 63;
    const int wm = w >> 1, wn = w & 1;
    const int lr = l & 15, lq = l >> 4;
    const int srow = l >> 3;
    const int scol = (l & 7) * 8;
    f4v acc[4][4] = {};

    const unsigned short* Ag = A + (size_t)(row0 + w * 32 + srow) * K + scol;
    const unsigned short* Bg = BT + (size_t)(col0 + w * 32 + srow) * K + scol;
    unsigned short* Al = &As[(w * 32) * 64];
    unsigned short* Bl = &Bs[(w * 32) * 64];

    for (int k0 = 0; k0 < K; k0 += 64) {
#pragma unroll
        for (int it = 0; it < 4; ++it) {
            __builtin_amdgcn_global_load_lds(
                (const __attribute__((address_space(1))) unsigned*)(Ag + (size_t)(it * 8) * K + k0),
                (__attribute__((address_space(3))) unsigned*)(Al + it * 8 * 64), 16, 0, 0);
            __builtin_amdgcn_global_load_lds(
                (const __attribute__((address_space(1))) unsigned*)(Bg + (size_t)(it * 8) * K + k0),
                (__attribute__((address_space(3))) unsigned*)(Bl + it * 8 * 64), 16, 0, 0);
        }
        asm volatile("s_waitcnt vmcnt(0)" ::: "memory");
        __syncthreads();
#pragma unroll
        for (int kk = 0; kk < 2; ++kk) {
            s8v af[4], bf[4];
#pragma unroll
            for (int m = 0; m < 4; ++m)
                af[m] = *(const s8v*)&As[(wm * 64 + m * 16 + lr) * 64 + kk * 32 + lq * 8];
#pragma unroll
            for (int n = 0; n < 4; ++n)
                bf[n] = *(const s8v*)&Bs[(wn * 64 + n * 16 + lr) * 64 + kk * 32 + lq * 8];
#pragma unroll
            for (int m = 0; m < 4; ++m)
#pragma unroll
                for (int n = 0; n < 4; ++n)
                    acc[m][n] = __builtin_amdgcn_mfma_f32_16x16x32_bf16(af[m], bf[n], acc[m][n], 0, 0, 0);
        }
        __syncthreads();
    }
#pragma unroll
    for (int n = 0; n < 4; ++n) {
        int c = col0 + wn * 64 + n * 16 + lr;
        float bv = bias[c];
#pragma unroll
        for (int m = 0; m < 4; ++m) {
#pragma unroll
            for (int j = 0; j < 4; ++j) {
                int r = row0 + wm * 64 + m * 16 + lq * 4 + j;
                float v = acc[m][n][j] + bv;
                if (relu) v = fmaxf(v, 0.f);
                C[(size_t)r * N + c] = (unsigned short)bfr(v);
            }
        }
    }
}

// ---------------- BM=64 bf16 MFMA GEMM (single, N=256 shapes) ----------------
template<int RELU, int RES, int OBF, int STAT>
__global__ __launch_bounds__(256) void k_mm64(const unsigned short* __restrict__ A,
                                              const unsigned short* __restrict__ BT,
                                              const float* __restrict__ bias,
                                              const float* __restrict__ res,
                                              void* __restrict__ Cp,
                                              float* __restrict__ stat,
                                              int M, int N, int K) {
    __shared__ unsigned short As[64 * 64];
    __shared__ unsigned short Bs[128 * 64];
    const int tid = threadIdx.x;
    const int row0 = blockIdx.y * 64, col0 = blockIdx.x * 128;
    const int w = tid >> 6, l = tid & 63;
    const int wn = w;
    const int lr = l & 15, lq = l >> 4;
    const int srow = l >> 3;
    const int scol = (l & 7) * 8;
    f4v acc[4][2] = {};

    const unsigned short* Ag = A + (size_t)(row0 + w * 16 + srow) * K + scol;
    const unsigned short* Bg = BT + (size_t)(col0 + w * 32 + srow) * K + scol;
    unsigned short* Al = &As[(w * 16) * 64];
    unsigned short* Bl = &Bs[(w * 32) * 64];

    for (int k0 = 0; k0 < K; k0 += 64) {
#pragma unroll
        for (int it = 0; it < 2; ++it)
            __builtin_amdgcn_global_load_lds(
                (const __attribute__((address_space(1))) unsigned*)(Ag + (size_t)(it * 8) * K + k0),
                (__attribute__((address_space(3))) unsigned*)(Al + it * 8 * 64), 16, 0, 0);
#pragma unroll
        for (int it = 0; it < 4; ++it)
            __builtin_amdgcn_global_load_lds(
                (const __attribute__((address_space(1))) unsigned*)(Bg + (size_t)(it * 8) * K + k0),
                (__attribute__((address_space(3))) unsigned*)(Bl + it * 8 * 64), 16, 0, 0);
        asm volatile("s_waitcnt vmcnt(0)" ::: "memory");
        __syncthreads();
#pragma unroll
        for (int kk = 0; kk < 2; ++kk) {
            s8v af[4], bf[2];
#pragma unroll
            for (int m = 0; m < 4; ++m)
                af[m] = *(const s8v*)&As[(m * 16 + lr) * 64 + kk * 32 + lq * 8];
#pragma unroll
            for (int n = 0; n < 2; ++n)
                bf[n] = *(const s8v*)&Bs[(wn * 32 + n * 16 + lr) * 64 + kk * 32 + lq * 8];
#pragma unroll
            for (int m = 0; m < 4; ++m)
#pragma unroll
                for (int n = 0; n < 2; ++n)
                    acc[m][n] = __builtin_amdgcn_mfma_f32_16x16x32_bf16(af[m], bf[n], acc[m][n], 0, 0, 0);
        }
        __syncthreads();
    }
    float cs[2], cs2[2];
#pragma unroll
    for (int n = 0; n < 2; ++n) { cs[n] = 0.f; cs2[n] = 0.f; }
#pragma unroll
    for (int n = 0; n < 2; ++n) {
        int c = col0 + wn * 32 + n * 16 + lr;
        float bv = bias[c];
#pragma unroll
        for (int m = 0; m < 4; ++m) {
#pragma unroll
            for (int j = 0; j < 4; ++j) {
                int r = row0 + m * 16 + lq * 4 + j;
                float v = acc[m][n][j] + bv;
                if (RES) v += res[(size_t)r * N + c];
                if (STAT) { cs[n] += v; cs2[n] += v * v; }
                if (RELU) v = fmaxf(v, 0.f);
                if (OBF) ((unsigned short*)Cp)[(size_t)r * N + c] = (unsigned short)bfr(v);
                else ((float*)Cp)[(size_t)r * N + c] = v;
            }
        }
    }
    if (STAT) {
#pragma unroll
        for (int n = 0; n < 2; ++n) {
            float s = cs[n], s2 = cs2[n];
            s += __shfl_xor(s, 16);  s2 += __shfl_xor(s2, 16);
            s += __shfl_xor(s, 32);  s2 += __shfl_xor(s2, 32);
            if (lq == 0) {
                int c = col0 + wn * 32 + n * 16 + lr;
                atomicAdd(&stat[c], s);
                atomicAdd(&stat[256 + c], s2);
            }
        }
    }
}

// ---------------- dual BM=64 GEMM: gw2 (K=512) + aw_out (K=256), both RES+STAT, f32 out ----------------
__global__ __launch_bounds__(256) void k_mm64_dual(const unsigned short* __restrict__ A1,
                                                   const unsigned short* __restrict__ B1,
                                                   const float* __restrict__ bias1,
                                                   const float* __restrict__ res1,
                                                   float* __restrict__ C1,
                                                   float* __restrict__ stat1, int K1, int nb1,
                                                   const unsigned short* __restrict__ A2,
                                                   const unsigned short* __restrict__ B2,
                                                   const float* __restrict__ bias2,
                                                   const float* __restrict__ res2,
                                                   float* __restrict__ C2,
                                                   float* __restrict__ stat2, int K2) {
    __shared__ unsigned short As[64 * 64];
    __shared__ unsigned short Bs[128 * 64];
    const unsigned short *A, *BT; const float *bias, *res; float *C, *stat;
    int K, cb;
    if ((int)blockIdx.x < nb1) { A = A1; BT = B1; bias = bias1; res = res1; C = C1; stat = stat1; K = K1; cb = blockIdx.x; }
    else { A = A2; BT = B2; bias = bias2; res = res2; C = C2; stat = stat2; K = K2; cb = blockIdx.x - nb1; }
    const int N = 256;
    const int tid = threadIdx.x;
    const int row0 = blockIdx.y * 64, col0 = cb * 128;
    const int w = tid >> 6, l = tid & 63;
    const int wn = w;
    const int lr = l & 15, lq = l >> 4;
    const int srow = l >> 3;
    const int scol = (l & 7) * 8;
    f4v acc[4][2] = {};

    const unsigned short* Ag = A + (size_t)(row0 + w * 16 + srow) * K + scol;
    const unsigned short* Bg = BT + (size_t)(col0 + w * 32 + srow) * K + scol;
    unsigned short* Al = &As[(w * 16) * 64];
    unsigned short* Bl = &Bs[(w * 32) * 64];

    for (int k0 = 0; k0 < K; k0 += 64) {
#pragma unroll
        for (int it = 0; it < 2; ++it)
            __builtin_amdgcn_global_load_lds(
                (const __attribute__((address_space(1))) unsigned*)(Ag + (size_t)(it * 8) * K + k0),
                (__attribute__((address_space(3))) unsigned*)(Al + it * 8 * 64), 16, 0, 0);
#pragma unroll
        for (int it = 0; it < 4; ++it)
            __builtin_amdgcn_global_load_lds(
                (const __attribute__((address_space(1))) unsigned*)(Bg + (size_t)(it * 8) * K + k0),
                (__attribute__((address_space(3))) unsigned*)(Bl + it * 8 * 64), 16, 0, 0);
        asm volatile("s_waitcnt vmcnt(0)" ::: "memory");
        __syncthreads();
#pragma unroll
        for (int kk = 0; kk < 2; ++kk) {
            s8v af[4], bf[2];
#pragma unroll
            for (int m = 0; m < 4; ++m)
                af[m] = *(const s8v*)&As[(m * 16 + lr) * 64 + kk * 32 + lq * 8];
#pragma unroll
            for (int n = 0; n < 2; ++n)
                bf[n] = *(const s8v*)&Bs[(wn * 32 + n * 16 + lr) * 64 + kk * 32 + lq * 8];
#pragma unroll
            for (int m = 0; m < 4; ++m)
#pragma unroll
                for (int n = 0; n < 2; ++n)
                    acc[m][n] = __builtin_amdgcn_mfma_f32_16x16x32_bf16(af[m], bf[n], acc[m][n], 0, 0, 0);
        }
        __syncthreads();
    }
    float cs[2], cs2[2];
#pragma unroll
    for (int n = 0; n < 2; ++n) { cs[n] = 0.f; cs2[n] = 0.f; }
#pragma unroll
    for (int n = 0; n < 2; ++n) {
        int c = col0 + wn * 32 + n * 16 + lr;
        float bv = bias[c];
#pragma unroll
        for (int m = 0; m < 4; ++m) {
#pragma unroll
            for (int j = 0; j < 4; ++j) {
                int r = row0 + m * 16 + lq * 4 + j;
                float v = acc[m][n][j] + bv + res[(size_t)r * N + c];
                cs[n] += v; cs2[n] += v * v;
                C[(size_t)r * N + c] = v;
            }
        }
    }
#pragma unroll
    for (int n = 0; n < 2; ++n) {
        float s = cs[n], s2 = cs2[n];
        s += __shfl_xor(s, 16);  s2 += __shfl_xor(s2, 16);
        s += __shfl_xor(s, 32);  s2 += __shfl_xor(s2, 32);
        if (lq == 0) {
            int c = col0 + wn * 32 + n * 16 + lr;
            atomicAdd(&stat[c], s);
            atomicAdd(&stat[256 + c], s2);
        }
    }
}

// ---------------- fused: y = bn1(t1) + bn2(t2), inline stats, dual write ----------------
__global__ __launch_bounds__(256) void k_bn12i(const float* __restrict__ t1,
                                               const float* __restrict__ sa1,
                                               const float* __restrict__ g1,
                                               const float* __restrict__ b1,
                                               const float* __restrict__ t2,
                                               const float* __restrict__ sa2,
                                               const float* __restrict__ g2,
                                               const float* __restrict__ b2,
                                               float* __restrict__ y,
                                               unsigned short* __restrict__ yb) {
    size_t i4 = (size_t)blockIdx.x * blockDim.x + threadIdx.x;
    int c = (int)((i4 & 63) << 2);
    float a1[4], a2[4], o[4];
    *(float4*)a1 = ((const float4*)t1)[i4];
    *(float4*)a2 = ((const float4*)t2)[i4];
#pragma unroll
    for (int q = 0; q < 4; ++q) {
        int cc = c + q;
        float m1 = sa1[cc] * INV_N;
        float r1 = rsqrtf(sa1[256 + cc] * INV_N - m1 * m1 + 1e-5f);
        float m2 = sa2[cc] * INV_N;
        float r2 = rsqrtf(sa2[256 + cc] * INV_N - m2 * m2 + 1e-5f);
        o[q] = (a1[q] - m1) * r1 * g1[cc] + b1[cc] + (a2[q] - m2) * r2 * g2[cc] + b2[cc];
    }
    ((float4*)y)[i4] = *(float4*)o;
    ushort4 ob;
    ob.x = (unsigned short)bfr(o[0]); ob.y = (unsigned short)bfr(o[1]);
    ob.z = (unsigned short)bfr(o[2]); ob.w = (unsigned short)bfr(o[3]);
    ((ushort4*)yb)[i4] = ob;
}

// ---------------- bn apply (single), inline stats, dual write ----------------
__global__ __launch_bounds__(256) void k_bn_apply_i(const float* __restrict__ x,
                                                    const float* __restrict__ sa,
                                                    const float* __restrict__ g,
                                                    const float* __restrict__ b,
                                                    float* __restrict__ y,
                                                    unsigned short* __restrict__ yb) {
    size_t i4 = (size_t)blockIdx.x * blockDim.x + threadIdx.x;
    int c = (int)((i4 & 63) << 2);
    float a[4], o[4];
    *(float4*)a = ((const float4*)x)[i4];
#pragma unroll
    for (int q = 0; q < 4; ++q) {
        int cc = c + q;
        float m = sa[cc] * INV_N;
        float r = rsqrtf(sa[256 + cc] * INV_N - m * m + 1e-5f);
        o[q] = (a[q] - m) * r * g[cc] + b[cc];
    }
    ((float4*)y)[i4] = *(float4*)o;
    ushort4 ob;
    ob.x = (unsigned short)bfr(o[0]); ob.y = (unsigned short)bfr(o[1]);
    ob.z = (unsigned short)bfr(o[2]); ob.w = (unsigned short)bfr(o[3]);
    ((ushort4*)yb)[i4] = ob;
}

// ---------------- MFMA flash attention: 128 q-rows per block ----------------
__global__ __launch_bounds__(256) void k_flash_mfma(const unsigned short* __restrict__ qkv,
                                                    unsigned short* __restrict__ ao) {
    __shared__ unsigned short Ks[64][72];
    __shared__ unsigned short VT[64][72];
    __shared__ unsigned short Ps[4][2][16][72];
    const int bh = blockIdx.x;
    const int b = bh >> 2, hh = bh & 3;
    const int i0 = blockIdx.y << 7;              // 128 q rows
    const int tid = threadIdx.x;
    const int w = tid >> 6, l = tid & 63;
    const int lr = l & 15, lq = l >> 4;
    const int hd = hh * DHD;
    const size_t rowbase = (size_t)(b * S_PG) * D3;

    s8v aq[2][2];
#pragma unroll
    for (int g = 0; g < 2; ++g) {
        const unsigned short* qrow = &qkv[rowbase + (size_t)(i0 + g * 64 + w * 16 + lr) * D3 + hd + lq * 8];
        aq[g][0] = *(const s8v*)&qrow[0];
        aq[g][1] = *(const s8v*)&qrow[32];
    }

    float mrow[2][4], lrow[2][4];
    f4v oacc[2][4] = {};
#pragma unroll
    for (int g = 0; g < 2; ++g)
#pragma unroll
        for (int j = 0; j < 4; ++j) { mrow[g][j] = -INFINITY; lrow[g][j] = 0.f; }

    const int skv = tid >> 2;                  // K staging: kv row 0..63
    const int sd0 = (tid & 3) << 4;            // K staging: d segment
    const int d0v = (tid >> 4) << 2;           // V staging: d block
    const int kv0 = (tid & 15) << 2;           // V staging: kv block

    for (int j0 = 0; j0 < S_PG; j0 += 64) {
        __syncthreads();
        {
            const unsigned short* kr = &qkv[rowbase + (size_t)(j0 + skv) * D3 + D + hd + sd0];
            *(uint4*)&Ks[skv][sd0]     = *(const uint4*)&kr[0];
            *(uint4*)&Ks[skv][sd0 + 8] = *(const uint4*)&kr[8];
            unsigned short vv[4][4];
#pragma unroll
            for (int i = 0; i < 4; ++i) {
                uint2 lv = *(const uint2*)&qkv[rowbase + (size_t)(j0 + kv0 + i) * D3 + D2 + hd + d0v];
                vv[i][0] = (unsigned short)(lv.x & 0xffffu);
                vv[i][1] = (unsigned short)(lv.x >> 16);
                vv[i][2] = (unsigned short)(lv.y & 0xffffu);
                vv[i][3] = (unsigned short)(lv.y >> 16);
            }
#pragma unroll
            for (int i2 = 0; i2 < 4; ++i2) {
                ushort4 o4;
                o4.x = vv[0][i2]; o4.y = vv[1][i2]; o4.z = vv[2][i2]; o4.w = vv[3][i2];
                *(ushort4*)&VT[d0v + i2][kv0] = o4;
            }
        }
        __syncthreads();
#pragma unroll
        for (int g = 0; g < 2; ++g) {
            f4v sc[4] = {};
#pragma unroll
            for (int nt = 0; nt < 4; ++nt) {
                s8v bk0 = *(const s8v*)&Ks[nt * 16 + lr][lq * 8];
                s8v bk1 = *(const s8v*)&Ks[nt * 16 + lr][32 + lq * 8];
                sc[nt] = __builtin_amdgcn_mfma_f32_16x16x32_bf16(aq[g][0], bk0, sc[nt], 0, 0, 0);
                sc[nt] = __builtin_amdgcn_mfma_f32_16x16x32_bf16(aq[g][1], bk1, sc[nt], 0, 0, 0);
            }
            float ps[4][4], alpha[4];
#pragma unroll
            for (int j = 0; j < 4; ++j) {
#pragma unroll
                for (int nt = 0; nt < 4; ++nt) ps[nt][j] = sc[nt][j] * 0.125f;
                float pm = fmaxf(fmaxf(ps[0][j], ps[1][j]), fmaxf(ps[2][j], ps[3][j]));
#pragma unroll
                for (int off = 1; off < 16; off <<= 1) pm = fmaxf(pm, __shfl_xor(pm, off));
                float mn = fmaxf(mrow[g][j], pm);
                alpha[j] = __expf(mrow[g][j] - mn);
                float rs = 0.f;
#pragma unroll
                for (int nt = 0; nt < 4; ++nt) { ps[nt][j] = __expf(ps[nt][j] - mn); rs += ps[nt][j]; }
#pragma unroll
                for (int off = 1; off < 16; off <<= 1) rs += __shfl_xor(rs, off);
                lrow[g][j] = lrow[g][j] * alpha[j] + rs;
                mrow[g][j] = mn;
            }
#pragma unroll
            for (int nt = 0; nt < 4; ++nt)
#pragma unroll
                for (int j = 0; j < 4; ++j)
                    Ps[w][g][lq * 4 + j][nt * 16 + lr] = (unsigned short)bfr(ps[nt][j]);
#pragma unroll
            for (int ntd = 0; ntd < 4; ++ntd)
#pragma unroll
                for (int j = 0; j < 4; ++j) oacc[g][ntd][j] *= alpha[j];
            s8v pa0 = *(const s8v*)&Ps[w][g][lr][lq * 8];
            s8v pa1 = *(const s8v*)&Ps[w][g][lr][32 + lq * 8];
#pragma unroll
            for (int ntd = 0; ntd < 4; ++ntd) {
                s8v bv0 = *(const s8v*)&VT[ntd * 16 + lr][lq * 8];
                s8v bv1 = *(const s8v*)&VT[ntd * 16 + lr][32 + lq * 8];
                oacc[g][ntd] = __builtin_amdgcn_mfma_f32_16x16x32_bf16(pa0, bv0, oacc[g][ntd], 0, 0, 0);
                oacc[g][ntd] = __builtin_amdgcn_mfma_f32_16x16x32_bf16(pa1, bv1, oacc[g][ntd], 0, 0, 0);
            }
        }
    }
#pragma unroll
    for (int g = 0; g < 2; ++g)
#pragma unroll
        for (int j = 0; j < 4; ++j) {
            float inv = 1.f / lrow[g][j];
            int node = b * S_PG + i0 + g * 64 + w * 16 + lq * 4 + j;
#pragma unroll
            for (int ntd = 0; ntd < 4; ++ntd)
                ao[(size_t)node * D + hd + ntd * 16 + lr] = (unsigned short)bfr(oacc[g][ntd][j] * inv);
        }
}

// ---------------- mean pool per graph ----------------
__global__ __launch_bounds__(256) void k_pool(const float* __restrict__ h, float* __restrict__ g) {
    int b = blockIdx.x, c = threadIdx.x;
    const float* p = h + (size_t)b * S_PG * D + c;
    float s = 0.f;
    for (int r = 0; r < S_PG; ++r) s += p[(size_t)r * D];
    g[b * D + c] = s * (1.f / (float)S_PG);
}

// ---------------- final head ----------------
__global__ __launch_bounds__(256) void k_final(const float* __restrict__ g,
                                               const float* __restrict__ pw1,
                                               const float* __restrict__ pb1,
                                               const float* __restrict__ pw2,
                                               const float* __restrict__ pb2,
                                               float* __restrict__ out) {
    __shared__ float gs[D];
    __shared__ float ts[D];
    __shared__ float red[4];
    int b = blockIdx.x, tid = threadIdx.x;
    gs[tid] = g[b * D + tid];
    __syncthreads();
    float acc = pb1[tid];
    for (int d = 0; d < D; ++d) acc = fmaf(gs[d], pw1[d * D + tid], acc);
    ts[tid] = fmaxf(acc, 0.f);
    __syncthreads();
    float z[3];
#pragma unroll
    for (int rep = 0; rep < 3; ++rep) {
        int j = tid + rep * 256;
        float a = pb2[j];
        for (int d = 0; d < D; ++d) a = fmaf(ts[d], pw2[(size_t)d * OUTD + j], a);
        z[rep] = a;
    }
    float ss = z[0] * z[0] + z[1] * z[1] + z[2] * z[2];
#pragma unroll
    for (int o = 32; o >= 1; o >>= 1) ss += __shfl_xor(ss, o);
    if ((tid & 63) == 0) red[tid >> 6] = ss;
    __syncthreads();
    float rn = rsqrtf(red[0] + red[1] + red[2] + red[3]);
#pragma unroll
    for (int rep = 0; rep < 3; ++rep) out[b * OUTD + tid + rep * 256] = z[rep] * rn;
}

extern "C" void kernel_launch(void* const* d_in, const int* in_sizes, int n_in,
                              void* d_out, int out_size, void* d_ws, size_t ws_size,
                              hipStream_t stream) {
    const int* x        = (const int*)d_in[0];
    const int* ea       = (const int*)d_in[1];
    const int* eidx     = (const int*)d_in[2];
    const float* atom_tab = (const float*)d_in[4];
    const float* bond_tab = (const float*)d_in[5];
    const float* elin_w = (const float*)d_in[6];
    const float* elin_b = (const float*)d_in[7];
    const float* eps    = (const float*)d_in[8];
    const float* gw1    = (const float*)d_in[9];
    const float* gb1    = (const float*)d_in[10];
    const float* gw2    = (const float*)d_in[11];
    const float* gb2    = (const float*)d_in[12];
    const float* aw_in  = (const float*)d_in[13];
    const float* ab_in  = (const float*)d_in[14];
    const float* aw_out = (const float*)d_in[15];
    const float* ab_out = (const float*)d_in[16];
    const float* n1g    = (const float*)d_in[17];
    const float* n1b    = (const float*)d_in[18];
    const float* n2g    = (const float*)d_in[19];
    const float* n2b    = (const float*)d_in[20];
    const float* n3g    = (const float*)d_in[21];
    const float* n3b    = (const float*)d_in[22];
    const float* mw1    = (const float*)d_in[23];
    const float* mb1    = (const float*)d_in[24];
    const float* mw2    = (const float*)d_in[25];
    const float* mb2    = (const float*)d_in[26];
    const float* pw1    = (const float*)d_in[27];
    const float* pb1    = (const float*)d_in[28];
    const float* pw2    = (const float*)d_in[29];
    const float* pb2    = (const float*)d_in[30];

    char* ws = (char*)d_ws;
    size_t off = 0;
    auto alloc = [&](size_t bytes) {
        void* p = ws + off;
        off += (bytes + 255) & ~(size_t)255;
        return p;
    };
    float*  h    = (float*)alloc((size_t)N_NODES * D * 4);
    float*  bufB = (float*)alloc((size_t)N_NODES * D * 4);
    float*  tmp1 = (float*)alloc((size_t)N_NODES * D * 4);
    unsigned short* hb = (unsigned short*)alloc((size_t)N_NODES * D * 2);
    char*   U    = (char*)alloc((size_t)N_NODES * D3 * 2);
    unsigned short* bfA = (unsigned short*)alloc((size_t)N_NODES * D3 * 2);
    unsigned short* WT  = (unsigned short*)alloc((size_t)NL * WT_PER_LAYER * 2);
    float*  bw   = (float*)alloc((size_t)NL * 66 * D * 4);
    unsigned short* ctb = (unsigned short*)alloc((size_t)NL * NCOMBO * D * 2);
    int*    deg  = (int*)alloc((size_t)N_NODES * 4);
    int*    row_ptr = (int*)alloc((size_t)(N_NODES + 1) * 4);
    int*    cursor  = (int*)alloc((size_t)N_NODES * 4);
    int2*   sorted  = (int2*)alloc((size_t)NE * 8);
    float*  statacc = (float*)alloc((size_t)12 * 512 * 4);   // 12 per-layer slots [sum|sum2]
    float*  g    = (float*)alloc((size_t)NB * D * 4);
    (void)ws_size; (void)in_sizes; (void)n_in; (void)out_size;

    float* tmp23 = (float*)U;
    unsigned short* qkv = (unsigned short*)U;
    unsigned short* aggb  = bfA;
    unsigned short* ao    = bfA;
    unsigned short* bufBb = bfA;
    unsigned short* hid   = bfA + (size_t)N_NODES * D;

    const int* srcp = eidx;
    const int* dstp = eidx + NE;
    const int EW = N_NODES * D / 1024;

    k_zero16k<<<N_NODES / 256, 256, 0, stream>>>(deg);
    k_zero_stats12<<<1, 256, 0, stream>>>(statacc);
    k_hist<<<NE / 256, 256, 0, stream>>>(dstp, deg);
    k_scan<<<1, 256, 0, stream>>>(deg, row_ptr, cursor);
    k_scatter<<<NE / 256, 256, 0, stream>>>(srcp, dstp, ea, cursor, sorted);
    k_atom_enc<<<N_NODES / 4, 256, 0, stream>>>(x, atom_tab, h, hb);
    k_bondw<<<NL * 66, 256, 0, stream>>>(bond_tab, elin_w, bw);
    k_combo<<<NL * NCOMBO, 256, 0, stream>>>(bw, elin_b, ctb);
    k_wcvt<<<NL * 768, 256, 0, stream>>>(gw1, gw2, aw_in, aw_out, mw1, mw2, WT);

    for (int l = 0; l < NL; ++l) {
        const unsigned short* WTl = WT + (size_t)l * WT_PER_LAYER;
        float* sl0 = statacc + (size_t)(l * 3 + 0) * 512;
        float* sl1 = statacc + (size_t)(l * 3 + 1) * 512;
        float* sl2 = statacc + (size_t)(l * 3 + 2) * 512;
        // --- GINE aggregation ---
        k_gine_agg<<<N_NODES / 4, 256, 0, stream>>>(hb, h, ctb + (size_t)l * NCOMBO * D, eps, l,
                                                    row_ptr, sorted, aggb);
        // --- merged gw1 (relu, ->hid) + aw_in (->qkv) ---
        k_mm2_dual<<<dim3(10, N_NODES / 128), 256, 0, stream>>>(
            aggb, WTl + 0, gb1 + (size_t)l * D2, hid, D2, 4,
            hb, WTl + 262144, ab_in + (size_t)l * D3, qkv, D3, D);
        // --- flash attention (128 q rows / block) ---
        k_flash_mfma<<<dim3(NB * NH, S_PG / 128), 256, 0, stream>>>(qkv, ao);
        // --- merged gw2 (K=512, ->tmp1, stats sl0) + aw_out (K=256, ->tmp23, stats sl1) ---
        k_mm64_dual<<<dim3(4, N_NODES / 64), 256, 0, stream>>>(
            hid, WTl + 131072, gb2 + (size_t)l * D, h, tmp1, sl0, D2, 2,
            ao, WTl + 458752, ab_out + (size_t)l * D, h, tmp23, sl1, D);
        // --- combine bn1+bn2 (inline stats) ---
        k_bn12i<<<EW, 256, 0, stream>>>(tmp1, sl0, n1g + l * D, n1b + l * D,
                                        tmp23, sl1, n2g + l * D, n2b + l * D, bufB, bufBb);
        // --- MLP ---
        k_mm2<1, 0, 1, 0><<<dim3(D2 / 128, N_NODES / 128), 256, 0, stream>>>(
            bufBb, WTl + 524288, mb1 + (size_t)l * D2, nullptr, hid, nullptr, N_NODES, D2, D);
        k_mm64<0, 1, 0, 1><<<dim3(D / 128, N_NODES / 64), 256, 0, stream>>>(
            hid, WTl + 655360, mb2 + (size_t)l * D, bufB, tmp23, sl2, N_NODES, D, D2);
        k_bn_apply_i<<<EW, 256, 0, stream>>>(tmp23, sl2, n3g + l * D, n3b + l * D, h, hb);
    }
    k_pool<<<NB, 256, 0, stream>>>(h, g);
    k_final<<<NB, 256, 0, stream>>>(g, pw1, pb1, pw2, pb2, (float*)d_out);
}

// Round 10
// 904.277 us; speedup vs baseline: 6.8560x; 1.0054x over previous
//
#include <hip/hip_runtime.h>
#include <hip/hip_bf16.h>
#include <math.h>

#define N_NODES 16384
#define NB      32
#define S_PG    512
#define NE      262144
#define EPG     8192
#define D       256
#define D2      512
#define D3      768
#define NL      4
#define NH      4
#define DHD     64
#define OUTD    768
#define NCOMBO  264
#define WT_PER_LAYER 786432
#define INV_N   (1.0f / (float)N_NODES)
#define QSCALE  0.1803368801111244f   // 0.125 * log2(e)

typedef short s8v __attribute__((ext_vector_type(8)));
typedef float f4v __attribute__((ext_vector_type(4)));

__device__ __forceinline__ unsigned bfr(float f) {   // fp32 -> bf16 bits, RNE
    unsigned u = __float_as_uint(f);
    return (u + 0x7fffu + ((u >> 16) & 1u)) >> 16;
}
__device__ __forceinline__ float b2f(unsigned short u) {
    return __uint_as_float(((unsigned)u) << 16);
}

// ---------------- Atom encoder: h (f32) + hb (bf16) ----------------
__global__ __launch_bounds__(256) void k_atom_enc(const int* __restrict__ x,
                                                  const float* __restrict__ tab,
                                                  float* __restrict__ h,
                                                  unsigned short* __restrict__ hb) {
    int node = blockIdx.x * 4 + (threadIdx.x >> 6);
    int lane = threadIdx.x & 63;
    int dd = lane << 2;
    float4 acc = {0.f, 0.f, 0.f, 0.f};
#pragma unroll
    for (int f = 0; f < 9; ++f) {
        int v = x[node * 9 + f];
        const float4 t = *(const float4*)&tab[((size_t)(f * 119 + v)) * D + dd];
        acc.x += t.x; acc.y += t.y; acc.z += t.z; acc.w += t.w;
    }
    *(float4*)&h[(size_t)node * D + dd] = acc;
    ushort4 o;
    o.x = (unsigned short)bfr(acc.x); o.y = (unsigned short)bfr(acc.y);
    o.z = (unsigned short)bfr(acc.z); o.w = (unsigned short)bfr(acc.w);
    *(ushort4*)&hb[(size_t)node * D + dd] = o;
}

// ---------------- bw[l,fv,:] = bond_tab[fv,:] @ elin_w[l] ----------------
__global__ __launch_bounds__(256) void k_bondw(const float* __restrict__ bond_tab,
                                               const float* __restrict__ elin_w,
                                               float* __restrict__ bw) {
    int blk = blockIdx.x;         // L*66
    int l = blk / 66, fv = blk % 66;
    int dout = threadIdx.x;
    const float* tabrow = bond_tab + (size_t)fv * D;
    const float* w = elin_w + (size_t)l * D * D;
    float acc = 0.f;
    for (int d = 0; d < D; ++d) acc = fmaf(tabrow[d], w[d * D + dout], acc);
    bw[((size_t)l * 66 + fv) * D + dout] = acc;
}

// ---------------- combo table (bf16) ----------------
__global__ __launch_bounds__(256) void k_combo(const float* __restrict__ bw,
                                               const float* __restrict__ elin_b,
                                               unsigned short* __restrict__ ctb) {
    int b = blockIdx.x;           // NL*264
    int l = b / NCOMBO, cid = b % NCOMBO;
    int a0 = cid / 12, a1 = (cid % 12) / 2, a2 = cid & 1;
    int d = threadIdx.x;
    const float* bwl = bw + (size_t)l * 66 * D;
    float v = bwl[(size_t)a0 * D + d] + bwl[(size_t)(22 + a1) * D + d] +
              bwl[(size_t)(44 + a2) * D + d] + elin_b[(size_t)l * D + d];
    ctb[((size_t)l * NCOMBO + cid) * D + d] = (unsigned short)bfr(v);
}

// ---------------- CSR build ----------------
__global__ __launch_bounds__(256) void k_zero16k(int* __restrict__ p) {
    p[blockIdx.x * 256 + threadIdx.x] = 0;
}
__global__ __launch_bounds__(256) void k_zero_stats12(float* __restrict__ p) {
    for (int i = 0; i < 24; ++i) p[i * 256 + threadIdx.x] = 0.f;   // 12 slots x 512
}
__global__ __launch_bounds__(256) void k_hist(const int* __restrict__ dst, int* __restrict__ deg) {
    int e = blockIdx.x * 256 + threadIdx.x;
    atomicAdd(&deg[dst[e]], 1);
}
__global__ __launch_bounds__(256) void k_scan(const int* __restrict__ deg,
                                              int* __restrict__ row_ptr,
                                              int* __restrict__ cursor) {
    __shared__ int partial[256];
    int t = threadIdx.x;
    int base = t * 64;
    int s = 0;
    for (int i = 0; i < 64; ++i) s += deg[base + i];
    partial[t] = s;
    __syncthreads();
    for (int dstp = 1; dstp < 256; dstp <<= 1) {
        int v = (t >= dstp) ? partial[t - dstp] : 0;
        __syncthreads();
        partial[t] += v;
        __syncthreads();
    }
    int run = partial[t] - s;
    for (int i = 0; i < 64; ++i) {
        int dcur = deg[base + i];
        row_ptr[base + i] = run;
        cursor[base + i] = run;
        run += dcur;
    }
    if (t == 255) row_ptr[N_NODES] = run;
}
__global__ __launch_bounds__(256) void k_scatter(const int* __restrict__ src,
                                                 const int* __restrict__ dst,
                                                 const int* __restrict__ ea,
                                                 int* __restrict__ cursor,
                                                 int2* __restrict__ sorted) {
    int e = blockIdx.x * 256 + threadIdx.x;
    int d = dst[e];
    int pos = atomicAdd(&cursor[d], 1);
    int cid = ea[e * 3] * 12 + ea[e * 3 + 1] * 2 + ea[e * 3 + 2];
    sorted[pos] = make_int2(src[e], cid);
}

// ---------------- GINE aggregation (bf16 gather) ----------------
__global__ __launch_bounds__(256) void k_gine_agg(const unsigned short* __restrict__ hb,
                                                  const float* __restrict__ h,
                                                  const unsigned short* __restrict__ ctb,
                                                  const float* __restrict__ eps, int l,
                                                  const int* __restrict__ row_ptr,
                                                  const int2* __restrict__ sorted,
                                                  unsigned short* __restrict__ aggb) {
    int w = threadIdx.x >> 6;
    int lane = threadIdx.x & 63;
    int n = blockIdx.x * 4 + w;
    int dd = lane << 2;
    int beg = row_ptr[n], end = row_ptr[n + 1];
    float4 acc = {0.f, 0.f, 0.f, 0.f};
    int i = beg;
    for (; i + 2 <= end; i += 2) {
        int2 e0 = sorted[i];
        int2 e1 = sorted[i + 1];
        ushort4 h0 = *(const ushort4*)&hb[(size_t)e0.x * D + dd];
        ushort4 c0 = *(const ushort4*)&ctb[(size_t)e0.y * D + dd];
        ushort4 h1 = *(const ushort4*)&hb[(size_t)e1.x * D + dd];
        ushort4 c1 = *(const ushort4*)&ctb[(size_t)e1.y * D + dd];
        acc.x += fmaxf(b2f(h0.x) + b2f(c0.x), 0.f) + fmaxf(b2f(h1.x) + b2f(c1.x), 0.f);
        acc.y += fmaxf(b2f(h0.y) + b2f(c0.y), 0.f) + fmaxf(b2f(h1.y) + b2f(c1.y), 0.f);
        acc.z += fmaxf(b2f(h0.z) + b2f(c0.z), 0.f) + fmaxf(b2f(h1.z) + b2f(c1.z), 0.f);
        acc.w += fmaxf(b2f(h0.w) + b2f(c0.w), 0.f) + fmaxf(b2f(h1.w) + b2f(c1.w), 0.f);
    }
    if (i < end) {
        int2 e0 = sorted[i];
        ushort4 h0 = *(const ushort4*)&hb[(size_t)e0.x * D + dd];
        ushort4 c0 = *(const ushort4*)&ctb[(size_t)e0.y * D + dd];
        acc.x += fmaxf(b2f(h0.x) + b2f(c0.x), 0.f);
        acc.y += fmaxf(b2f(h0.y) + b2f(c0.y), 0.f);
        acc.z += fmaxf(b2f(h0.z) + b2f(c0.z), 0.f);
        acc.w += fmaxf(b2f(h0.w) + b2f(c0.w), 0.f);
    }
    float s1p = 1.f + eps[l];
    float4 hn = *(const float4*)&h[(size_t)n * D + dd];
    ushort4 o;
    o.x = (unsigned short)bfr(s1p * hn.x + acc.x);
    o.y = (unsigned short)bfr(s1p * hn.y + acc.y);
    o.z = (unsigned short)bfr(s1p * hn.z + acc.z);
    o.w = (unsigned short)bfr(s1p * hn.w + acc.w);
    *(ushort4*)&aggb[(size_t)n * D + dd] = o;
}

// ---------------- weight transpose+convert ----------------
__global__ __launch_bounds__(256) void k_wcvt(const float* __restrict__ gw1, const float* __restrict__ gw2,
                                              const float* __restrict__ aw_in, const float* __restrict__ aw_out,
                                              const float* __restrict__ mw1, const float* __restrict__ mw2,
                                              unsigned short* __restrict__ WT) {
    const int KS[6]   = {256, 512, 256, 256, 256, 512};
    const int NS[6]   = {512, 256, 768, 256, 512, 256};
    const int TOFF[7] = {0, 128, 256, 448, 512, 640, 768};
    const int DOFF[6] = {0, 131072, 262144, 458752, 524288, 655360};
    int b = blockIdx.x;
    int l = b / 768, wb = b % 768;
    int widx = 0;
    while (wb >= TOFF[widx + 1]) ++widx;
    int t = wb - TOFF[widx];
    int K = KS[widx], N = NS[widx];
    int nn = N / 32;
    int kt = t / nn, nt = t % nn;
    const float* srcs[6] = {gw1, gw2, aw_in, aw_out, mw1, mw2};
    const float* W = srcs[widx] + (size_t)l * K * N;
    unsigned short* WTp = WT + (size_t)l * WT_PER_LAYER + DOFF[widx];
    __shared__ float tile[32][33];
    int tid = threadIdx.x;
    int r = tid >> 3, c4 = (tid & 7) << 2;
    float4 v = *(const float4*)&W[(size_t)(kt * 32 + r) * N + nt * 32 + c4];
    tile[r][c4] = v.x; tile[r][c4 + 1] = v.y; tile[r][c4 + 2] = v.z; tile[r][c4 + 3] = v.w;
    __syncthreads();
    int nr = tid >> 3, kc = (tid & 7) << 2;
    ushort4 o;
    o.x = (unsigned short)bfr(tile[kc + 0][nr]);
    o.y = (unsigned short)bfr(tile[kc + 1][nr]);
    o.z = (unsigned short)bfr(tile[kc + 2][nr]);
    o.w = (unsigned short)bfr(tile[kc + 3][nr]);
    *(ushort4*)&WTp[(size_t)(nt * 32 + nr) * K + kt * 32 + kc] = o;
}

// ---------------- BM=128 bf16 MFMA GEMM (single) ----------------
template<int RELU, int RES, int OBF, int STAT>
__global__ __launch_bounds__(256) void k_mm2(const unsigned short* __restrict__ A,
                                             const unsigned short* __restrict__ BT,
                                             const float* __restrict__ bias,
                                             const float* __restrict__ res,
                                             void* __restrict__ Cp,
                                             float* __restrict__ stat,
                                             int M, int N, int K) {
    __shared__ unsigned short As[128 * 64];
    __shared__ unsigned short Bs[128 * 64];
    const int tid = threadIdx.x;
    const int row0 = blockIdx.y * 128, col0 = blockIdx.x * 128;
    const int w = tid >> 6, l = tid & 63;
    const int wm = w >> 1, wn = w & 1;
    const int lr = l & 15, lq = l >> 4;
    const int srow = l >> 3;
    const int scol = (l & 7) * 8;
    f4v acc[4][4] = {};

    const unsigned short* Ag = A + (size_t)(row0 + w * 32 + srow) * K + scol;
    const unsigned short* Bg = BT + (size_t)(col0 + w * 32 + srow) * K + scol;
    unsigned short* Al = &As[(w * 32) * 64];
    unsigned short* Bl = &Bs[(w * 32) * 64];

    for (int k0 = 0; k0 < K; k0 += 64) {
#pragma unroll
        for (int it = 0; it < 4; ++it) {
            __builtin_amdgcn_global_load_lds(
                (const __attribute__((address_space(1))) unsigned*)(Ag + (size_t)(it * 8) * K + k0),
                (__attribute__((address_space(3))) unsigned*)(Al + it * 8 * 64), 16, 0, 0);
            __builtin_amdgcn_global_load_lds(
                (const __attribute__((address_space(1))) unsigned*)(Bg + (size_t)(it * 8) * K + k0),
                (__attribute__((address_space(3))) unsigned*)(Bl + it * 8 * 64), 16, 0, 0);
        }
        asm volatile("s_waitcnt vmcnt(0)" ::: "memory");
        __syncthreads();
#pragma unroll
        for (int kk = 0; kk < 2; ++kk) {
            s8v af[4], bf[4];
#pragma unroll
            for (int m = 0; m < 4; ++m)
                af[m] = *(const s8v*)&As[(wm * 64 + m * 16 + lr) * 64 + kk * 32 + lq * 8];
#pragma unroll
            for (int n = 0; n < 4; ++n)
                bf[n] = *(const s8v*)&Bs[(wn * 64 + n * 16 + lr) * 64 + kk * 32 + lq * 8];
#pragma unroll
            for (int m = 0; m < 4; ++m)
#pragma unroll
                for (int n = 0; n < 4; ++n)
                    acc[m][n] = __builtin_amdgcn_mfma_f32_16x16x32_bf16(af[m], bf[n], acc[m][n], 0, 0, 0);
        }
        __syncthreads();
    }
    float cs[4], cs2[4];
#pragma unroll
    for (int n = 0; n < 4; ++n) { cs[n] = 0.f; cs2[n] = 0.f; }
#pragma unroll
    for (int n = 0; n < 4; ++n) {
        int c = col0 + wn * 64 + n * 16 + lr;
        float bv = bias[c];
#pragma unroll
        for (int m = 0; m < 4; ++m) {
#pragma unroll
            for (int j = 0; j < 4; ++j) {
                int r = row0 + wm * 64 + m * 16 + lq * 4 + j;
                float v = acc[m][n][j] + bv;
                if (RES) v += res[(size_t)r * N + c];
                if (STAT) { cs[n] += v; cs2[n] += v * v; }
                if (RELU) v = fmaxf(v, 0.f);
                if (OBF) ((unsigned short*)Cp)[(size_t)r * N + c] = (unsigned short)bfr(v);
                else ((float*)Cp)[(size_t)r * N + c] = v;
            }
        }
    }
    if (STAT) {
#pragma unroll
        for (int n = 0; n < 4; ++n) {
            float s = cs[n], s2 = cs2[n];
            s += __shfl_xor(s, 16);  s2 += __shfl_xor(s2, 16);
            s += __shfl_xor(s, 32);  s2 += __shfl_xor(s2, 32);
            if (lq == 0) {
                int c = col0 + wn * 64 + n * 16 + lr;
                atomicAdd(&stat[c], s);
                atomicAdd(&stat[256 + c], s2);
            }
        }
    }
}

// ---------------- dual GEMM dispatch (BM=128): gw1 (relu) + aw_in (Q prescaled) ----------------
__global__ __launch_bounds__(256) void k_mm2_dual(const unsigned short* __restrict__ A1,
                                                  const unsigned short* __restrict__ B1,
                                                  const float* __restrict__ bias1,
                                                  unsigned short* __restrict__ C1, int N1, int nb1,
                                                  const unsigned short* __restrict__ A2,
                                                  const unsigned short* __restrict__ B2,
                                                  const float* __restrict__ bias2,
                                                  unsigned short* __restrict__ C2, int N2,
                                                  int K) {
    __shared__ unsigned short As[128 * 64];
    __shared__ unsigned short Bs[128 * 64];
    const unsigned short* A; const unsigned short* BT; const float* bias;
    unsigned short* C; int N, cb, relu;
    if ((int)blockIdx.x < nb1) { A = A1; BT = B1; bias = bias1; C = C1; N = N1; cb = blockIdx.x; relu = 1; }
    else { A = A2; BT = B2; bias = bias2; C = C2; N = N2; cb = blockIdx.x - nb1; relu = 0; }
    const int tid = threadIdx.x;
    const int row0 = blockIdx.y * 128, col0 = cb * 128;
    const int w = tid >> 6, l = tid & 63;
    const int wm = w >> 1, wn = w & 1;
    const int lr = l & 15, lq = l >> 4;
    const int srow = l >> 3;
    const int scol = (l & 7) * 8;
    f4v acc[4][4] = {};

    const unsigned short* Ag = A + (size_t)(row0 + w * 32 + srow) * K + scol;
    const unsigned short* Bg = BT + (size_t)(col0 + w * 32 + srow) * K + scol;
    unsigned short* Al = &As[(w * 32) * 64];
    unsigned short* Bl = &Bs[(w * 32) * 64];

    for (int k0 = 0; k0 < K; k0 += 64) {
#pragma unroll
        for (int it = 0; it < 4; ++it) {
            __builtin_amdgcn_global_load_lds(
                (const __attribute__((address_space(1))) unsigned*)(Ag + (size_t)(it * 8) * K + k0),
                (__attribute__((address_space(3))) unsigned*)(Al + it * 8 * 64), 16, 0, 0);
            __builtin_amdgcn_global_load_lds(
                (const __attribute__((address_space(1))) unsigned*)(Bg + (size_t)(it * 8) * K + k0),
                (__attribute__((address_space(3))) unsigned*)(Bl + it * 8 * 64), 16, 0, 0);
        }
        asm volatile("s_waitcnt vmcnt(0)" ::: "memory");
        __syncthreads();
#pragma unroll
        for (int kk = 0; kk < 2; ++kk) {
            s8v af[4], bf[4];
#pragma unroll
            for (int m = 0; m < 4; ++m)
                af[m] = *(const s8v*)&As[(wm * 64 + m * 16 + lr) * 64 + kk * 32 + lq * 8];
#pragma unroll
            for (int n = 0; n < 4; ++n)
                bf[n] = *(const s8v*)&Bs[(wn * 64 + n * 16 + lr) * 64 + kk * 32 + lq * 8];
#pragma unroll
            for (int m = 0; m < 4; ++m)
#pragma unroll
                for (int n = 0; n < 4; ++n)
                    acc[m][n] = __builtin_amdgcn_mfma_f32_16x16x32_bf16(af[m], bf[n], acc[m][n], 0, 0, 0);
        }
        __syncthreads();
    }
#pragma unroll
    for (int n = 0; n < 4; ++n) {
        int c = col0 + wn * 64 + n * 16 + lr;
        float bv = bias[c];
#pragma unroll
        for (int m = 0; m < 4; ++m) {
#pragma unroll
            for (int j = 0; j < 4; ++j) {
                int r = row0 + wm * 64 + m * 16 + lq * 4 + j;
                float v = acc[m][n][j] + bv;
                if (relu) v = fmaxf(v, 0.f);
                else if (c < 256) v *= QSCALE;      // Q columns: fold 0.125*log2(e)
                C[(size_t)r * N + c] = (unsigned short)bfr(v);
            }
        }
    }
}

// ---------------- BM=64 bf16 MFMA GEMM (single, N=256 shapes) ----------------
template<int RELU, int RES, int OBF, int STAT>
__global__ __launch_bounds__(256) void k_mm64(const unsigned short* __restrict__ A,
                                              const unsigned short* __restrict__ BT,
                                              const float* __restrict__ bias,
                                              const float* __restrict__ res,
                                              void* __restrict__ Cp,
                                              float* __restrict__ stat,
                                              int M, int N, int K) {
    __shared__ unsigned short As[64 * 64];
    __shared__ unsigned short Bs[128 * 64];
    const int tid = threadIdx.x;
    const int row0 = blockIdx.y * 64, col0 = blockIdx.x * 128;
    const int w = tid >> 6, l = tid & 63;
    const int wn = w;
    const int lr = l & 15, lq = l >> 4;
    const int srow = l >> 3;
    const int scol = (l & 7) * 8;
    f4v acc[4][2] = {};

    const unsigned short* Ag = A + (size_t)(row0 + w * 16 + srow) * K + scol;
    const unsigned short* Bg = BT + (size_t)(col0 + w * 32 + srow) * K + scol;
    unsigned short* Al = &As[(w * 16) * 64];
    unsigned short* Bl = &Bs[(w * 32) * 64];

    for (int k0 = 0; k0 < K; k0 += 64) {
#pragma unroll
        for (int it = 0; it < 2; ++it)
            __builtin_amdgcn_global_load_lds(
                (const __attribute__((address_space(1))) unsigned*)(Ag + (size_t)(it * 8) * K + k0),
                (__attribute__((address_space(3))) unsigned*)(Al + it * 8 * 64), 16, 0, 0);
#pragma unroll
        for (int it = 0; it < 4; ++it)
            __builtin_amdgcn_global_load_lds(
                (const __attribute__((address_space(1))) unsigned*)(Bg + (size_t)(it * 8) * K + k0),
                (__attribute__((address_space(3))) unsigned*)(Bl + it * 8 * 64), 16, 0, 0);
        asm volatile("s_waitcnt vmcnt(0)" ::: "memory");
        __syncthreads();
#pragma unroll
        for (int kk = 0; kk < 2; ++kk) {
            s8v af[4], bf[2];
#pragma unroll
            for (int m = 0; m < 4; ++m)
                af[m] = *(const s8v*)&As[(m * 16 + lr) * 64 + kk * 32 + lq * 8];
#pragma unroll
            for (int n = 0; n < 2; ++n)
                bf[n] = *(const s8v*)&Bs[(wn * 32 + n * 16 + lr) * 64 + kk * 32 + lq * 8];
#pragma unroll
            for (int m = 0; m < 4; ++m)
#pragma unroll
                for (int n = 0; n < 2; ++n)
                    acc[m][n] = __builtin_amdgcn_mfma_f32_16x16x32_bf16(af[m], bf[n], acc[m][n], 0, 0, 0);
        }
        __syncthreads();
    }
    float cs[2], cs2[2];
#pragma unroll
    for (int n = 0; n < 2; ++n) { cs[n] = 0.f; cs2[n] = 0.f; }
#pragma unroll
    for (int n = 0; n < 2; ++n) {
        int c = col0 + wn * 32 + n * 16 + lr;
        float bv = bias[c];
#pragma unroll
        for (int m = 0; m < 4; ++m) {
#pragma unroll
            for (int j = 0; j < 4; ++j) {
                int r = row0 + m * 16 + lq * 4 + j;
                float v = acc[m][n][j] + bv;
                if (RES) v += res[(size_t)r * N + c];
                if (STAT) { cs[n] += v; cs2[n] += v * v; }
                if (RELU) v = fmaxf(v, 0.f);
                if (OBF) ((unsigned short*)Cp)[(size_t)r * N + c] = (unsigned short)bfr(v);
                else ((float*)Cp)[(size_t)r * N + c] = v;
            }
        }
    }
    if (STAT) {
#pragma unroll
        for (int n = 0; n < 2; ++n) {
            float s = cs[n], s2 = cs2[n];
            s += __shfl_xor(s, 16);  s2 += __shfl_xor(s2, 16);
            s += __shfl_xor(s, 32);  s2 += __shfl_xor(s2, 32);
            if (lq == 0) {
                int c = col0 + wn * 32 + n * 16 + lr;
                atomicAdd(&stat[c], s);
                atomicAdd(&stat[256 + c], s2);
            }
        }
    }
}

// ---------------- dual BM=64 GEMM: gw2 (K=512) + aw_out (K=256), both RES+STAT, f32 out ----------------
__global__ __launch_bounds__(256) void k_mm64_dual(const unsigned short* __restrict__ A1,
                                                   const unsigned short* __restrict__ B1,
                                                   const float* __restrict__ bias1,
                                                   const float* __restrict__ res1,
                                                   float* __restrict__ C1,
                                                   float* __restrict__ stat1, int K1, int nb1,
                                                   const unsigned short* __restrict__ A2,
                                                   const unsigned short* __restrict__ B2,
                                                   const float* __restrict__ bias2,
                                                   const float* __restrict__ res2,
                                                   float* __restrict__ C2,
                                                   float* __restrict__ stat2, int K2) {
    __shared__ unsigned short As[64 * 64];
    __shared__ unsigned short Bs[128 * 64];
    const unsigned short *A, *BT; const float *bias, *res; float *C, *stat;
    int K, cb;
    if ((int)blockIdx.x < nb1) { A = A1; BT = B1; bias = bias1; res = res1; C = C1; stat = stat1; K = K1; cb = blockIdx.x; }
    else { A = A2; BT = B2; bias = bias2; res = res2; C = C2; stat = stat2; K = K2; cb = blockIdx.x - nb1; }
    const int N = 256;
    const int tid = threadIdx.x;
    const int row0 = blockIdx.y * 64, col0 = cb * 128;
    const int w = tid >> 6, l = tid & 63;
    const int wn = w;
    const int lr = l & 15, lq = l >> 4;
    const int srow = l >> 3;
    const int scol = (l & 7) * 8;
    f4v acc[4][2] = {};

    const unsigned short* Ag = A + (size_t)(row0 + w * 16 + srow) * K + scol;
    const unsigned short* Bg = BT + (size_t)(col0 + w * 32 + srow) * K + scol;
    unsigned short* Al = &As[(w * 16) * 64];
    unsigned short* Bl = &Bs[(w * 32) * 64];

    for (int k0 = 0; k0 < K; k0 += 64) {
#pragma unroll
        for (int it = 0; it < 2; ++it)
            __builtin_amdgcn_global_load_lds(
                (const __attribute__((address_space(1))) unsigned*)(Ag + (size_t)(it * 8) * K + k0),
                (__attribute__((address_space(3))) unsigned*)(Al + it * 8 * 64), 16, 0, 0);
#pragma unroll
        for (int it = 0; it < 4; ++it)
            __builtin_amdgcn_global_load_lds(
                (const __attribute__((address_space(1))) unsigned*)(Bg + (size_t)(it * 8) * K + k0),
                (__attribute__((address_space(3))) unsigned*)(Bl + it * 8 * 64), 16, 0, 0);
        asm volatile("s_waitcnt vmcnt(0)" ::: "memory");
        __syncthreads();
#pragma unroll
        for (int kk = 0; kk < 2; ++kk) {
            s8v af[4], bf[2];
#pragma unroll
            for (int m = 0; m < 4; ++m)
                af[m] = *(const s8v*)&As[(m * 16 + lr) * 64 + kk * 32 + lq * 8];
#pragma unroll
            for (int n = 0; n < 2; ++n)
                bf[n] = *(const s8v*)&Bs[(wn * 32 + n * 16 + lr) * 64 + kk * 32 + lq * 8];
#pragma unroll
            for (int m = 0; m < 4; ++m)
#pragma unroll
                for (int n = 0; n < 2; ++n)
                    acc[m][n] = __builtin_amdgcn_mfma_f32_16x16x32_bf16(af[m], bf[n], acc[m][n], 0, 0, 0);
        }
        __syncthreads();
    }
    float cs[2], cs2[2];
#pragma unroll
    for (int n = 0; n < 2; ++n) { cs[n] = 0.f; cs2[n] = 0.f; }
#pragma unroll
    for (int n = 0; n < 2; ++n) {
        int c = col0 + wn * 32 + n * 16 + lr;
        float bv = bias[c];
#pragma unroll
        for (int m = 0; m < 4; ++m) {
#pragma unroll
            for (int j = 0; j < 4; ++j) {
                int r = row0 + m * 16 + lq * 4 + j;
                float v = acc[m][n][j] + bv + res[(size_t)r * N + c];
                cs[n] += v; cs2[n] += v * v;
                C[(size_t)r * N + c] = v;
            }
        }
    }
#pragma unroll
    for (int n = 0; n < 2; ++n) {
        float s = cs[n], s2 = cs2[n];
        s += __shfl_xor(s, 16);  s2 += __shfl_xor(s2, 16);
        s += __shfl_xor(s, 32);  s2 += __shfl_xor(s2, 32);
        if (lq == 0) {
            int c = col0 + wn * 32 + n * 16 + lr;
            atomicAdd(&stat[c], s);
            atomicAdd(&stat[256 + c], s2);
        }
    }
}

// ---------------- fused: y = bn1(t1) + bn2(t2), inline stats, dual write ----------------
__global__ __launch_bounds__(256) void k_bn12i(const float* __restrict__ t1,
                                               const float* __restrict__ sa1,
                                               const float* __restrict__ g1,
                                               const float* __restrict__ b1,
                                               const float* __restrict__ t2,
                                               const float* __restrict__ sa2,
                                               const float* __restrict__ g2,
                                               const float* __restrict__ b2,
                                               float* __restrict__ y,
                                               unsigned short* __restrict__ yb) {
    size_t i4 = (size_t)blockIdx.x * blockDim.x + threadIdx.x;
    int c = (int)((i4 & 63) << 2);
    float a1[4], a2[4], o[4];
    *(float4*)a1 = ((const float4*)t1)[i4];
    *(float4*)a2 = ((const float4*)t2)[i4];
#pragma unroll
    for (int q = 0; q < 4; ++q) {
        int cc = c + q;
        float m1 = sa1[cc] * INV_N;
        float r1 = rsqrtf(sa1[256 + cc] * INV_N - m1 * m1 + 1e-5f);
        float m2 = sa2[cc] * INV_N;
        float r2 = rsqrtf(sa2[256 + cc] * INV_N - m2 * m2 + 1e-5f);
        o[q] = (a1[q] - m1) * r1 * g1[cc] + b1[cc] + (a2[q] - m2) * r2 * g2[cc] + b2[cc];
    }
    ((float4*)y)[i4] = *(float4*)o;
    ushort4 ob;
    ob.x = (unsigned short)bfr(o[0]); ob.y = (unsigned short)bfr(o[1]);
    ob.z = (unsigned short)bfr(o[2]); ob.w = (unsigned short)bfr(o[3]);
    ((ushort4*)yb)[i4] = ob;
}

// ---------------- bn apply (single), inline stats, dual write ----------------
__global__ __launch_bounds__(256) void k_bn_apply_i(const float* __restrict__ x,
                                                    const float* __restrict__ sa,
                                                    const float* __restrict__ g,
                                                    const float* __restrict__ b,
                                                    float* __restrict__ y,
                                                    unsigned short* __restrict__ yb) {
    size_t i4 = (size_t)blockIdx.x * blockDim.x + threadIdx.x;
    int c = (int)((i4 & 63) << 2);
    float a[4], o[4];
    *(float4*)a = ((const float4*)x)[i4];
#pragma unroll
    for (int q = 0; q < 4; ++q) {
        int cc = c + q;
        float m = sa[cc] * INV_N;
        float r = rsqrtf(sa[256 + cc] * INV_N - m * m + 1e-5f);
        o[q] = (a[q] - m) * r * g[cc] + b[cc];
    }
    ((float4*)y)[i4] = *(float4*)o;
    ushort4 ob;
    ob.x = (unsigned short)bfr(o[0]); ob.y = (unsigned short)bfr(o[1]);
    ob.z = (unsigned short)bfr(o[2]); ob.w = (unsigned short)bfr(o[3]);
    ((ushort4*)yb)[i4] = ob;
}

// ---------------- MFMA flash attention: 128 q-rows per block, base-2 softmax ----------------
__global__ __launch_bounds__(256) void k_flash_mfma(const unsigned short* __restrict__ qkv,
                                                    unsigned short* __restrict__ ao) {
    __shared__ unsigned short Ks[64][72];
    __shared__ unsigned short VT[64][72];
    __shared__ unsigned short Ps[4][2][16][72];
    const int bh = blockIdx.x;
    const int b = bh >> 2, hh = bh & 3;
    const int i0 = blockIdx.y << 7;              // 128 q rows
    const int tid = threadIdx.x;
    const int w = tid >> 6, l = tid & 63;
    const int lr = l & 15, lq = l >> 4;
    const int hd = hh * DHD;
    const size_t rowbase = (size_t)(b * S_PG) * D3;

    s8v aq[2][2];
#pragma unroll
    for (int g = 0; g < 2; ++g) {
        const unsigned short* qrow = &qkv[rowbase + (size_t)(i0 + g * 64 + w * 16 + lr) * D3 + hd + lq * 8];
        aq[g][0] = *(const s8v*)&qrow[0];
        aq[g][1] = *(const s8v*)&qrow[32];
    }

    float mrow[2][4], lrow[2][4];
    f4v oacc[2][4] = {};
#pragma unroll
    for (int g = 0; g < 2; ++g)
#pragma unroll
        for (int j = 0; j < 4; ++j) { mrow[g][j] = -INFINITY; lrow[g][j] = 0.f; }

    const int skv = tid >> 2;                  // K staging: kv row 0..63
    const int sd0 = (tid & 3) << 4;            // K staging: d segment
    const int d0v = (tid >> 4) << 2;           // V staging: d block
    const int kv0 = (tid & 15) << 2;           // V staging: kv block

    for (int j0 = 0; j0 < S_PG; j0 += 64) {
        __syncthreads();
        {
            const unsigned short* kr = &qkv[rowbase + (size_t)(j0 + skv) * D3 + D + hd + sd0];
            *(uint4*)&Ks[skv][sd0]     = *(const uint4*)&kr[0];
            *(uint4*)&Ks[skv][sd0 + 8] = *(const uint4*)&kr[8];
            unsigned short vv[4][4];
#pragma unroll
            for (int i = 0; i < 4; ++i) {
                uint2 lv = *(const uint2*)&qkv[rowbase + (size_t)(j0 + kv0 + i) * D3 + D2 + hd + d0v];
                vv[i][0] = (unsigned short)(lv.x & 0xffffu);
                vv[i][1] = (unsigned short)(lv.x >> 16);
                vv[i][2] = (unsigned short)(lv.y & 0xffffu);
                vv[i][3] = (unsigned short)(lv.y >> 16);
            }
#pragma unroll
            for (int i2 = 0; i2 < 4; ++i2) {
                ushort4 o4;
                o4.x = vv[0][i2]; o4.y = vv[1][i2]; o4.z = vv[2][i2]; o4.w = vv[3][i2];
                *(ushort4*)&VT[d0v + i2][kv0] = o4;
            }
        }
        __syncthreads();
#pragma unroll
        for (int g = 0; g < 2; ++g) {
            f4v sc[4] = {};
#pragma unroll
            for (int nt = 0; nt < 4; ++nt) {
                s8v bk0 = *(const s8v*)&Ks[nt * 16 + lr][lq * 8];
                s8v bk1 = *(const s8v*)&Ks[nt * 16 + lr][32 + lq * 8];
                sc[nt] = __builtin_amdgcn_mfma_f32_16x16x32_bf16(aq[g][0], bk0, sc[nt], 0, 0, 0);
                sc[nt] = __builtin_amdgcn_mfma_f32_16x16x32_bf16(aq[g][1], bk1, sc[nt], 0, 0, 0);
            }
            float ps[4][4], alpha[4];
#pragma unroll
            for (int j = 0; j < 4; ++j) {
#pragma unroll
                for (int nt = 0; nt < 4; ++nt) ps[nt][j] = sc[nt][j];   // Q pre-scaled by 0.125*log2e
                float pm = fmaxf(fmaxf(ps[0][j], ps[1][j]), fmaxf(ps[2][j], ps[3][j]));
#pragma unroll
                for (int off = 1; off < 16; off <<= 1) pm = fmaxf(pm, __shfl_xor(pm, off));
                float mn = fmaxf(mrow[g][j], pm);
                alpha[j] = exp2f(mrow[g][j] - mn);
                float rs = 0.f;
#pragma unroll
                for (int nt = 0; nt < 4; ++nt) { ps[nt][j] = exp2f(ps[nt][j] - mn); rs += ps[nt][j]; }
#pragma unroll
                for (int off = 1; off < 16; off <<= 1) rs += __shfl_xor(rs, off);
                lrow[g][j] = lrow[g][j] * alpha[j] + rs;
                mrow[g][j] = mn;
            }
#pragma unroll
            for (int nt = 0; nt < 4; ++nt)
#pragma unroll
                for (int j = 0; j < 4; ++j)
                    Ps[w][g][lq * 4 + j][nt * 16 + lr] = (unsigned short)bfr(ps[nt][j]);
#pragma unroll
            for (int ntd = 0; ntd < 4; ++ntd)
#pragma unroll
                for (int j = 0; j < 4; ++j) oacc[g][ntd][j] *= alpha[j];
            s8v pa0 = *(const s8v*)&Ps[w][g][lr][lq * 8];
            s8v pa1 = *(const s8v*)&Ps[w][g][lr][32 + lq * 8];
#pragma unroll
            for (int ntd = 0; ntd < 4; ++ntd) {
                s8v bv0 = *(const s8v*)&VT[ntd * 16 + lr][lq * 8];
                s8v bv1 = *(const s8v*)&VT[ntd * 16 + lr][32 + lq * 8];
                oacc[g][ntd] = __builtin_amdgcn_mfma_f32_16x16x32_bf16(pa0, bv0, oacc[g][ntd], 0, 0, 0);
                oacc[g][ntd] = __builtin_amdgcn_mfma_f32_16x16x32_bf16(pa1, bv1, oacc[g][ntd], 0, 0, 0);
            }
        }
    }
#pragma unroll
    for (int g = 0; g < 2; ++g)
#pragma unroll
        for (int j = 0; j < 4; ++j) {
            float inv = 1.f / lrow[g][j];
            int node = b * S_PG + i0 + g * 64 + w * 16 + lq * 4 + j;
#pragma unroll
            for (int ntd = 0; ntd < 4; ++ntd)
                ao[(size_t)node * D + hd + ntd * 16 + lr] = (unsigned short)bfr(oacc[g][ntd][j] * inv);
        }
}

// ---------------- mean pool per graph (parallel: 32x8 blocks) ----------------
__global__ __launch_bounds__(256) void k_pool2(const float* __restrict__ h, float* __restrict__ g) {
    __shared__ float red[8][33];
    int b = blockIdx.x, cc = blockIdx.y;             // column chunk of 32
    int col = threadIdx.x & 31, rg = threadIdx.x >> 5;  // 8 row groups of 64
    const float* p = h + ((size_t)(b * S_PG + rg * 64)) * D + cc * 32 + col;
    float s = 0.f;
    for (int r = 0; r < 64; ++r) s += p[(size_t)r * D];
    red[rg][col] = s;
    __syncthreads();
    if (rg == 0) {
        float t = 0.f;
#pragma unroll
        for (int i = 0; i < 8; ++i) t += red[i][col];
        g[b * D + cc * 32 + col] = t * (1.f / (float)S_PG);
    }
}

// ---------------- final head, stage A: z chunk + sumsq partial (grid 32x3) ----------------
__global__ __launch_bounds__(256) void k_final_a(const float* __restrict__ g,
                                                 const float* __restrict__ pw1,
                                                 const float* __restrict__ pb1,
                                                 const float* __restrict__ pw2,
                                                 const float* __restrict__ pb2,
                                                 float* __restrict__ z,
                                                 float* __restrict__ zpart) {
    __shared__ float gs[D];
    __shared__ float ts[D];
    __shared__ float red[4];
    int b = blockIdx.x, ch = blockIdx.y, tid = threadIdx.x;
    gs[tid] = g[b * D + tid];
    __syncthreads();
    float acc = pb1[tid];
    for (int d = 0; d < D; ++d) acc = fmaf(gs[d], pw1[d * D + tid], acc);
    ts[tid] = fmaxf(acc, 0.f);
    __syncthreads();
    int j = ch * 256 + tid;
    float a = pb2[j];
    for (int d = 0; d < D; ++d) a = fmaf(ts[d], pw2[(size_t)d * OUTD + j], a);
    z[b * OUTD + j] = a;
    float ss = a * a;
#pragma unroll
    for (int o = 32; o >= 1; o >>= 1) ss += __shfl_xor(ss, o);
    if ((tid & 63) == 0) red[tid >> 6] = ss;
    __syncthreads();
    if (tid == 0) zpart[b * 3 + ch] = red[0] + red[1] + red[2] + red[3];
}

// ---------------- final head, stage B: normalize (grid 32x3) ----------------
__global__ __launch_bounds__(256) void k_final_b(const float* __restrict__ z,
                                                 const float* __restrict__ zpart,
                                                 float* __restrict__ out) {
    int b = blockIdx.x, ch = blockIdx.y, tid = threadIdx.x;
    float rn = rsqrtf(zpart[b * 3] + zpart[b * 3 + 1] + zpart[b * 3 + 2]);
    int j = ch * 256 + tid;
    out[b * OUTD + j] = z[b * OUTD + j] * rn;
}

extern "C" void kernel_launch(void* const* d_in, const int* in_sizes, int n_in,
                              void* d_out, int out_size, void* d_ws, size_t ws_size,
                              hipStream_t stream) {
    const int* x        = (const int*)d_in[0];
    const int* ea       = (const int*)d_in[1];
    const int* eidx     = (const int*)d_in[2];
    const float* atom_tab = (const float*)d_in[4];
    const float* bond_tab = (const float*)d_in[5];
    const float* elin_w = (const float*)d_in[6];
    const float* elin_b = (const float*)d_in[7];
    const float* eps    = (const float*)d_in[8];
    const float* gw1    = (const float*)d_in[9];
    const float* gb1    = (const float*)d_in[10];
    const float* gw2    = (const float*)d_in[11];
    const float* gb2    = (const float*)d_in[12];
    const float* aw_in  = (const float*)d_in[13];
    const float* ab_in  = (const float*)d_in[14];
    const float* aw_out = (const float*)d_in[15];
    const float* ab_out = (const float*)d_in[16];
    const float* n1g    = (const float*)d_in[17];
    const float* n1b    = (const float*)d_in[18];
    const float* n2g    = (const float*)d_in[19];
    const float* n2b    = (const float*)d_in[20];
    const float* n3g    = (const float*)d_in[21];
    const float* n3b    = (const float*)d_in[22];
    const float* mw1    = (const float*)d_in[23];
    const float* mb1    = (const float*)d_in[24];
    const float* mw2    = (const float*)d_in[25];
    const float* mb2    = (const float*)d_in[26];
    const float* pw1    = (const float*)d_in[27];
    const float* pb1    = (const float*)d_in[28];
    const float* pw2    = (const float*)d_in[29];
    const float* pb2    = (const float*)d_in[30];

    char* ws = (char*)d_ws;
    size_t off = 0;
    auto alloc = [&](size_t bytes) {
        void* p = ws + off;
        off += (bytes + 255) & ~(size_t)255;
        return p;
    };
    float*  h    = (float*)alloc((size_t)N_NODES * D * 4);
    float*  bufB = (float*)alloc((size_t)N_NODES * D * 4);
    float*  tmp1 = (float*)alloc((size_t)N_NODES * D * 4);
    unsigned short* hb = (unsigned short*)alloc((size_t)N_NODES * D * 2);
    char*   U    = (char*)alloc((size_t)N_NODES * D3 * 2);
    unsigned short* bfA = (unsigned short*)alloc((size_t)N_NODES * D3 * 2);
    unsigned short* WT  = (unsigned short*)alloc((size_t)NL * WT_PER_LAYER * 2);
    float*  bw   = (float*)alloc((size_t)NL * 66 * D * 4);
    unsigned short* ctb = (unsigned short*)alloc((size_t)NL * NCOMBO * D * 2);
    int*    deg  = (int*)alloc((size_t)N_NODES * 4);
    int*    row_ptr = (int*)alloc((size_t)(N_NODES + 1) * 4);
    int*    cursor  = (int*)alloc((size_t)N_NODES * 4);
    int2*   sorted  = (int2*)alloc((size_t)NE * 8);
    float*  statacc = (float*)alloc((size_t)12 * 512 * 4);   // 12 per-layer slots [sum|sum2]
    float*  g    = (float*)alloc((size_t)NB * D * 4);
    float*  z    = (float*)alloc((size_t)NB * OUTD * 4);
    float*  zpart = (float*)alloc((size_t)NB * 3 * 4);
    (void)ws_size; (void)in_sizes; (void)n_in; (void)out_size;

    float* tmp23 = (float*)U;
    unsigned short* qkv = (unsigned short*)U;
    unsigned short* aggb  = bfA;
    unsigned short* ao    = bfA;
    unsigned short* bufBb = bfA;
    unsigned short* hid   = bfA + (size_t)N_NODES * D;

    const int* srcp = eidx;
    const int* dstp = eidx + NE;
    const int EW = N_NODES * D / 1024;

    k_zero16k<<<N_NODES / 256, 256, 0, stream>>>(deg);
    k_zero_stats12<<<1, 256, 0, stream>>>(statacc);
    k_hist<<<NE / 256, 256, 0, stream>>>(dstp, deg);
    k_scan<<<1, 256, 0, stream>>>(deg, row_ptr, cursor);
    k_scatter<<<NE / 256, 256, 0, stream>>>(srcp, dstp, ea, cursor, sorted);
    k_atom_enc<<<N_NODES / 4, 256, 0, stream>>>(x, atom_tab, h, hb);
    k_bondw<<<NL * 66, 256, 0, stream>>>(bond_tab, elin_w, bw);
    k_combo<<<NL * NCOMBO, 256, 0, stream>>>(bw, elin_b, ctb);
    k_wcvt<<<NL * 768, 256, 0, stream>>>(gw1, gw2, aw_in, aw_out, mw1, mw2, WT);

    for (int l = 0; l < NL; ++l) {
        const unsigned short* WTl = WT + (size_t)l * WT_PER_LAYER;
        float* sl0 = statacc + (size_t)(l * 3 + 0) * 512;
        float* sl1 = statacc + (size_t)(l * 3 + 1) * 512;
        float* sl2 = statacc + (size_t)(l * 3 + 2) * 512;
        // --- GINE aggregation ---
        k_gine_agg<<<N_NODES / 4, 256, 0, stream>>>(hb, h, ctb + (size_t)l * NCOMBO * D, eps, l,
                                                    row_ptr, sorted, aggb);
        // --- merged gw1 (relu, ->hid) + aw_in (->qkv, Q prescaled) ---
        k_mm2_dual<<<dim3(10, N_NODES / 128), 256, 0, stream>>>(
            aggb, WTl + 0, gb1 + (size_t)l * D2, hid, D2, 4,
            hb, WTl + 262144, ab_in + (size_t)l * D3, qkv, D3, D);
        // --- flash attention (128 q rows / block) ---
        k_flash_mfma<<<dim3(NB * NH, S_PG / 128), 256, 0, stream>>>(qkv, ao);
        // --- merged gw2 (K=512, ->tmp1, stats sl0) + aw_out (K=256, ->tmp23, stats sl1) ---
        k_mm64_dual<<<dim3(4, N_NODES / 64), 256, 0, stream>>>(
            hid, WTl + 131072, gb2 + (size_t)l * D, h, tmp1, sl0, D2, 2,
            ao, WTl + 458752, ab_out + (size_t)l * D, h, tmp23, sl1, D);
        // --- combine bn1+bn2 (inline stats) ---
        k_bn12i<<<EW, 256, 0, stream>>>(tmp1, sl0, n1g + l * D, n1b + l * D,
                                        tmp23, sl1, n2g + l * D, n2b + l * D, bufB, bufBb);
        // --- MLP ---
        k_mm2<1, 0, 1, 0><<<dim3(D2 / 128, N_NODES / 128), 256, 0, stream>>>(
            bufBb, WTl + 524288, mb1 + (size_t)l * D2, nullptr, hid, nullptr, N_NODES, D2, D);
        k_mm64<0, 1, 0, 1><<<dim3(D / 128, N_NODES / 64), 256, 0, stream>>>(
            hid, WTl + 655360, mb2 + (size_t)l * D, bufB, tmp23, sl2, N_NODES, D, D2);
        k_bn_apply_i<<<EW, 256, 0, stream>>>(tmp23, sl2, n3g + l * D, n3b + l * D, h, hb);
    }
    k_pool2<<<dim3(NB, 8), 256, 0, stream>>>(h, g);
    k_final_a<<<dim3(NB, 3), 256, 0, stream>>>(g, pw1, pb1, pw2, pb2, z, zpart);
    k_final_b<<<dim3(NB, 3), 256, 0, stream>>>(z, zpart, (float*)d_out);
}